// Round 7
// baseline (826.721 us; speedup 1.0000x reference)
//
#include <hip/hip_runtime.h>
#include <hip/hip_bf16.h>
#include <cstdint>
#include <cstddef>

#define BB 4
#define CC 192
#define NHEAD 6
#define WSZ 16
#define SSH 8
#define NTOK 256
#define HD 32
#define HWPIX 16384
#define TTOT 65536
#define WWID 128
#define SCALE_Q 0.17677669529663687f
#define CONV_SC 0.01f
#define PSTR 264   // attn LDS row stride (shorts): 16B-aligned, <=2-way banks

typedef __hip_bfloat16 bf16;
typedef __attribute__((ext_vector_type(8))) short short8;
typedef __attribute__((ext_vector_type(4))) float float4v;

__device__ __forceinline__ float b2f(bf16 v) { return __bfloat162float(v); }
__device__ __forceinline__ bf16 f2b(float v) { return __float2bfloat16(v); }
__device__ __forceinline__ unsigned short f2bu(float f) {
  bf16 h = __float2bfloat16(f);
  return *reinterpret_cast<unsigned short*>(&h);
}
__device__ __forceinline__ float gelu_exact(float x) {
  return 0.5f * x * (1.0f + erff(x * 0.7071067811865475f));
}
__device__ __forceinline__ short8 ld8z(const bf16* p, bool ok) {
  if (ok) return *(const short8*)p;
  short8 z = {0, 0, 0, 0, 0, 0, 0, 0};
  return z;
}
// async global->LDS 16B per lane: LDS dest = wave-uniform base + lane*16,
// global source is per-lane. size must be literal 16.
__device__ __forceinline__ void glds16(const void* g, void* l) {
  __builtin_amdgcn_global_load_lds(
      (const __attribute__((address_space(1))) unsigned int*)g,
      (__attribute__((address_space(3))) unsigned int*)l, 16, 0, 0);
}

// ---------------- K1: LayerNorm1 (x fp32 -> xn bf16). 1 wave per token -----
__global__ __launch_bounds__(256) void k_ln1(const float* __restrict__ x,
                                             const float* __restrict__ g,
                                             const float* __restrict__ b,
                                             bf16* __restrict__ xn) {
  int wv = threadIdx.x >> 6, lane = threadIdx.x & 63;
  int tok = blockIdx.x * 4 + wv;
  size_t row = (size_t)tok * CC;
  float v0 = x[row + lane], v1 = x[row + lane + 64], v2 = x[row + lane + 128];
  float s = v0 + v1 + v2, ss = v0 * v0 + v1 * v1 + v2 * v2;
#pragma unroll
  for (int off = 1; off < 64; off <<= 1) {
    s += __shfl_xor(s, off, 64);
    ss += __shfl_xor(ss, off, 64);
  }
  float mean = s * (1.0f / CC);
  float rstd = rsqrtf(ss * (1.0f / CC) - mean * mean + 1e-5f);
  xn[row + lane]       = f2b((v0 - mean) * rstd * g[lane]       + b[lane]);
  xn[row + lane + 64]  = f2b((v1 - mean) * rstd * g[lane + 64]  + b[lane + 64]);
  xn[row + lane + 128] = f2b((v2 - mean) * rstd * g[lane + 128] + b[lane + 128]);
}

// ------------- K2: bias gather biasQ[h][query][key] (fp32) ------------------
__global__ __launch_bounds__(256) void k_biasq(const int* __restrict__ rpi,
                                               const float* __restrict__ rpb,
                                               float* __restrict__ biasQ) {
  int k = threadIdx.x;
  int h = blockIdx.x >> 8;
  int q = blockIdx.x & 255;
  biasQ[(size_t)blockIdx.x * 256 + k] = rpb[rpi[q * 256 + k] * NHEAD + h];
}

// ------- K2b: conv weight transpose to [tap][oc][ci] bf16 -------------------
__global__ __launch_bounds__(256) void k_wprep(const float* __restrict__ c1w,
                                               const float* __restrict__ c2w,
                                               bf16* __restrict__ wT1,
                                               bf16* __restrict__ wT2) {
  int i = blockIdx.x * 256 + threadIdx.x;   // 0 .. 110591
  {
    int tap = i / (64 * 192); int r = i % (64 * 192);
    int oc = r / 192, ci = r % 192;
    wT1[i] = f2b(c1w[(size_t)(tap * 192 + ci) * 64 + oc]);
  }
  {
    int tap = i / (192 * 64); int r = i % (192 * 64);
    int oc = r / 64, ci = r % 64;
    wT2[i] = f2b(c2w[(size_t)(tap * 64 + ci) * 192 + oc]);
  }
}

// ------- K2c: MLP weight transpose to n-major bf16 --------------------------
__global__ __launch_bounds__(256) void k_wprep2(const float* __restrict__ fc1w,
                                                const float* __restrict__ fc2w,
                                                bf16* __restrict__ wF1,
                                                bf16* __restrict__ wF2) {
  int i = blockIdx.x * 256 + threadIdx.x;   // 0 .. 147455
  {
    int n = i / 192, k = i % 192;           // wF1[n][k], n<768 k<192
    wF1[i] = f2b(fc1w[(size_t)k * 768 + n]);
  }
  {
    int n = i / 768, k = i % 768;           // wF2[n][k], n<192 k<768
    wF2[i] = f2b(fc2w[(size_t)k * 192 + n]);
  }
}

// ------- K2d: qkv/proj weight transpose to n-major bf16 ---------------------
__global__ __launch_bounds__(256) void k_wprep3(const float* __restrict__ qkvw,
                                                const float* __restrict__ projw,
                                                bf16* __restrict__ wQv,
                                                bf16* __restrict__ wP) {
  int i = blockIdx.x * 256 + threadIdx.x;   // 0 .. 147455 (grid 576)
  if (i < 576 * 192) {
    int n = i / 192, k = i % 192;           // wQv[n][k], n<576
    wQv[i] = f2b(qkvw[(size_t)k * 576 + n]);
  }
  if (i < 192 * 192) {
    int n = i / 192, k = i % 192;           // wP[n][k]
    wP[i] = f2b(projw[(size_t)k * 192 + n]);
  }
}

// --- K3: QKV GEMM via MFMA (N=576, K=192), gathered scatter store -----------
// grid TTOT/32, block 256 (4 waves). Wave w: cols w*144..+143 (9 tiles).
// 2 token-tiles per block: each weight fragment feeds 2 MFMA.
__global__ __launch_bounds__(256) void k_qkvg2(const bf16* __restrict__ xn,
                                               const bf16* __restrict__ wQv,
                                               const float* __restrict__ qb,
                                               bf16* __restrict__ Qg,
                                               bf16* __restrict__ Kg,
                                               bf16* __restrict__ Vg) {
  int tok0 = blockIdx.x * 32;
  int wave = threadIdx.x >> 6, lane = threadIdx.x & 63;
  int lm = lane & 15, lq = lane >> 4;
  const bf16* arow0 = xn + (size_t)(tok0 + lm) * CC + lq * 8;
  const bf16* arow1 = xn + (size_t)(tok0 + 16 + lm) * CC + lq * 8;
  float4v acc[9][2];
#pragma unroll
  for (int nt = 0; nt < 9; ++nt)
#pragma unroll
    for (int tt = 0; tt < 2; ++tt) acc[nt][tt] = (float4v){0.f, 0.f, 0.f, 0.f};
#pragma unroll
  for (int ks = 0; ks < 6; ++ks) {
    short8 af0 = *(const short8*)(arow0 + ks * 32);
    short8 af1 = *(const short8*)(arow1 + ks * 32);
#pragma unroll
    for (int nt = 0; nt < 9; ++nt) {
      int col = wave * 144 + nt * 16 + lm;
      short8 bfrag = *(const short8*)(wQv + (size_t)col * CC + ks * 32 + lq * 8);
      acc[nt][0] = __builtin_amdgcn_mfma_f32_16x16x32_bf16(af0, bfrag, acc[nt][0], 0, 0, 0);
      acc[nt][1] = __builtin_amdgcn_mfma_f32_16x16x32_bf16(af1, bfrag, acc[nt][1], 0, 0, 0);
    }
  }
  // per-(tt,reg) token -> gathered (window,head) coords
  size_t base[2][4];
#pragma unroll
  for (int tt = 0; tt < 2; ++tt)
#pragma unroll
    for (int reg = 0; reg < 4; ++reg) {
      int tg = tok0 + tt * 16 + lq * 4 + reg;
      int b = tg >> 14;
      int pix = tg & 16383;
      int gh = pix >> 7, gw = pix & 127;
      int hs = (gh + 120) & 127, wsx = (gw + 120) & 127;
      int wdx = (b << 6) + ((hs >> 4) << 3) + (wsx >> 4);
      int ndx = ((hs & 15) << 4) + (wsx & 15);
      base[tt][reg] = ((size_t)wdx * NHEAD) * NTOK * HD + (size_t)ndx * HD;
    }
#pragma unroll
  for (int nt = 0; nt < 9; ++nt) {
    int col = wave * 144 + nt * 16 + lm;
    float bias = qb[col];
    int sect = col / 192, within = col - sect * 192;
    int head = within >> 5, d = within & 31;
    bf16* dst = (sect == 0) ? Qg : (sect == 1) ? Kg : Vg;
    float scale = (sect == 0) ? SCALE_Q : 1.f;
#pragma unroll
    for (int tt = 0; tt < 2; ++tt)
#pragma unroll
      for (int reg = 0; reg < 4; ++reg) {
        dst[base[tt][reg] + (size_t)head * NTOK * HD + d] =
            f2b((acc[nt][tt][reg] + bias) * scale);
      }
  }
}

// --- K4: windowed attention via MFMA --------------------------------------
// grid = 1536*2 (wh, query-half). block 256 = 4 waves x 32 queries.
// S = Q*K^T (MFMA), full softmax per 16-row tile, P->LDS bf16, O = P*V (MFMA).
__global__ __launch_bounds__(256) void k_attn2(const bf16* __restrict__ Qg,
                                               const bf16* __restrict__ Kg,
                                               const bf16* __restrict__ Vg,
                                               const float* __restrict__ biasQ,
                                               bf16* __restrict__ AO) {
  __shared__ unsigned short PTw[4][16 * PSTR];  // 33,792 B (wave-private P tiles)
  __shared__ unsigned short VT[32 * PSTR];      // 16,896 B (V transposed)
  int wh = blockIdx.x >> 1, half = blockIdx.x & 1;
  int wdx = wh / NHEAD, h = wh - wdx * NHEAD;
  int wl = wdx & 63;
  int wr = wl >> 3, wc = wl & 7;
  int tid = threadIdx.x;
  int wave = tid >> 6, lane = tid & 63;
  int lm = lane & 15, lq = lane >> 4;
  int q0 = half * 128;

  // stage V^T: thread tid handles key row tid
  {
    const uint4* vp = (const uint4*)(Vg + ((size_t)wh * NTOK + tid) * HD);
    uint4 vv[4] = {vp[0], vp[1], vp[2], vp[3]};
#pragma unroll
    for (int i = 0; i < 4; ++i) {
      unsigned arr[4] = {vv[i].x, vv[i].y, vv[i].z, vv[i].w};
#pragma unroll
      for (int j = 0; j < 4; ++j) {
        int d = i * 8 + j * 2;
        VT[d * PSTR + tid]       = (unsigned short)(arr[j] & 0xffffu);
        VT[(d + 1) * PSTR + tid] = (unsigned short)(arr[j] >> 16);
      }
    }
  }
  __syncthreads();

  int wsk = (wc << 4) + lm;                       // lane's key col (w coord)
  int ridk_w = (wsk >= 112) + (wsk >= 120);
  unsigned short* PT = &PTw[wave][0];

  float4v oacc[2][2];
#pragma unroll
  for (int rt = 0; rt < 2; ++rt)
#pragma unroll
    for (int c2 = 0; c2 < 2; ++c2) oacc[rt][c2] = (float4v){0.f, 0.f, 0.f, 0.f};
  float linv[2][4];

#pragma unroll
  for (int rt = 0; rt < 2; ++rt) {
    int qrow = q0 + wave * 32 + rt * 16;
    short8 aq = *(const short8*)(Qg + ((size_t)wh * NTOK + qrow + lm) * HD + lq * 8);
    float4v sacc[16];
#pragma unroll
    for (int ct = 0; ct < 16; ++ct) sacc[ct] = (float4v){0.f, 0.f, 0.f, 0.f};
#pragma unroll
    for (int ct = 0; ct < 16; ++ct) {
      short8 kf = *(const short8*)(Kg + ((size_t)wh * NTOK + ct * 16 + lm) * HD + lq * 8);
      sacc[ct] = __builtin_amdgcn_mfma_f32_16x16x32_bf16(aq, kf, sacc[ct], 0, 0, 0);
    }
    // softmax over 256 keys, rows lq*4+reg of this 16-row tile
#pragma unroll
    for (int reg = 0; reg < 4; ++reg) {
      int nq = qrow + lq * 4 + reg;
      int hsq = (wr << 4) + (nq >> 4), wsq = (wc << 4) + (nq & 15);
      int ridq = ((hsq >= 112) + (hsq >= 120)) * 3 + ((wsq >= 112) + (wsq >= 120));
      const float* bq = biasQ + ((size_t)(h * 256 + nq)) * 256 + lm;
      float sv[16];
      float mx = -1.0e30f;
#pragma unroll
      for (int ct = 0; ct < 16; ++ct) {
        int hsk = (wr << 4) + ct;
        int ridk = ((hsk >= 112) + (hsk >= 120)) * 3 + ridk_w;
        float s = sacc[ct][reg] + bq[ct * 16] + ((ridk != ridq) ? -100.f : 0.f);
        sv[ct] = s;
        mx = fmaxf(mx, s);
      }
#pragma unroll
      for (int off = 1; off < 16; off <<= 1) mx = fmaxf(mx, __shfl_xor(mx, off, 64));
      float l = 0.f;
#pragma unroll
      for (int ct = 0; ct < 16; ++ct) {
        float p = __expf(sv[ct] - mx);
        l += p;
        PT[(lq * 4 + reg) * PSTR + ct * 16 + lm] = f2bu(p);
      }
#pragma unroll
      for (int off = 1; off < 16; off <<= 1) l += __shfl_xor(l, off, 64);
      linv[rt][reg] = 1.f / l;
    }
    // PV for this row tile: A = P rows (wave-private, in-wave LDS ordering)
#pragma unroll
    for (int kb = 0; kb < 8; ++kb) {
      short8 pf = *(const short8*)&PT[lm * PSTR + kb * 32 + lq * 8];
#pragma unroll
      for (int c2 = 0; c2 < 2; ++c2) {
        short8 vf = *(const short8*)&VT[(c2 * 16 + lm) * PSTR + kb * 32 + lq * 8];
        oacc[rt][c2] = __builtin_amdgcn_mfma_f32_16x16x32_bf16(pf, vf, oacc[rt][c2], 0, 0, 0);
      }
    }
  }
  // write AO
#pragma unroll
  for (int rt = 0; rt < 2; ++rt)
#pragma unroll
    for (int c2 = 0; c2 < 2; ++c2) {
      int d = c2 * 16 + lm;
#pragma unroll
      for (int reg = 0; reg < 4; ++reg) {
        int nq = q0 + wave * 32 + rt * 16 + lq * 4 + reg;
        AO[((size_t)wdx * NTOK + nq) * CC + h * HD + d] =
            f2b(oacc[rt][c2][reg] * linv[rt][reg]);
      }
    }
}

// --- K5: proj GEMM via MFMA (N=192, K=192) + shift-reverse + x residual -----
// grid TTOT/32 (win-order rows), block 256 (4 waves). Wave w: cols w*48..+47.
// 2 token-tiles per block: each wP fragment feeds 2 MFMA.
__global__ __launch_bounds__(256) void k_proj2(const bf16* __restrict__ AO,
                                               const bf16* __restrict__ wP,
                                               const float* __restrict__ pb,
                                               const float* __restrict__ x,
                                               float* __restrict__ y) {
  int r0 = blockIdx.x * 32;
  int wave = threadIdx.x >> 6, lane = threadIdx.x & 63;
  int lm = lane & 15, lq = lane >> 4;
  const bf16* arow0 = AO + (size_t)(r0 + lm) * CC + lq * 8;
  const bf16* arow1 = AO + (size_t)(r0 + 16 + lm) * CC + lq * 8;
  float4v acc[3][2];
#pragma unroll
  for (int nt = 0; nt < 3; ++nt)
#pragma unroll
    for (int tt = 0; tt < 2; ++tt) acc[nt][tt] = (float4v){0.f, 0.f, 0.f, 0.f};
#pragma unroll
  for (int ks = 0; ks < 6; ++ks) {
    short8 af0 = *(const short8*)(arow0 + ks * 32);
    short8 af1 = *(const short8*)(arow1 + ks * 32);
#pragma unroll
    for (int nt = 0; nt < 3; ++nt) {
      int col = wave * 48 + nt * 16 + lm;
      short8 bfrag = *(const short8*)(wP + (size_t)col * CC + ks * 32 + lq * 8);
      acc[nt][0] = __builtin_amdgcn_mfma_f32_16x16x32_bf16(af0, bfrag, acc[nt][0], 0, 0, 0);
      acc[nt][1] = __builtin_amdgcn_mfma_f32_16x16x32_bf16(af1, bfrag, acc[nt][1], 0, 0, 0);
    }
  }
  size_t drow[2][4];
#pragma unroll
  for (int tt = 0; tt < 2; ++tt)
#pragma unroll
    for (int reg = 0; reg < 4; ++reg) {
      int r = r0 + tt * 16 + lq * 4 + reg;
      int wdx = r >> 8, n = r & 255;
      int wb = wdx >> 6, wl = wdx & 63;
      int hs = ((wl >> 3) << 4) + (n >> 4);
      int wsx = ((wl & 7) << 4) + (n & 15);
      int gh = (hs + SSH) & 127, gw = (wsx + SSH) & 127;
      drow[tt][reg] = ((size_t)wb * HWPIX + (size_t)gh * WWID + gw) * CC;
    }
#pragma unroll
  for (int nt = 0; nt < 3; ++nt) {
    int col = wave * 48 + nt * 16 + lm;
    float bias = pb[col];
#pragma unroll
    for (int tt = 0; tt < 2; ++tt)
#pragma unroll
      for (int reg = 0; reg < 4; ++reg) {
        y[drow[tt][reg] + col] = x[drow[tt][reg] + col] + acc[nt][tt][reg] + bias;
      }
  }
}

// ---- K6: conv3x3 192->64 + GELU via MFMA implicit GEMM ---------------------
__global__ __launch_bounds__(256) void k_conv1m(const bf16* __restrict__ xn,
                                                const bf16* __restrict__ wT1,
                                                const float* __restrict__ c1b,
                                                bf16* __restrict__ cv1) {
  int bi = blockIdx.x;
  int seg = bi & 1, hh = (bi >> 1) & 127, b = bi >> 8;
  int px0 = seg * 64;
  int wave = threadIdx.x >> 6, lane = threadIdx.x & 63;
  int lm = lane & 15, lq = lane >> 4;
  int oc = wave * 16 + lm;
  float4v acc[4];
#pragma unroll
  for (int t = 0; t < 4; ++t) acc[t] = (float4v){0.f, 0.f, 0.f, 0.f};
#pragma unroll
  for (int tap = 0; tap < 9; ++tap) {
    int kh = tap / 3, kw = tap % 3;
    int gh = hh + kh - 1;
    bool rowok = ((unsigned)gh < 128u);
    const bf16* wrow = wT1 + ((size_t)tap * 64 + oc) * CC + lq * 8;
    const bf16* xrow = xn + ((size_t)b * HWPIX + (size_t)gh * WWID) * CC + lq * 8;
#pragma unroll
    for (int ks = 0; ks < 6; ++ks) {
      short8 bfrag = *(const short8*)(wrow + ks * 32);
#pragma unroll
      for (int t = 0; t < 4; ++t) {
        int px = px0 + t * 16 + lm + kw - 1;
        short8 afrag = ld8z(xrow + (size_t)px * CC + ks * 32,
                            rowok && ((unsigned)px < 128u));
        acc[t] = __builtin_amdgcn_mfma_f32_16x16x32_bf16(afrag, bfrag, acc[t], 0, 0, 0);
      }
    }
  }
  float bias = c1b[oc];
#pragma unroll
  for (int t = 0; t < 4; ++t) {
    int pxb = px0 + t * 16 + lq * 4;
    size_t base = ((size_t)b * HWPIX + (size_t)hh * WWID + pxb) * 64 + oc;
    cv1[base]       = f2b(gelu_exact(acc[t][0] + bias));
    cv1[base + 64]  = f2b(gelu_exact(acc[t][1] + bias));
    cv1[base + 128] = f2b(gelu_exact(acc[t][2] + bias));
    cv1[base + 192] = f2b(gelu_exact(acc[t][3] + bias));
  }
}

// ---- K7: conv3x3 64->192 + bias via MFMA implicit GEMM ---------------------
__global__ __launch_bounds__(256) void k_conv2m(const bf16* __restrict__ cv1,
                                                const bf16* __restrict__ wT2,
                                                const float* __restrict__ c2b,
                                                bf16* __restrict__ cv2) {
  int bi = blockIdx.x;
  int seg = bi & 1, hh = (bi >> 1) & 127, b = bi >> 8;
  int px0 = seg * 64;
  int wave = threadIdx.x >> 6, lane = threadIdx.x & 63;
  int lm = lane & 15, lq = lane >> 4;
  float4v acc[3][4];
#pragma unroll
  for (int nt = 0; nt < 3; ++nt)
#pragma unroll
    for (int t = 0; t < 4; ++t) acc[nt][t] = (float4v){0.f, 0.f, 0.f, 0.f};
#pragma unroll
  for (int tap = 0; tap < 9; ++tap) {
    int kh = tap / 3, kw = tap % 3;
    int gh = hh + kh - 1;
    bool rowok = ((unsigned)gh < 128u);
    const bf16* xrow = cv1 + ((size_t)b * HWPIX + (size_t)gh * WWID) * 64 + lq * 8;
#pragma unroll
    for (int ks = 0; ks < 2; ++ks) {
      short8 bfrag[3];
#pragma unroll
      for (int nt = 0; nt < 3; ++nt) {
        int oc = wave * 48 + nt * 16 + lm;
        bfrag[nt] = *(const short8*)(wT2 + ((size_t)tap * 192 + oc) * 64 + ks * 32 + lq * 8);
      }
#pragma unroll
      for (int t = 0; t < 4; ++t) {
        int px = px0 + t * 16 + lm + kw - 1;
        short8 afrag = ld8z(xrow + (size_t)px * 64 + ks * 32,
                            rowok && ((unsigned)px < 128u));
#pragma unroll
        for (int nt = 0; nt < 3; ++nt)
          acc[nt][t] = __builtin_amdgcn_mfma_f32_16x16x32_bf16(afrag, bfrag[nt], acc[nt][t], 0, 0, 0);
      }
    }
  }
#pragma unroll
  for (int nt = 0; nt < 3; ++nt) {
    int oc = wave * 48 + nt * 16 + lm;
    float bias = c2b[oc];
#pragma unroll
    for (int t = 0; t < 4; ++t) {
      int pxb = px0 + t * 16 + lq * 4;
      size_t base = ((size_t)b * HWPIX + (size_t)hh * WWID + pxb) * CC + oc;
      cv2[base]           = f2b(acc[nt][t][0] + bias);
      cv2[base + CC]      = f2b(acc[nt][t][1] + bias);
      cv2[base + 2 * CC]  = f2b(acc[nt][t][2] + bias);
      cv2[base + 3 * CC]  = f2b(acc[nt][t][3] + bias);
    }
  }
}

// ---------------- K8: global average pool (sum into pooled, pre-zeroed) ----
__global__ __launch_bounds__(192) void k_pool(const bf16* __restrict__ cv2,
                                              float* __restrict__ pooled) {
  int t = threadIdx.x;                        // channel
  int b = blockIdx.x >> 7;
  int pc = blockIdx.x & 127;                  // 128-pixel chunk
  const bf16* base = cv2 + ((size_t)b * HWPIX + (size_t)pc * 128) * CC + t;
  float s = 0.f;
#pragma unroll 4
  for (int p = 0; p < 128; ++p) s += b2f(base[(size_t)p * CC]);
  atomicAdd(&pooled[b * CC + t], s);
}

// ---------------- K9: channel attention weights ----------------
__global__ __launch_bounds__(192) void k_ca(const float* __restrict__ pooled,
                                            const float* __restrict__ w1,
                                            const float* __restrict__ b1,
                                            const float* __restrict__ w2,
                                            const float* __restrict__ b2,
                                            float* __restrict__ ca) {
  __shared__ float pld[CC];
  __shared__ float t1[6];
  int t = threadIdx.x, b = blockIdx.x;
  pld[t] = pooled[b * CC + t] * (1.0f / HWPIX);
  __syncthreads();
  if (t < 6) {
    float s = b1[t];
    for (int c = 0; c < CC; ++c) s += pld[c] * w1[c * 6 + t];
    t1[t] = fmaxf(s, 0.f);
  }
  __syncthreads();
  float s = b2[t];
#pragma unroll
  for (int k = 0; k < 6; ++k) s += t1[k] * w2[k * CC + t];
  ca[b * CC + t] = 1.f / (1.f + __expf(-s));
}

// --- K10: LN2 with conv-branch fold: yn = LN(y + cv2*ca*0.01) bf16 ---------
__global__ __launch_bounds__(256) void k_ln2(const float* __restrict__ y,
                                             const bf16* __restrict__ cv2,
                                             const float* __restrict__ ca,
                                             const float* __restrict__ g2,
                                             const float* __restrict__ b2,
                                             bf16* __restrict__ yn) {
  int wv = threadIdx.x >> 6, lane = threadIdx.x & 63;
  int tok = blockIdx.x * 4 + wv;
  const float* cab = ca + (tok >> 14) * CC;
  size_t row = (size_t)tok * CC;
  float v0 = y[row + lane]       + b2f(cv2[row + lane])       * cab[lane]       * CONV_SC;
  float v1 = y[row + lane + 64]  + b2f(cv2[row + lane + 64])  * cab[lane + 64]  * CONV_SC;
  float v2 = y[row + lane + 128] + b2f(cv2[row + lane + 128]) * cab[lane + 128] * CONV_SC;
  float s = v0 + v1 + v2, ss = v0 * v0 + v1 * v1 + v2 * v2;
#pragma unroll
  for (int off = 1; off < 64; off <<= 1) {
    s += __shfl_xor(s, off, 64);
    ss += __shfl_xor(ss, off, 64);
  }
  float mean = s * (1.0f / CC);
  float rstd = rsqrtf(ss * (1.0f / CC) - mean * mean + 1e-5f);
  yn[row + lane]       = f2b((v0 - mean) * rstd * g2[lane]       + b2[lane]);
  yn[row + lane + 64]  = f2b((v1 - mean) * rstd * g2[lane + 64]  + b2[lane + 64]);
  yn[row + lane + 128] = f2b((v2 - mean) * rstd * g2[lane + 128] + b2[lane + 128]);
}

// --- K11a: fc1 weight-stationary: h = GELU(yn @ fc1 + b) --------------------
// grid 512 = 4 col-panels (cg) x 128 token-blocks (tb, 512 tokens).
// Panel wF1[cg*192..+192)[192] = 73,728 B is CONTIGUOUS in wF1 -> staged once
// by a linear global_load_lds memcpy (source XOR-swizzled at 16B granularity
// with (row&7); LDS stays linear per rule #21). Wave's 18 weight frags
// hoisted to 72 VGPR, then a barrier-free loop over 32 token tiles.
__global__ __launch_bounds__(256, 2) void k_fc1ws(const bf16* __restrict__ yn,
                                                  const bf16* __restrict__ wF1,
                                                  const float* __restrict__ fb1,
                                                  bf16* __restrict__ h) {
  __shared__ unsigned short wl[192 * 192];   // 73,728 B
  int cg = blockIdx.x & 3, tb = blockIdx.x >> 2;
  int tid = threadIdx.x;
  int wave = tid >> 6, lane = tid & 63;
  int lm = lane & 15, lq = lane >> 4;

  const char* src = (const char*)wF1 + (size_t)cg * 73728;
#pragma unroll
  for (int j = 0; j < 18; ++j) {
    int ci = j * 256 + tid;                  // 16B-chunk index 0..4607
    int r = ci / 24, c = ci - r * 24;        // row 0..191, chunk 0..23
    glds16(src + (size_t)r * 384 + ((c ^ (r & 7)) << 4),
           (char*)wl + (size_t)(j * 256 + wave * 64) * 16);
  }
  __syncthreads();

  // hoist wave's B-frags (cols wave*48 + nt*16 + lm) -- one-time LDS reads
  short8 wfr[3][6];
#pragma unroll
  for (int nt = 0; nt < 3; ++nt) {
    int rl = wave * 48 + nt * 16 + lm;
#pragma unroll
    for (int ks = 0; ks < 6; ++ks)
      wfr[nt][ks] = *(const short8*)&wl[rl * 192 + (((ks * 4 + lq) ^ (rl & 7)) << 3)];
  }
  float4 b4[3];
#pragma unroll
  for (int nt = 0; nt < 3; ++nt)
    b4[nt] = *(const float4*)(fb1 + cg * 192 + wave * 48 + nt * 16 + lq * 4);

  int tok0b = tb * 512;
#pragma unroll 2
  for (int t = 0; t < 32; ++t) {
    int tok0 = tok0b + t * 16;
    const bf16* arow = yn + (size_t)(tok0 + lm) * CC + lq * 8;
    float4v acc[3];
#pragma unroll
    for (int nt = 0; nt < 3; ++nt) acc[nt] = (float4v){0.f, 0.f, 0.f, 0.f};
#pragma unroll
    for (int ks = 0; ks < 6; ++ks) {
      short8 tf = *(const short8*)(arow + ks * 32);
#pragma unroll
      for (int nt = 0; nt < 3; ++nt)
        acc[nt] = __builtin_amdgcn_mfma_f32_16x16x32_bf16(wfr[nt][ks], tf, acc[nt], 0, 0, 0);
    }
    bf16* hrow = h + (size_t)(tok0 + lm) * 768 + cg * 192 + wave * 48 + lq * 4;
#pragma unroll
    for (int nt = 0; nt < 3; ++nt) {
      unsigned short u0 = f2bu(gelu_exact(acc[nt][0] + b4[nt].x));
      unsigned short u1 = f2bu(gelu_exact(acc[nt][1] + b4[nt].y));
      unsigned short u2 = f2bu(gelu_exact(acc[nt][2] + b4[nt].z));
      unsigned short u3 = f2bu(gelu_exact(acc[nt][3] + b4[nt].w));
      uint2 pk;
      pk.x = (unsigned)u0 | ((unsigned)u1 << 16);
      pk.y = (unsigned)u2 | ((unsigned)u3 << 16);
      *(uint2*)(hrow + nt * 16) = pk;
    }
  }
}

// --- K11b: fc2 register-weight-stationary + residual epilogue ---------------
// grid 256 (= 1 block/CU), block 768 (12 waves, 3/SIMD). Each wave holds its
// 16-col x 768-k wF2 panel in 96 VGPRs (24 statically-indexed short8 frags)
// -> a block computes ALL 192 columns, so h is read ONCE (prev: 4 col-panel
// blocks on different XCDs re-read h 4x = 364 MB FETCH, BW-bound at 173us).
// All 12 waves stream the same h rows -> L1/L2 temporal sharing. No LDS, no
// mid-loop barriers. 8 token-pair tiles x {48 h-loads, 48 MFMA, epilogue}.
__global__ __launch_bounds__(768, 3) void k_fc2r(const bf16* __restrict__ h,
                                                 const bf16* __restrict__ wF2,
                                                 const float* __restrict__ fb2,
                                                 const float* __restrict__ y,
                                                 const bf16* __restrict__ cv2,
                                                 const float* __restrict__ ca,
                                                 float* __restrict__ out) {
  int wave = threadIdx.x >> 6, lane = threadIdx.x & 63;
  int lm = lane & 15, lq = lane >> 4;
  int col = wave * 16 + lm;                  // this lane's output column
  // hoist this wave's 16-col full-K weight panel into 96 VGPRs
  short8 wfr[24];
#pragma unroll
  for (int ks = 0; ks < 24; ++ks)
    wfr[ks] = *(const short8*)(wF2 + (size_t)col * 768 + ks * 32 + lq * 8);
  int tok0b = blockIdx.x * 256;
  float bias = fb2[col];
  float cas = ca[(tok0b >> 14) * CC + col] * CONV_SC;

  for (int tp = 0; tp < 8; ++tp) {
    int t0 = tok0b + tp * 32;
    const bf16* ar0 = h + (size_t)(t0 + lm) * 768 + lq * 8;
    const bf16* ar1 = h + (size_t)(t0 + 16 + lm) * 768 + lq * 8;
    float4v acc[2];
    acc[0] = (float4v){0.f, 0.f, 0.f, 0.f};
    acc[1] = (float4v){0.f, 0.f, 0.f, 0.f};
#pragma unroll
    for (int ks = 0; ks < 24; ++ks) {
      short8 a0 = *(const short8*)(ar0 + ks * 32);
      short8 a1 = *(const short8*)(ar1 + ks * 32);
      acc[0] = __builtin_amdgcn_mfma_f32_16x16x32_bf16(a0, wfr[ks], acc[0], 0, 0, 0);
      acc[1] = __builtin_amdgcn_mfma_f32_16x16x32_bf16(a1, wfr[ks], acc[1], 0, 0, 0);
    }
#pragma unroll
    for (int tt = 0; tt < 2; ++tt) {
#pragma unroll
      for (int reg = 0; reg < 4; ++reg) {
        int tok = t0 + tt * 16 + lq * 4 + reg;
        size_t idx = (size_t)tok * CC + col;
        out[idx] = y[idx] + b2f(cv2[idx]) * cas + acc[tt][reg] + bias;
      }
    }
  }
}

extern "C" void kernel_launch(void* const* d_in, const int* in_sizes, int n_in,
                              void* d_out, int out_size, void* d_ws, size_t ws_size,
                              hipStream_t stream) {
  const float* x      = (const float*)d_in[0];
  const float* qkv_w  = (const float*)d_in[1];
  const float* qkv_b  = (const float*)d_in[2];
  const float* proj_w = (const float*)d_in[3];
  const float* proj_b = (const float*)d_in[4];
  const float* rpb    = (const float*)d_in[5];
  const float* n1w    = (const float*)d_in[6];
  const float* n1b    = (const float*)d_in[7];
  const float* n2w    = (const float*)d_in[8];
  const float* n2b    = (const float*)d_in[9];
  const float* c1w    = (const float*)d_in[10];
  const float* c1b    = (const float*)d_in[11];
  const float* c2w    = (const float*)d_in[12];
  const float* c2b    = (const float*)d_in[13];
  const float* ca1w   = (const float*)d_in[14];
  const float* ca1b   = (const float*)d_in[15];
  const float* ca2w   = (const float*)d_in[16];
  const float* ca2b   = (const float*)d_in[17];
  const float* fc1w   = (const float*)d_in[18];
  const float* fc1b   = (const float*)d_in[19];
  const float* fc2w   = (const float*)d_in[20];
  const float* fc2b   = (const float*)d_in[21];
  const int*   rpi    = (const int*)d_in[22];
  (void)in_sizes; (void)n_in; (void)out_size; (void)ws_size;

  // ---- workspace layout: peak ~212.6 MB (< 256 MiB) ----
  char* wsb = (char*)d_ws;
  bf16*  xn    = (bf16*)(wsb + 0);            // 25,165,824
  bf16*  yn    = (bf16*)(wsb + 0);            // alias xn (dead after conv1m)
  float* biasQ = (float*)(wsb + 25165824);    //  1,572,864
  bf16*  Qg    = (bf16*)(wsb + 26738688);     // 25,165,824
  bf16*  Kg    = (bf16*)(wsb + 51904512);     // 25,165,824
  bf16*  Vg    = (bf16*)(wsb + 77070336);     // 25,165,824
  bf16*  AO    = (bf16*)(wsb + 102236160);    // 25,165,824
  bf16*  hbuf  = (bf16*)(wsb + 26738688);     // 100,663,296 alias Qg..AO (dead after proj2)
  float* y     = (float*)(wsb + 127401984);   // 50,331,648
  bf16*  cv1   = (bf16*)(wsb + 177733632);    //  8,388,608
  bf16*  cv2   = (bf16*)(wsb + 186122240);    // 25,165,824
  float* pool  = (float*)(wsb + 211288064);   //      3,072
  float* cavec = (float*)(wsb + 211291136);   //      3,072
  bf16*  wT1   = (bf16*)(wsb + 211294208);    //    221,184  [9][64][192]
  bf16*  wT2   = (bf16*)(wsb + 211515392);    //    221,184  [9][192][64]
  bf16*  wF1   = (bf16*)(wsb + 211736576);    //    294,912  [768][192]
  bf16*  wF2   = (bf16*)(wsb + 212031488);    //    294,912  [192][768]
  bf16*  wQv   = (bf16*)(wsb + 212326400);    //    221,184  [576][192]
  bf16*  wP    = (bf16*)(wsb + 212547584);    //     73,728  [192][192]
  float* out   = (float*)d_out;               // end 212,621,312

  k_ln1<<<TTOT / 4, 256, 0, stream>>>(x, n1w, n1b, xn);
  k_biasq<<<NHEAD * NTOK, 256, 0, stream>>>(rpi, rpb, biasQ);
  k_wprep<<<432, 256, 0, stream>>>(c1w, c2w, wT1, wT2);
  k_wprep2<<<576, 256, 0, stream>>>(fc1w, fc2w, wF1, wF2);
  k_wprep3<<<576, 256, 0, stream>>>(qkv_w, proj_w, wQv, wP);
  k_qkvg2<<<TTOT / 32, 256, 0, stream>>>(xn, wQv, qkv_b, Qg, Kg, Vg);
  k_attn2<<<BB * 64 * NHEAD * 2, 256, 0, stream>>>(Qg, Kg, Vg, biasQ, AO);
  k_proj2<<<TTOT / 32, 256, 0, stream>>>(AO, wP, proj_b, x, y);
  k_conv1m<<<1024, 256, 0, stream>>>(xn, wT1, c1b, cv1);
  k_conv2m<<<1024, 256, 0, stream>>>(cv1, wT2, c2b, cv2);
  hipMemsetAsync(pool, 0, BB * CC * sizeof(float), stream);
  k_pool<<<512, 192, 0, stream>>>(cv2, pool);
  k_ca<<<BB, 192, 0, stream>>>(pool, ca1w, ca1b, ca2w, ca2b, cavec);
  k_ln2<<<TTOT / 4, 256, 0, stream>>>(y, cv2, cavec, n2w, n2b, yn);
  k_fc1ws<<<512, 256, 0, stream>>>(yn, wF1, fc1b, hbuf);
  k_fc2r<<<256, 768, 0, stream>>>(hbuf, wF2, fc2b, y, cv2, cavec, out);
}

// Round 8
// 707.372 us; speedup vs baseline: 1.1687x; 1.1687x over previous
//
#include <hip/hip_runtime.h>
#include <hip/hip_bf16.h>
#include <cstdint>
#include <cstddef>

#define BB 4
#define CC 192
#define NHEAD 6
#define WSZ 16
#define SSH 8
#define NTOK 256
#define HD 32
#define HWPIX 16384
#define TTOT 65536
#define WWID 128
#define SCALE_Q 0.17677669529663687f
#define CONV_SC 0.01f
#define PSTR 264   // attn LDS row stride (shorts): 16B-aligned, <=2-way banks

typedef __hip_bfloat16 bf16;
typedef __attribute__((ext_vector_type(8))) short short8;
typedef __attribute__((ext_vector_type(4))) float float4v;

__device__ __forceinline__ float b2f(bf16 v) { return __bfloat162float(v); }
__device__ __forceinline__ bf16 f2b(float v) { return __float2bfloat16(v); }
__device__ __forceinline__ unsigned short f2bu(float f) {
  bf16 h = __float2bfloat16(f);
  return *reinterpret_cast<unsigned short*>(&h);
}
__device__ __forceinline__ float gelu_exact(float x) {
  return 0.5f * x * (1.0f + erff(x * 0.7071067811865475f));
}
__device__ __forceinline__ short8 ld8z(const bf16* p, bool ok) {
  if (ok) return *(const short8*)p;
  short8 z = {0, 0, 0, 0, 0, 0, 0, 0};
  return z;
}
// async global->LDS 16B per lane: LDS dest = wave-uniform base + lane*16,
// global source is per-lane. size must be literal 16.
__device__ __forceinline__ void glds16(const void* g, void* l) {
  __builtin_amdgcn_global_load_lds(
      (const __attribute__((address_space(1))) unsigned int*)g,
      (__attribute__((address_space(3))) unsigned int*)l, 16, 0, 0);
}

// ---------------- K1: LayerNorm1 (x fp32 -> xn bf16). 1 wave per token -----
__global__ __launch_bounds__(256) void k_ln1(const float* __restrict__ x,
                                             const float* __restrict__ g,
                                             const float* __restrict__ b,
                                             bf16* __restrict__ xn) {
  int wv = threadIdx.x >> 6, lane = threadIdx.x & 63;
  int tok = blockIdx.x * 4 + wv;
  size_t row = (size_t)tok * CC;
  float v0 = x[row + lane], v1 = x[row + lane + 64], v2 = x[row + lane + 128];
  float s = v0 + v1 + v2, ss = v0 * v0 + v1 * v1 + v2 * v2;
#pragma unroll
  for (int off = 1; off < 64; off <<= 1) {
    s += __shfl_xor(s, off, 64);
    ss += __shfl_xor(ss, off, 64);
  }
  float mean = s * (1.0f / CC);
  float rstd = rsqrtf(ss * (1.0f / CC) - mean * mean + 1e-5f);
  xn[row + lane]       = f2b((v0 - mean) * rstd * g[lane]       + b[lane]);
  xn[row + lane + 64]  = f2b((v1 - mean) * rstd * g[lane + 64]  + b[lane + 64]);
  xn[row + lane + 128] = f2b((v2 - mean) * rstd * g[lane + 128] + b[lane + 128]);
}

// ------------- K2: bias gather biasQ[h][query][key] (fp32) ------------------
__global__ __launch_bounds__(256) void k_biasq(const int* __restrict__ rpi,
                                               const float* __restrict__ rpb,
                                               float* __restrict__ biasQ) {
  int k = threadIdx.x;
  int h = blockIdx.x >> 8;
  int q = blockIdx.x & 255;
  biasQ[(size_t)blockIdx.x * 256 + k] = rpb[rpi[q * 256 + k] * NHEAD + h];
}

// ------- K2b: conv weight transpose to [tap][oc][ci] bf16 -------------------
__global__ __launch_bounds__(256) void k_wprep(const float* __restrict__ c1w,
                                               const float* __restrict__ c2w,
                                               bf16* __restrict__ wT1,
                                               bf16* __restrict__ wT2) {
  int i = blockIdx.x * 256 + threadIdx.x;   // 0 .. 110591
  {
    int tap = i / (64 * 192); int r = i % (64 * 192);
    int oc = r / 192, ci = r % 192;
    wT1[i] = f2b(c1w[(size_t)(tap * 192 + ci) * 64 + oc]);
  }
  {
    int tap = i / (192 * 64); int r = i % (192 * 64);
    int oc = r / 64, ci = r % 64;
    wT2[i] = f2b(c2w[(size_t)(tap * 64 + ci) * 192 + oc]);
  }
}

// ------- K2c: MLP weight transpose to n-major bf16 --------------------------
__global__ __launch_bounds__(256) void k_wprep2(const float* __restrict__ fc1w,
                                                const float* __restrict__ fc2w,
                                                bf16* __restrict__ wF1,
                                                bf16* __restrict__ wF2) {
  int i = blockIdx.x * 256 + threadIdx.x;   // 0 .. 147455
  {
    int n = i / 192, k = i % 192;           // wF1[n][k], n<768 k<192
    wF1[i] = f2b(fc1w[(size_t)k * 768 + n]);
  }
  {
    int n = i / 768, k = i % 768;           // wF2[n][k], n<192 k<768
    wF2[i] = f2b(fc2w[(size_t)k * 192 + n]);
  }
}

// ------- K2d: qkv/proj weight transpose to n-major bf16 ---------------------
__global__ __launch_bounds__(256) void k_wprep3(const float* __restrict__ qkvw,
                                                const float* __restrict__ projw,
                                                bf16* __restrict__ wQv,
                                                bf16* __restrict__ wP) {
  int i = blockIdx.x * 256 + threadIdx.x;   // 0 .. 147455 (grid 576)
  if (i < 576 * 192) {
    int n = i / 192, k = i % 192;           // wQv[n][k], n<576
    wQv[i] = f2b(qkvw[(size_t)k * 576 + n]);
  }
  if (i < 192 * 192) {
    int n = i / 192, k = i % 192;           // wP[n][k]
    wP[i] = f2b(projw[(size_t)k * 192 + n]);
  }
}

// --- K3: QKV GEMM via MFMA (N=576, K=192), gathered scatter store -----------
// grid TTOT/32, block 256 (4 waves). Wave w: cols w*144..+143 (9 tiles).
// 2 token-tiles per block: each weight fragment feeds 2 MFMA.
__global__ __launch_bounds__(256) void k_qkvg2(const bf16* __restrict__ xn,
                                               const bf16* __restrict__ wQv,
                                               const float* __restrict__ qb,
                                               bf16* __restrict__ Qg,
                                               bf16* __restrict__ Kg,
                                               bf16* __restrict__ Vg) {
  int tok0 = blockIdx.x * 32;
  int wave = threadIdx.x >> 6, lane = threadIdx.x & 63;
  int lm = lane & 15, lq = lane >> 4;
  const bf16* arow0 = xn + (size_t)(tok0 + lm) * CC + lq * 8;
  const bf16* arow1 = xn + (size_t)(tok0 + 16 + lm) * CC + lq * 8;
  float4v acc[9][2];
#pragma unroll
  for (int nt = 0; nt < 9; ++nt)
#pragma unroll
    for (int tt = 0; tt < 2; ++tt) acc[nt][tt] = (float4v){0.f, 0.f, 0.f, 0.f};
#pragma unroll
  for (int ks = 0; ks < 6; ++ks) {
    short8 af0 = *(const short8*)(arow0 + ks * 32);
    short8 af1 = *(const short8*)(arow1 + ks * 32);
#pragma unroll
    for (int nt = 0; nt < 9; ++nt) {
      int col = wave * 144 + nt * 16 + lm;
      short8 bfrag = *(const short8*)(wQv + (size_t)col * CC + ks * 32 + lq * 8);
      acc[nt][0] = __builtin_amdgcn_mfma_f32_16x16x32_bf16(af0, bfrag, acc[nt][0], 0, 0, 0);
      acc[nt][1] = __builtin_amdgcn_mfma_f32_16x16x32_bf16(af1, bfrag, acc[nt][1], 0, 0, 0);
    }
  }
  // per-(tt,reg) token -> gathered (window,head) coords
  size_t base[2][4];
#pragma unroll
  for (int tt = 0; tt < 2; ++tt)
#pragma unroll
    for (int reg = 0; reg < 4; ++reg) {
      int tg = tok0 + tt * 16 + lq * 4 + reg;
      int b = tg >> 14;
      int pix = tg & 16383;
      int gh = pix >> 7, gw = pix & 127;
      int hs = (gh + 120) & 127, wsx = (gw + 120) & 127;
      int wdx = (b << 6) + ((hs >> 4) << 3) + (wsx >> 4);
      int ndx = ((hs & 15) << 4) + (wsx & 15);
      base[tt][reg] = ((size_t)wdx * NHEAD) * NTOK * HD + (size_t)ndx * HD;
    }
#pragma unroll
  for (int nt = 0; nt < 9; ++nt) {
    int col = wave * 144 + nt * 16 + lm;
    float bias = qb[col];
    int sect = col / 192, within = col - sect * 192;
    int head = within >> 5, d = within & 31;
    bf16* dst = (sect == 0) ? Qg : (sect == 1) ? Kg : Vg;
    float scale = (sect == 0) ? SCALE_Q : 1.f;
#pragma unroll
    for (int tt = 0; tt < 2; ++tt)
#pragma unroll
      for (int reg = 0; reg < 4; ++reg) {
        dst[base[tt][reg] + (size_t)head * NTOK * HD + d] =
            f2b((acc[nt][tt][reg] + bias) * scale);
      }
  }
}

// --- K4: windowed attention via MFMA --------------------------------------
// grid = 1536*2 (wh, query-half). block 256 = 4 waves x 32 queries.
// S = Q*K^T (MFMA), full softmax per 16-row tile, P->LDS bf16, O = P*V (MFMA).
__global__ __launch_bounds__(256) void k_attn2(const bf16* __restrict__ Qg,
                                               const bf16* __restrict__ Kg,
                                               const bf16* __restrict__ Vg,
                                               const float* __restrict__ biasQ,
                                               bf16* __restrict__ AO) {
  __shared__ unsigned short PTw[4][16 * PSTR];  // 33,792 B (wave-private P tiles)
  __shared__ unsigned short VT[32 * PSTR];      // 16,896 B (V transposed)
  int wh = blockIdx.x >> 1, half = blockIdx.x & 1;
  int wdx = wh / NHEAD, h = wh - wdx * NHEAD;
  int wl = wdx & 63;
  int wr = wl >> 3, wc = wl & 7;
  int tid = threadIdx.x;
  int wave = tid >> 6, lane = tid & 63;
  int lm = lane & 15, lq = lane >> 4;
  int q0 = half * 128;

  // stage V^T: thread tid handles key row tid
  {
    const uint4* vp = (const uint4*)(Vg + ((size_t)wh * NTOK + tid) * HD);
    uint4 vv[4] = {vp[0], vp[1], vp[2], vp[3]};
#pragma unroll
    for (int i = 0; i < 4; ++i) {
      unsigned arr[4] = {vv[i].x, vv[i].y, vv[i].z, vv[i].w};
#pragma unroll
      for (int j = 0; j < 4; ++j) {
        int d = i * 8 + j * 2;
        VT[d * PSTR + tid]       = (unsigned short)(arr[j] & 0xffffu);
        VT[(d + 1) * PSTR + tid] = (unsigned short)(arr[j] >> 16);
      }
    }
  }
  __syncthreads();

  int wsk = (wc << 4) + lm;                       // lane's key col (w coord)
  int ridk_w = (wsk >= 112) + (wsk >= 120);
  unsigned short* PT = &PTw[wave][0];

  float4v oacc[2][2];
#pragma unroll
  for (int rt = 0; rt < 2; ++rt)
#pragma unroll
    for (int c2 = 0; c2 < 2; ++c2) oacc[rt][c2] = (float4v){0.f, 0.f, 0.f, 0.f};
  float linv[2][4];

#pragma unroll
  for (int rt = 0; rt < 2; ++rt) {
    int qrow = q0 + wave * 32 + rt * 16;
    short8 aq = *(const short8*)(Qg + ((size_t)wh * NTOK + qrow + lm) * HD + lq * 8);
    float4v sacc[16];
#pragma unroll
    for (int ct = 0; ct < 16; ++ct) sacc[ct] = (float4v){0.f, 0.f, 0.f, 0.f};
#pragma unroll
    for (int ct = 0; ct < 16; ++ct) {
      short8 kf = *(const short8*)(Kg + ((size_t)wh * NTOK + ct * 16 + lm) * HD + lq * 8);
      sacc[ct] = __builtin_amdgcn_mfma_f32_16x16x32_bf16(aq, kf, sacc[ct], 0, 0, 0);
    }
    // softmax over 256 keys, rows lq*4+reg of this 16-row tile
#pragma unroll
    for (int reg = 0; reg < 4; ++reg) {
      int nq = qrow + lq * 4 + reg;
      int hsq = (wr << 4) + (nq >> 4), wsq = (wc << 4) + (nq & 15);
      int ridq = ((hsq >= 112) + (hsq >= 120)) * 3 + ((wsq >= 112) + (wsq >= 120));
      const float* bq = biasQ + ((size_t)(h * 256 + nq)) * 256 + lm;
      float sv[16];
      float mx = -1.0e30f;
#pragma unroll
      for (int ct = 0; ct < 16; ++ct) {
        int hsk = (wr << 4) + ct;
        int ridk = ((hsk >= 112) + (hsk >= 120)) * 3 + ridk_w;
        float s = sacc[ct][reg] + bq[ct * 16] + ((ridk != ridq) ? -100.f : 0.f);
        sv[ct] = s;
        mx = fmaxf(mx, s);
      }
#pragma unroll
      for (int off = 1; off < 16; off <<= 1) mx = fmaxf(mx, __shfl_xor(mx, off, 64));
      float l = 0.f;
#pragma unroll
      for (int ct = 0; ct < 16; ++ct) {
        float p = __expf(sv[ct] - mx);
        l += p;
        PT[(lq * 4 + reg) * PSTR + ct * 16 + lm] = f2bu(p);
      }
#pragma unroll
      for (int off = 1; off < 16; off <<= 1) l += __shfl_xor(l, off, 64);
      linv[rt][reg] = 1.f / l;
    }
    // PV for this row tile: A = P rows (wave-private, in-wave LDS ordering)
#pragma unroll
    for (int kb = 0; kb < 8; ++kb) {
      short8 pf = *(const short8*)&PT[lm * PSTR + kb * 32 + lq * 8];
#pragma unroll
      for (int c2 = 0; c2 < 2; ++c2) {
        short8 vf = *(const short8*)&VT[(c2 * 16 + lm) * PSTR + kb * 32 + lq * 8];
        oacc[rt][c2] = __builtin_amdgcn_mfma_f32_16x16x32_bf16(pf, vf, oacc[rt][c2], 0, 0, 0);
      }
    }
  }
  // write AO
#pragma unroll
  for (int rt = 0; rt < 2; ++rt)
#pragma unroll
    for (int c2 = 0; c2 < 2; ++c2) {
      int d = c2 * 16 + lm;
#pragma unroll
      for (int reg = 0; reg < 4; ++reg) {
        int nq = q0 + wave * 32 + rt * 16 + lq * 4 + reg;
        AO[((size_t)wdx * NTOK + nq) * CC + h * HD + d] =
            f2b(oacc[rt][c2][reg] * linv[rt][reg]);
      }
    }
}

// --- K5: proj GEMM via MFMA (N=192, K=192) + shift-reverse + x residual -----
// grid TTOT/32 (win-order rows), block 256 (4 waves). Wave w: cols w*48..+47.
// 2 token-tiles per block: each wP fragment feeds 2 MFMA.
__global__ __launch_bounds__(256) void k_proj2(const bf16* __restrict__ AO,
                                               const bf16* __restrict__ wP,
                                               const float* __restrict__ pb,
                                               const float* __restrict__ x,
                                               float* __restrict__ y) {
  int r0 = blockIdx.x * 32;
  int wave = threadIdx.x >> 6, lane = threadIdx.x & 63;
  int lm = lane & 15, lq = lane >> 4;
  const bf16* arow0 = AO + (size_t)(r0 + lm) * CC + lq * 8;
  const bf16* arow1 = AO + (size_t)(r0 + 16 + lm) * CC + lq * 8;
  float4v acc[3][2];
#pragma unroll
  for (int nt = 0; nt < 3; ++nt)
#pragma unroll
    for (int tt = 0; tt < 2; ++tt) acc[nt][tt] = (float4v){0.f, 0.f, 0.f, 0.f};
#pragma unroll
  for (int ks = 0; ks < 6; ++ks) {
    short8 af0 = *(const short8*)(arow0 + ks * 32);
    short8 af1 = *(const short8*)(arow1 + ks * 32);
#pragma unroll
    for (int nt = 0; nt < 3; ++nt) {
      int col = wave * 48 + nt * 16 + lm;
      short8 bfrag = *(const short8*)(wP + (size_t)col * CC + ks * 32 + lq * 8);
      acc[nt][0] = __builtin_amdgcn_mfma_f32_16x16x32_bf16(af0, bfrag, acc[nt][0], 0, 0, 0);
      acc[nt][1] = __builtin_amdgcn_mfma_f32_16x16x32_bf16(af1, bfrag, acc[nt][1], 0, 0, 0);
    }
  }
  size_t drow[2][4];
#pragma unroll
  for (int tt = 0; tt < 2; ++tt)
#pragma unroll
    for (int reg = 0; reg < 4; ++reg) {
      int r = r0 + tt * 16 + lq * 4 + reg;
      int wdx = r >> 8, n = r & 255;
      int wb = wdx >> 6, wl = wdx & 63;
      int hs = ((wl >> 3) << 4) + (n >> 4);
      int wsx = ((wl & 7) << 4) + (n & 15);
      int gh = (hs + SSH) & 127, gw = (wsx + SSH) & 127;
      drow[tt][reg] = ((size_t)wb * HWPIX + (size_t)gh * WWID + gw) * CC;
    }
#pragma unroll
  for (int nt = 0; nt < 3; ++nt) {
    int col = wave * 48 + nt * 16 + lm;
    float bias = pb[col];
#pragma unroll
    for (int tt = 0; tt < 2; ++tt)
#pragma unroll
      for (int reg = 0; reg < 4; ++reg) {
        y[drow[tt][reg] + col] = x[drow[tt][reg] + col] + acc[nt][tt][reg] + bias;
      }
  }
}

// ---- K6: conv3x3 192->64 + GELU via MFMA implicit GEMM ---------------------
__global__ __launch_bounds__(256) void k_conv1m(const bf16* __restrict__ xn,
                                                const bf16* __restrict__ wT1,
                                                const float* __restrict__ c1b,
                                                bf16* __restrict__ cv1) {
  int bi = blockIdx.x;
  int seg = bi & 1, hh = (bi >> 1) & 127, b = bi >> 8;
  int px0 = seg * 64;
  int wave = threadIdx.x >> 6, lane = threadIdx.x & 63;
  int lm = lane & 15, lq = lane >> 4;
  int oc = wave * 16 + lm;
  float4v acc[4];
#pragma unroll
  for (int t = 0; t < 4; ++t) acc[t] = (float4v){0.f, 0.f, 0.f, 0.f};
#pragma unroll
  for (int tap = 0; tap < 9; ++tap) {
    int kh = tap / 3, kw = tap % 3;
    int gh = hh + kh - 1;
    bool rowok = ((unsigned)gh < 128u);
    const bf16* wrow = wT1 + ((size_t)tap * 64 + oc) * CC + lq * 8;
    const bf16* xrow = xn + ((size_t)b * HWPIX + (size_t)gh * WWID) * CC + lq * 8;
#pragma unroll
    for (int ks = 0; ks < 6; ++ks) {
      short8 bfrag = *(const short8*)(wrow + ks * 32);
#pragma unroll
      for (int t = 0; t < 4; ++t) {
        int px = px0 + t * 16 + lm + kw - 1;
        short8 afrag = ld8z(xrow + (size_t)px * CC + ks * 32,
                            rowok && ((unsigned)px < 128u));
        acc[t] = __builtin_amdgcn_mfma_f32_16x16x32_bf16(afrag, bfrag, acc[t], 0, 0, 0);
      }
    }
  }
  float bias = c1b[oc];
#pragma unroll
  for (int t = 0; t < 4; ++t) {
    int pxb = px0 + t * 16 + lq * 4;
    size_t base = ((size_t)b * HWPIX + (size_t)hh * WWID + pxb) * 64 + oc;
    cv1[base]       = f2b(gelu_exact(acc[t][0] + bias));
    cv1[base + 64]  = f2b(gelu_exact(acc[t][1] + bias));
    cv1[base + 128] = f2b(gelu_exact(acc[t][2] + bias));
    cv1[base + 192] = f2b(gelu_exact(acc[t][3] + bias));
  }
}

// ---- K7: conv3x3 64->192 + bias via MFMA implicit GEMM ---------------------
__global__ __launch_bounds__(256) void k_conv2m(const bf16* __restrict__ cv1,
                                                const bf16* __restrict__ wT2,
                                                const float* __restrict__ c2b,
                                                bf16* __restrict__ cv2) {
  int bi = blockIdx.x;
  int seg = bi & 1, hh = (bi >> 1) & 127, b = bi >> 8;
  int px0 = seg * 64;
  int wave = threadIdx.x >> 6, lane = threadIdx.x & 63;
  int lm = lane & 15, lq = lane >> 4;
  float4v acc[3][4];
#pragma unroll
  for (int nt = 0; nt < 3; ++nt)
#pragma unroll
    for (int t = 0; t < 4; ++t) acc[nt][t] = (float4v){0.f, 0.f, 0.f, 0.f};
#pragma unroll
  for (int tap = 0; tap < 9; ++tap) {
    int kh = tap / 3, kw = tap % 3;
    int gh = hh + kh - 1;
    bool rowok = ((unsigned)gh < 128u);
    const bf16* xrow = cv1 + ((size_t)b * HWPIX + (size_t)gh * WWID) * 64 + lq * 8;
#pragma unroll
    for (int ks = 0; ks < 2; ++ks) {
      short8 bfrag[3];
#pragma unroll
      for (int nt = 0; nt < 3; ++nt) {
        int oc = wave * 48 + nt * 16 + lm;
        bfrag[nt] = *(const short8*)(wT2 + ((size_t)tap * 192 + oc) * 64 + ks * 32 + lq * 8);
      }
#pragma unroll
      for (int t = 0; t < 4; ++t) {
        int px = px0 + t * 16 + lm + kw - 1;
        short8 afrag = ld8z(xrow + (size_t)px * 64 + ks * 32,
                            rowok && ((unsigned)px < 128u));
#pragma unroll
        for (int nt = 0; nt < 3; ++nt)
          acc[nt][t] = __builtin_amdgcn_mfma_f32_16x16x32_bf16(afrag, bfrag[nt], acc[nt][t], 0, 0, 0);
      }
    }
  }
#pragma unroll
  for (int nt = 0; nt < 3; ++nt) {
    int oc = wave * 48 + nt * 16 + lm;
    float bias = c2b[oc];
#pragma unroll
    for (int t = 0; t < 4; ++t) {
      int pxb = px0 + t * 16 + lq * 4;
      size_t base = ((size_t)b * HWPIX + (size_t)hh * WWID + pxb) * CC + oc;
      cv2[base]           = f2b(acc[nt][t][0] + bias);
      cv2[base + CC]      = f2b(acc[nt][t][1] + bias);
      cv2[base + 2 * CC]  = f2b(acc[nt][t][2] + bias);
      cv2[base + 3 * CC]  = f2b(acc[nt][t][3] + bias);
    }
  }
}

// ---------------- K8: global average pool (sum into pooled, pre-zeroed) ----
__global__ __launch_bounds__(192) void k_pool(const bf16* __restrict__ cv2,
                                              float* __restrict__ pooled) {
  int t = threadIdx.x;                        // channel
  int b = blockIdx.x >> 7;
  int pc = blockIdx.x & 127;                  // 128-pixel chunk
  const bf16* base = cv2 + ((size_t)b * HWPIX + (size_t)pc * 128) * CC + t;
  float s = 0.f;
#pragma unroll 4
  for (int p = 0; p < 128; ++p) s += b2f(base[(size_t)p * CC]);
  atomicAdd(&pooled[b * CC + t], s);
}

// ---------------- K9: channel attention weights ----------------
__global__ __launch_bounds__(192) void k_ca(const float* __restrict__ pooled,
                                            const float* __restrict__ w1,
                                            const float* __restrict__ b1,
                                            const float* __restrict__ w2,
                                            const float* __restrict__ b2,
                                            float* __restrict__ ca) {
  __shared__ float pld[CC];
  __shared__ float t1[6];
  int t = threadIdx.x, b = blockIdx.x;
  pld[t] = pooled[b * CC + t] * (1.0f / HWPIX);
  __syncthreads();
  if (t < 6) {
    float s = b1[t];
    for (int c = 0; c < CC; ++c) s += pld[c] * w1[c * 6 + t];
    t1[t] = fmaxf(s, 0.f);
  }
  __syncthreads();
  float s = b2[t];
#pragma unroll
  for (int k = 0; k < 6; ++k) s += t1[k] * w2[k * CC + t];
  ca[b * CC + t] = 1.f / (1.f + __expf(-s));
}

// --- K10: LN2 with conv-branch fold: yn = LN(y + cv2*ca*0.01) bf16 ---------
__global__ __launch_bounds__(256) void k_ln2(const float* __restrict__ y,
                                             const bf16* __restrict__ cv2,
                                             const float* __restrict__ ca,
                                             const float* __restrict__ g2,
                                             const float* __restrict__ b2,
                                             bf16* __restrict__ yn) {
  int wv = threadIdx.x >> 6, lane = threadIdx.x & 63;
  int tok = blockIdx.x * 4 + wv;
  const float* cab = ca + (tok >> 14) * CC;
  size_t row = (size_t)tok * CC;
  float v0 = y[row + lane]       + b2f(cv2[row + lane])       * cab[lane]       * CONV_SC;
  float v1 = y[row + lane + 64]  + b2f(cv2[row + lane + 64])  * cab[lane + 64]  * CONV_SC;
  float v2 = y[row + lane + 128] + b2f(cv2[row + lane + 128]) * cab[lane + 128] * CONV_SC;
  float s = v0 + v1 + v2, ss = v0 * v0 + v1 * v1 + v2 * v2;
#pragma unroll
  for (int off = 1; off < 64; off <<= 1) {
    s += __shfl_xor(s, off, 64);
    ss += __shfl_xor(ss, off, 64);
  }
  float mean = s * (1.0f / CC);
  float rstd = rsqrtf(ss * (1.0f / CC) - mean * mean + 1e-5f);
  yn[row + lane]       = f2b((v0 - mean) * rstd * g2[lane]       + b2[lane]);
  yn[row + lane + 64]  = f2b((v1 - mean) * rstd * g2[lane + 64]  + b2[lane + 64]);
  yn[row + lane + 128] = f2b((v2 - mean) * rstd * g2[lane + 128] + b2[lane + 128]);
}

// --- K11a: fc1 weight-stationary: h = GELU(yn @ fc1 + b) --------------------
// grid 512 = 4 col-panels (cg) x 128 token-blocks (tb, 512 tokens).
// Panel wF1[cg*192..+192)[192] = 73,728 B is CONTIGUOUS in wF1 -> staged once
// by a linear global_load_lds memcpy (source XOR-swizzled at 16B granularity
// with (row&7); LDS stays linear per rule #21). Wave's 18 weight frags
// hoisted to 72 VGPR, then a barrier-free loop over 32 token tiles.
__global__ __launch_bounds__(256, 2) void k_fc1ws(const bf16* __restrict__ yn,
                                                  const bf16* __restrict__ wF1,
                                                  const float* __restrict__ fb1,
                                                  bf16* __restrict__ h) {
  __shared__ unsigned short wl[192 * 192];   // 73,728 B
  int cg = blockIdx.x & 3, tb = blockIdx.x >> 2;
  int tid = threadIdx.x;
  int wave = tid >> 6, lane = tid & 63;
  int lm = lane & 15, lq = lane >> 4;

  const char* src = (const char*)wF1 + (size_t)cg * 73728;
#pragma unroll
  for (int j = 0; j < 18; ++j) {
    int ci = j * 256 + tid;                  // 16B-chunk index 0..4607
    int r = ci / 24, c = ci - r * 24;        // row 0..191, chunk 0..23
    glds16(src + (size_t)r * 384 + ((c ^ (r & 7)) << 4),
           (char*)wl + (size_t)(j * 256 + wave * 64) * 16);
  }
  __syncthreads();

  // hoist wave's B-frags (cols wave*48 + nt*16 + lm) -- one-time LDS reads
  short8 wfr[3][6];
#pragma unroll
  for (int nt = 0; nt < 3; ++nt) {
    int rl = wave * 48 + nt * 16 + lm;
#pragma unroll
    for (int ks = 0; ks < 6; ++ks)
      wfr[nt][ks] = *(const short8*)&wl[rl * 192 + (((ks * 4 + lq) ^ (rl & 7)) << 3)];
  }
  float4 b4[3];
#pragma unroll
  for (int nt = 0; nt < 3; ++nt)
    b4[nt] = *(const float4*)(fb1 + cg * 192 + wave * 48 + nt * 16 + lq * 4);

  int tok0b = tb * 512;
#pragma unroll 2
  for (int t = 0; t < 32; ++t) {
    int tok0 = tok0b + t * 16;
    const bf16* arow = yn + (size_t)(tok0 + lm) * CC + lq * 8;
    float4v acc[3];
#pragma unroll
    for (int nt = 0; nt < 3; ++nt) acc[nt] = (float4v){0.f, 0.f, 0.f, 0.f};
#pragma unroll
    for (int ks = 0; ks < 6; ++ks) {
      short8 tf = *(const short8*)(arow + ks * 32);
#pragma unroll
      for (int nt = 0; nt < 3; ++nt)
        acc[nt] = __builtin_amdgcn_mfma_f32_16x16x32_bf16(wfr[nt][ks], tf, acc[nt], 0, 0, 0);
    }
    bf16* hrow = h + (size_t)(tok0 + lm) * 768 + cg * 192 + wave * 48 + lq * 4;
#pragma unroll
    for (int nt = 0; nt < 3; ++nt) {
      unsigned short u0 = f2bu(gelu_exact(acc[nt][0] + b4[nt].x));
      unsigned short u1 = f2bu(gelu_exact(acc[nt][1] + b4[nt].y));
      unsigned short u2 = f2bu(gelu_exact(acc[nt][2] + b4[nt].z));
      unsigned short u3 = f2bu(gelu_exact(acc[nt][3] + b4[nt].w));
      uint2 pk;
      pk.x = (unsigned)u0 | ((unsigned)u1 << 16);
      pk.y = (unsigned)u2 | ((unsigned)u3 << 16);
      *(uint2*)(hrow + nt * 16) = pk;
    }
  }
}

// --- K11b: fc2 via m97-style double-buffered LDS GEMM + residual epilogue ---
// grid 512 (2 blocks/CU, whole grid co-resident), block 256 (4 waves).
// Tile: 128 tokens x ALL 192 cols, BK=32, 24 K-steps. Per step: 5 glds16
// issues/thread stage ha (8KB, h tile) + wbt (12KB, wF2 tile) into buf[nxt];
// each wave ds_reads 2 A-frags + 12 B-frags from buf[cur] and does 24 MFMA
// (acc[2][12] = 96 VGPR cannot be rematerialized -> forces real regalloc);
// ONE __syncthreads per step (drains vmcnt+lgkm = the m97 barrier). h read
// once (100 MB); wF2 L2-resident. LDS 40,960 B.
__global__ __launch_bounds__(256, 2) void k_fc2m(const bf16* __restrict__ h,
                                                 const bf16* __restrict__ wF2,
                                                 const float* __restrict__ fb2,
                                                 const float* __restrict__ y,
                                                 const bf16* __restrict__ cv2,
                                                 const float* __restrict__ ca,
                                                 float* __restrict__ out) {
  __shared__ unsigned short ha[2][4096];   // [128 tok][32 k] bf16, 8,192 B/buf
  __shared__ unsigned short wbt[2][6144];  // [192 col][32 k] bf16, 12,288 B/buf
  int r0 = blockIdx.x * 128;
  int tid = threadIdx.x;
  int wave = tid >> 6, lane = tid & 63;
  int lm = lane & 15, lq = lane >> 4;

  const char* hsrc = (const char*)(h + (size_t)r0 * 768);
  const char* wsrc = (const char*)wF2;

  float4v acc[2][12];
#pragma unroll
  for (int mt = 0; mt < 2; ++mt)
#pragma unroll
    for (int nt = 0; nt < 12; ++nt) acc[mt][nt] = (float4v){0.f, 0.f, 0.f, 0.f};

  // stage K-chunk kc into buffer b (linear LDS, per m97: no swizzle)
  auto stage = [&](int kc, int b) {
    int k0b = kc * 64;                     // byte offset of k-chunk in a row
#pragma unroll
    for (int j = 0; j < 2; ++j) {          // ha: 512 x 16B chunks
      int c = j * 256 + tid;               // row=c>>2 (x1536B), koff=c&3 (x16B)
      glds16(hsrc + (size_t)(c >> 2) * 1536 + k0b + (c & 3) * 16,
             (char*)&ha[b][0] + (j * 256 + wave * 64) * 16);
    }
#pragma unroll
    for (int j = 0; j < 3; ++j) {          // wbt: 768 x 16B chunks
      int c = j * 256 + tid;               // col=c>>2, koff=c&3
      glds16(wsrc + (size_t)(c >> 2) * 1536 + k0b + (c & 3) * 16,
             (char*)&wbt[b][0] + (j * 256 + wave * 64) * 16);
    }
  };

  stage(0, 0);
  __syncthreads();
#pragma unroll 1
  for (int kc = 0; kc < 24; ++kc) {
    int cur = kc & 1;
    if (kc < 23) stage(kc + 1, cur ^ 1);
    short8 af[2], bf[12];
#pragma unroll
    for (int mt = 0; mt < 2; ++mt)
      af[mt] = *(const short8*)&ha[cur][(wave * 32 + mt * 16 + lm) * 32 + lq * 8];
#pragma unroll
    for (int nt = 0; nt < 12; ++nt)
      bf[nt] = *(const short8*)&wbt[cur][(nt * 16 + lm) * 32 + lq * 8];
#pragma unroll
    for (int mt = 0; mt < 2; ++mt)
#pragma unroll
      for (int nt = 0; nt < 12; ++nt)
        acc[mt][nt] = __builtin_amdgcn_mfma_f32_16x16x32_bf16(af[mt], bf[nt], acc[mt][nt], 0, 0, 0);
    __syncthreads();
  }

  // epilogue: out = acc + y + cv2*ca*0.01 + bias
  const float* cab = ca + (r0 >> 14) * CC;
#pragma unroll
  for (int nt = 0; nt < 12; ++nt) {
    int col = nt * 16 + lm;
    float bias = fb2[col];
    float cas = cab[col] * CONV_SC;
#pragma unroll
    for (int mt = 0; mt < 2; ++mt) {
#pragma unroll
      for (int reg = 0; reg < 4; ++reg) {
        int tok = r0 + wave * 32 + mt * 16 + lq * 4 + reg;
        size_t idx = (size_t)tok * CC + col;
        out[idx] = y[idx] + b2f(cv2[idx]) * cas + acc[mt][nt][reg] + bias;
      }
    }
  }
}

extern "C" void kernel_launch(void* const* d_in, const int* in_sizes, int n_in,
                              void* d_out, int out_size, void* d_ws, size_t ws_size,
                              hipStream_t stream) {
  const float* x      = (const float*)d_in[0];
  const float* qkv_w  = (const float*)d_in[1];
  const float* qkv_b  = (const float*)d_in[2];
  const float* proj_w = (const float*)d_in[3];
  const float* proj_b = (const float*)d_in[4];
  const float* rpb    = (const float*)d_in[5];
  const float* n1w    = (const float*)d_in[6];
  const float* n1b    = (const float*)d_in[7];
  const float* n2w    = (const float*)d_in[8];
  const float* n2b    = (const float*)d_in[9];
  const float* c1w    = (const float*)d_in[10];
  const float* c1b    = (const float*)d_in[11];
  const float* c2w    = (const float*)d_in[12];
  const float* c2b    = (const float*)d_in[13];
  const float* ca1w   = (const float*)d_in[14];
  const float* ca1b   = (const float*)d_in[15];
  const float* ca2w   = (const float*)d_in[16];
  const float* ca2b   = (const float*)d_in[17];
  const float* fc1w   = (const float*)d_in[18];
  const float* fc1b   = (const float*)d_in[19];
  const float* fc2w   = (const float*)d_in[20];
  const float* fc2b   = (const float*)d_in[21];
  const int*   rpi    = (const int*)d_in[22];
  (void)in_sizes; (void)n_in; (void)out_size; (void)ws_size;

  // ---- workspace layout: peak ~212.6 MB (< 256 MiB) ----
  char* wsb = (char*)d_ws;
  bf16*  xn    = (bf16*)(wsb + 0);            // 25,165,824
  bf16*  yn    = (bf16*)(wsb + 0);            // alias xn (dead after conv1m)
  float* biasQ = (float*)(wsb + 25165824);    //  1,572,864
  bf16*  Qg    = (bf16*)(wsb + 26738688);     // 25,165,824
  bf16*  Kg    = (bf16*)(wsb + 51904512);     // 25,165,824
  bf16*  Vg    = (bf16*)(wsb + 77070336);     // 25,165,824
  bf16*  AO    = (bf16*)(wsb + 102236160);    // 25,165,824
  bf16*  hbuf  = (bf16*)(wsb + 26738688);     // 100,663,296 alias Qg..AO (dead after proj2)
  float* y     = (float*)(wsb + 127401984);   // 50,331,648
  bf16*  cv1   = (bf16*)(wsb + 177733632);    //  8,388,608
  bf16*  cv2   = (bf16*)(wsb + 186122240);    // 25,165,824
  float* pool  = (float*)(wsb + 211288064);   //      3,072
  float* cavec = (float*)(wsb + 211291136);   //      3,072
  bf16*  wT1   = (bf16*)(wsb + 211294208);    //    221,184  [9][64][192]
  bf16*  wT2   = (bf16*)(wsb + 211515392);    //    221,184  [9][192][64]
  bf16*  wF1   = (bf16*)(wsb + 211736576);    //    294,912  [768][192]
  bf16*  wF2   = (bf16*)(wsb + 212031488);    //    294,912  [192][768]
  bf16*  wQv   = (bf16*)(wsb + 212326400);    //    221,184  [576][192]
  bf16*  wP    = (bf16*)(wsb + 212547584);    //     73,728  [192][192]
  float* out   = (float*)d_out;               // end 212,621,312

  k_ln1<<<TTOT / 4, 256, 0, stream>>>(x, n1w, n1b, xn);
  k_biasq<<<NHEAD * NTOK, 256, 0, stream>>>(rpi, rpb, biasQ);
  k_wprep<<<432, 256, 0, stream>>>(c1w, c2w, wT1, wT2);
  k_wprep2<<<576, 256, 0, stream>>>(fc1w, fc2w, wF1, wF2);
  k_wprep3<<<576, 256, 0, stream>>>(qkv_w, proj_w, wQv, wP);
  k_qkvg2<<<TTOT / 32, 256, 0, stream>>>(xn, wQv, qkv_b, Qg, Kg, Vg);
  k_attn2<<<BB * 64 * NHEAD * 2, 256, 0, stream>>>(Qg, Kg, Vg, biasQ, AO);
  k_proj2<<<TTOT / 32, 256, 0, stream>>>(AO, wP, proj_b, x, y);
  k_conv1m<<<1024, 256, 0, stream>>>(xn, wT1, c1b, cv1);
  k_conv2m<<<1024, 256, 0, stream>>>(cv1, wT2, c2b, cv2);
  hipMemsetAsync(pool, 0, BB * CC * sizeof(float), stream);
  k_pool<<<512, 192, 0, stream>>>(cv2, pool);
  k_ca<<<BB, 192, 0, stream>>>(pool, ca1w, ca1b, ca2w, ca2b, cavec);
  k_ln2<<<TTOT / 4, 256, 0, stream>>>(y, cv2, cavec, n2w, n2b, yn);
  k_fc1ws<<<512, 256, 0, stream>>>(yn, wF1, fc1b, hbuf);
  k_fc2m<<<512, 256, 0, stream>>>(hbuf, wF2, fc2b, y, cv2, cavec, out);
}

// Round 9
// 590.709 us; speedup vs baseline: 1.3995x; 1.1975x over previous
//
#include <hip/hip_runtime.h>
#include <hip/hip_bf16.h>
#include <cstdint>
#include <cstddef>

#define BB 4
#define CC 192
#define NHEAD 6
#define WSZ 16
#define SSH 8
#define NTOK 256
#define HD 32
#define HWPIX 16384
#define TTOT 65536
#define WWID 128
#define SCALE_Q 0.17677669529663687f
#define CONV_SC 0.01f
#define PSTR 264   // attn LDS row stride (shorts): 16B-aligned, <=2-way banks

typedef __hip_bfloat16 bf16;
typedef __attribute__((ext_vector_type(8))) short short8;
typedef __attribute__((ext_vector_type(4))) float float4v;

__device__ __forceinline__ float b2f(bf16 v) { return __bfloat162float(v); }
__device__ __forceinline__ bf16 f2b(float v) { return __float2bfloat16(v); }
__device__ __forceinline__ unsigned short f2bu(float f) {
  bf16 h = __float2bfloat16(f);
  return *reinterpret_cast<unsigned short*>(&h);
}
__device__ __forceinline__ float gelu_exact(float x) {
  return 0.5f * x * (1.0f + erff(x * 0.7071067811865475f));
}
__device__ __forceinline__ short8 ld8z(const bf16* p, bool ok) {
  if (ok) return *(const short8*)p;
  short8 z = {0, 0, 0, 0, 0, 0, 0, 0};
  return z;
}
// async global->LDS 16B per lane: LDS dest = wave-uniform base + lane*16,
// global source is per-lane. size must be literal 16.
__device__ __forceinline__ void glds16(const void* g, void* l) {
  __builtin_amdgcn_global_load_lds(
      (const __attribute__((address_space(1))) unsigned int*)g,
      (__attribute__((address_space(3))) unsigned int*)l, 16, 0, 0);
}

// ---------------- K1: LayerNorm1 (x fp32 -> xn bf16). 1 wave per token -----
__global__ __launch_bounds__(256) void k_ln1(const float* __restrict__ x,
                                             const float* __restrict__ g,
                                             const float* __restrict__ b,
                                             bf16* __restrict__ xn) {
  int wv = threadIdx.x >> 6, lane = threadIdx.x & 63;
  int tok = blockIdx.x * 4 + wv;
  size_t row = (size_t)tok * CC;
  float v0 = x[row + lane], v1 = x[row + lane + 64], v2 = x[row + lane + 128];
  float s = v0 + v1 + v2, ss = v0 * v0 + v1 * v1 + v2 * v2;
#pragma unroll
  for (int off = 1; off < 64; off <<= 1) {
    s += __shfl_xor(s, off, 64);
    ss += __shfl_xor(ss, off, 64);
  }
  float mean = s * (1.0f / CC);
  float rstd = rsqrtf(ss * (1.0f / CC) - mean * mean + 1e-5f);
  xn[row + lane]       = f2b((v0 - mean) * rstd * g[lane]       + b[lane]);
  xn[row + lane + 64]  = f2b((v1 - mean) * rstd * g[lane + 64]  + b[lane + 64]);
  xn[row + lane + 128] = f2b((v2 - mean) * rstd * g[lane + 128] + b[lane + 128]);
}

// ------------- K2: bias gather biasQ[h][query][key] (fp32) ------------------
__global__ __launch_bounds__(256) void k_biasq(const int* __restrict__ rpi,
                                               const float* __restrict__ rpb,
                                               float* __restrict__ biasQ) {
  int k = threadIdx.x;
  int h = blockIdx.x >> 8;
  int q = blockIdx.x & 255;
  biasQ[(size_t)blockIdx.x * 256 + k] = rpb[rpi[q * 256 + k] * NHEAD + h];
}

// ------- K2b: conv weight transpose to [tap][oc][ci] bf16 -------------------
__global__ __launch_bounds__(256) void k_wprep(const float* __restrict__ c1w,
                                               const float* __restrict__ c2w,
                                               bf16* __restrict__ wT1,
                                               bf16* __restrict__ wT2) {
  int i = blockIdx.x * 256 + threadIdx.x;   // 0 .. 110591
  {
    int tap = i / (64 * 192); int r = i % (64 * 192);
    int oc = r / 192, ci = r % 192;
    wT1[i] = f2b(c1w[(size_t)(tap * 192 + ci) * 64 + oc]);
  }
  {
    int tap = i / (192 * 64); int r = i % (192 * 64);
    int oc = r / 64, ci = r % 64;
    wT2[i] = f2b(c2w[(size_t)(tap * 64 + ci) * 192 + oc]);
  }
}

// ------- K2c: MLP weight transpose to n-major bf16 --------------------------
__global__ __launch_bounds__(256) void k_wprep2(const float* __restrict__ fc1w,
                                                const float* __restrict__ fc2w,
                                                bf16* __restrict__ wF1,
                                                bf16* __restrict__ wF2) {
  int i = blockIdx.x * 256 + threadIdx.x;   // 0 .. 147455
  {
    int n = i / 192, k = i % 192;           // wF1[n][k], n<768 k<192
    wF1[i] = f2b(fc1w[(size_t)k * 768 + n]);
  }
  {
    int n = i / 768, k = i % 768;           // wF2[n][k], n<192 k<768
    wF2[i] = f2b(fc2w[(size_t)k * 192 + n]);
  }
}

// ------- K2d: qkv/proj weight transpose to n-major bf16 ---------------------
__global__ __launch_bounds__(256) void k_wprep3(const float* __restrict__ qkvw,
                                                const float* __restrict__ projw,
                                                bf16* __restrict__ wQv,
                                                bf16* __restrict__ wP) {
  int i = blockIdx.x * 256 + threadIdx.x;   // 0 .. 147455 (grid 576)
  if (i < 576 * 192) {
    int n = i / 192, k = i % 192;           // wQv[n][k], n<576
    wQv[i] = f2b(qkvw[(size_t)k * 576 + n]);
  }
  if (i < 192 * 192) {
    int n = i / 192, k = i % 192;           // wP[n][k]
    wP[i] = f2b(projw[(size_t)k * 192 + n]);
  }
}

// --- K3: QKV GEMM via MFMA (N=576, K=192), gathered scatter store -----------
// grid TTOT/32, block 256 (4 waves). Wave w: cols w*144..+143 (9 tiles).
// 2 token-tiles per block: each weight fragment feeds 2 MFMA.
__global__ __launch_bounds__(256) void k_qkvg2(const bf16* __restrict__ xn,
                                               const bf16* __restrict__ wQv,
                                               const float* __restrict__ qb,
                                               bf16* __restrict__ Qg,
                                               bf16* __restrict__ Kg,
                                               bf16* __restrict__ Vg) {
  int tok0 = blockIdx.x * 32;
  int wave = threadIdx.x >> 6, lane = threadIdx.x & 63;
  int lm = lane & 15, lq = lane >> 4;
  const bf16* arow0 = xn + (size_t)(tok0 + lm) * CC + lq * 8;
  const bf16* arow1 = xn + (size_t)(tok0 + 16 + lm) * CC + lq * 8;
  float4v acc[9][2];
#pragma unroll
  for (int nt = 0; nt < 9; ++nt)
#pragma unroll
    for (int tt = 0; tt < 2; ++tt) acc[nt][tt] = (float4v){0.f, 0.f, 0.f, 0.f};
#pragma unroll
  for (int ks = 0; ks < 6; ++ks) {
    short8 af0 = *(const short8*)(arow0 + ks * 32);
    short8 af1 = *(const short8*)(arow1 + ks * 32);
#pragma unroll
    for (int nt = 0; nt < 9; ++nt) {
      int col = wave * 144 + nt * 16 + lm;
      short8 bfrag = *(const short8*)(wQv + (size_t)col * CC + ks * 32 + lq * 8);
      acc[nt][0] = __builtin_amdgcn_mfma_f32_16x16x32_bf16(af0, bfrag, acc[nt][0], 0, 0, 0);
      acc[nt][1] = __builtin_amdgcn_mfma_f32_16x16x32_bf16(af1, bfrag, acc[nt][1], 0, 0, 0);
    }
  }
  // per-(tt,reg) token -> gathered (window,head) coords
  size_t base[2][4];
#pragma unroll
  for (int tt = 0; tt < 2; ++tt)
#pragma unroll
    for (int reg = 0; reg < 4; ++reg) {
      int tg = tok0 + tt * 16 + lq * 4 + reg;
      int b = tg >> 14;
      int pix = tg & 16383;
      int gh = pix >> 7, gw = pix & 127;
      int hs = (gh + 120) & 127, wsx = (gw + 120) & 127;
      int wdx = (b << 6) + ((hs >> 4) << 3) + (wsx >> 4);
      int ndx = ((hs & 15) << 4) + (wsx & 15);
      base[tt][reg] = ((size_t)wdx * NHEAD) * NTOK * HD + (size_t)ndx * HD;
    }
#pragma unroll
  for (int nt = 0; nt < 9; ++nt) {
    int col = wave * 144 + nt * 16 + lm;
    float bias = qb[col];
    int sect = col / 192, within = col - sect * 192;
    int head = within >> 5, d = within & 31;
    bf16* dst = (sect == 0) ? Qg : (sect == 1) ? Kg : Vg;
    float scale = (sect == 0) ? SCALE_Q : 1.f;
#pragma unroll
    for (int tt = 0; tt < 2; ++tt)
#pragma unroll
      for (int reg = 0; reg < 4; ++reg) {
        dst[base[tt][reg] + (size_t)head * NTOK * HD + d] =
            f2b((acc[nt][tt][reg] + bias) * scale);
      }
  }
}

// --- K4: windowed attention via MFMA --------------------------------------
// grid = 1536*2 (wh, query-half). block 256 = 4 waves x 32 queries.
// S = Q*K^T (MFMA), full softmax per 16-row tile, P->LDS bf16, O = P*V (MFMA).
__global__ __launch_bounds__(256) void k_attn2(const bf16* __restrict__ Qg,
                                               const bf16* __restrict__ Kg,
                                               const bf16* __restrict__ Vg,
                                               const float* __restrict__ biasQ,
                                               bf16* __restrict__ AO) {
  __shared__ unsigned short PTw[4][16 * PSTR];  // 33,792 B (wave-private P tiles)
  __shared__ unsigned short VT[32 * PSTR];      // 16,896 B (V transposed)
  int wh = blockIdx.x >> 1, half = blockIdx.x & 1;
  int wdx = wh / NHEAD, h = wh - wdx * NHEAD;
  int wl = wdx & 63;
  int wr = wl >> 3, wc = wl & 7;
  int tid = threadIdx.x;
  int wave = tid >> 6, lane = tid & 63;
  int lm = lane & 15, lq = lane >> 4;
  int q0 = half * 128;

  // stage V^T: thread tid handles key row tid
  {
    const uint4* vp = (const uint4*)(Vg + ((size_t)wh * NTOK + tid) * HD);
    uint4 vv[4] = {vp[0], vp[1], vp[2], vp[3]};
#pragma unroll
    for (int i = 0; i < 4; ++i) {
      unsigned arr[4] = {vv[i].x, vv[i].y, vv[i].z, vv[i].w};
#pragma unroll
      for (int j = 0; j < 4; ++j) {
        int d = i * 8 + j * 2;
        VT[d * PSTR + tid]       = (unsigned short)(arr[j] & 0xffffu);
        VT[(d + 1) * PSTR + tid] = (unsigned short)(arr[j] >> 16);
      }
    }
  }
  __syncthreads();

  int wsk = (wc << 4) + lm;                       // lane's key col (w coord)
  int ridk_w = (wsk >= 112) + (wsk >= 120);
  unsigned short* PT = &PTw[wave][0];

  float4v oacc[2][2];
#pragma unroll
  for (int rt = 0; rt < 2; ++rt)
#pragma unroll
    for (int c2 = 0; c2 < 2; ++c2) oacc[rt][c2] = (float4v){0.f, 0.f, 0.f, 0.f};
  float linv[2][4];

#pragma unroll
  for (int rt = 0; rt < 2; ++rt) {
    int qrow = q0 + wave * 32 + rt * 16;
    short8 aq = *(const short8*)(Qg + ((size_t)wh * NTOK + qrow + lm) * HD + lq * 8);
    float4v sacc[16];
#pragma unroll
    for (int ct = 0; ct < 16; ++ct) sacc[ct] = (float4v){0.f, 0.f, 0.f, 0.f};
#pragma unroll
    for (int ct = 0; ct < 16; ++ct) {
      short8 kf = *(const short8*)(Kg + ((size_t)wh * NTOK + ct * 16 + lm) * HD + lq * 8);
      sacc[ct] = __builtin_amdgcn_mfma_f32_16x16x32_bf16(aq, kf, sacc[ct], 0, 0, 0);
    }
    // softmax over 256 keys, rows lq*4+reg of this 16-row tile
#pragma unroll
    for (int reg = 0; reg < 4; ++reg) {
      int nq = qrow + lq * 4 + reg;
      int hsq = (wr << 4) + (nq >> 4), wsq = (wc << 4) + (nq & 15);
      int ridq = ((hsq >= 112) + (hsq >= 120)) * 3 + ((wsq >= 112) + (wsq >= 120));
      const float* bq = biasQ + ((size_t)(h * 256 + nq)) * 256 + lm;
      float sv[16];
      float mx = -1.0e30f;
#pragma unroll
      for (int ct = 0; ct < 16; ++ct) {
        int hsk = (wr << 4) + ct;
        int ridk = ((hsk >= 112) + (hsk >= 120)) * 3 + ridk_w;
        float s = sacc[ct][reg] + bq[ct * 16] + ((ridk != ridq) ? -100.f : 0.f);
        sv[ct] = s;
        mx = fmaxf(mx, s);
      }
#pragma unroll
      for (int off = 1; off < 16; off <<= 1) mx = fmaxf(mx, __shfl_xor(mx, off, 64));
      float l = 0.f;
#pragma unroll
      for (int ct = 0; ct < 16; ++ct) {
        float p = __expf(sv[ct] - mx);
        l += p;
        PT[(lq * 4 + reg) * PSTR + ct * 16 + lm] = f2bu(p);
      }
#pragma unroll
      for (int off = 1; off < 16; off <<= 1) l += __shfl_xor(l, off, 64);
      linv[rt][reg] = 1.f / l;
    }
    // PV for this row tile: A = P rows (wave-private, in-wave LDS ordering)
#pragma unroll
    for (int kb = 0; kb < 8; ++kb) {
      short8 pf = *(const short8*)&PT[lm * PSTR + kb * 32 + lq * 8];
#pragma unroll
      for (int c2 = 0; c2 < 2; ++c2) {
        short8 vf = *(const short8*)&VT[(c2 * 16 + lm) * PSTR + kb * 32 + lq * 8];
        oacc[rt][c2] = __builtin_amdgcn_mfma_f32_16x16x32_bf16(pf, vf, oacc[rt][c2], 0, 0, 0);
      }
    }
  }
  // write AO
#pragma unroll
  for (int rt = 0; rt < 2; ++rt)
#pragma unroll
    for (int c2 = 0; c2 < 2; ++c2) {
      int d = c2 * 16 + lm;
#pragma unroll
      for (int reg = 0; reg < 4; ++reg) {
        int nq = q0 + wave * 32 + rt * 16 + lq * 4 + reg;
        AO[((size_t)wdx * NTOK + nq) * CC + h * HD + d] =
            f2b(oacc[rt][c2][reg] * linv[rt][reg]);
      }
    }
}

// --- K5: proj GEMM via MFMA (N=192, K=192) + shift-reverse + x residual -----
// grid TTOT/32 (win-order rows), block 256 (4 waves). Wave w: cols w*48..+47.
// 2 token-tiles per block: each wP fragment feeds 2 MFMA.
__global__ __launch_bounds__(256) void k_proj2(const bf16* __restrict__ AO,
                                               const bf16* __restrict__ wP,
                                               const float* __restrict__ pb,
                                               const float* __restrict__ x,
                                               float* __restrict__ y) {
  int r0 = blockIdx.x * 32;
  int wave = threadIdx.x >> 6, lane = threadIdx.x & 63;
  int lm = lane & 15, lq = lane >> 4;
  const bf16* arow0 = AO + (size_t)(r0 + lm) * CC + lq * 8;
  const bf16* arow1 = AO + (size_t)(r0 + 16 + lm) * CC + lq * 8;
  float4v acc[3][2];
#pragma unroll
  for (int nt = 0; nt < 3; ++nt)
#pragma unroll
    for (int tt = 0; tt < 2; ++tt) acc[nt][tt] = (float4v){0.f, 0.f, 0.f, 0.f};
#pragma unroll
  for (int ks = 0; ks < 6; ++ks) {
    short8 af0 = *(const short8*)(arow0 + ks * 32);
    short8 af1 = *(const short8*)(arow1 + ks * 32);
#pragma unroll
    for (int nt = 0; nt < 3; ++nt) {
      int col = wave * 48 + nt * 16 + lm;
      short8 bfrag = *(const short8*)(wP + (size_t)col * CC + ks * 32 + lq * 8);
      acc[nt][0] = __builtin_amdgcn_mfma_f32_16x16x32_bf16(af0, bfrag, acc[nt][0], 0, 0, 0);
      acc[nt][1] = __builtin_amdgcn_mfma_f32_16x16x32_bf16(af1, bfrag, acc[nt][1], 0, 0, 0);
    }
  }
  size_t drow[2][4];
#pragma unroll
  for (int tt = 0; tt < 2; ++tt)
#pragma unroll
    for (int reg = 0; reg < 4; ++reg) {
      int r = r0 + tt * 16 + lq * 4 + reg;
      int wdx = r >> 8, n = r & 255;
      int wb = wdx >> 6, wl = wdx & 63;
      int hs = ((wl >> 3) << 4) + (n >> 4);
      int wsx = ((wl & 7) << 4) + (n & 15);
      int gh = (hs + SSH) & 127, gw = (wsx + SSH) & 127;
      drow[tt][reg] = ((size_t)wb * HWPIX + (size_t)gh * WWID + gw) * CC;
    }
#pragma unroll
  for (int nt = 0; nt < 3; ++nt) {
    int col = wave * 48 + nt * 16 + lm;
    float bias = pb[col];
#pragma unroll
    for (int tt = 0; tt < 2; ++tt)
#pragma unroll
      for (int reg = 0; reg < 4; ++reg) {
        y[drow[tt][reg] + col] = x[drow[tt][reg] + col] + acc[nt][tt][reg] + bias;
      }
  }
}

// ---- K6: conv3x3 192->64 + GELU, LDS-staged input rows ---------------------
// grid BB*128 (b x row), block 512 (8 waves = 2 px-halves x 4 oc-tiles).
// 3 full xn rows staged to LDS via global_load_lds (147,456 B, 1 blk/CU);
// source XOR-swizzled (kc ^= px&7) since px stride 384B == 0 mod 128 would be
// a 16-way bank conflict; swizzled reads land 2-way (free). One barrier, then
// barrier-free main loop: 216 MFMA/wave fed from LDS; per-tap weight frags
// (6 = 24 VGPR) prefetched one tap ahead (L2-resident).
__global__ __launch_bounds__(512, 1) void k_conv1l(const bf16* __restrict__ xn,
                                                   const bf16* __restrict__ wT1,
                                                   const float* __restrict__ c1b,
                                                   bf16* __restrict__ cv1) {
  __shared__ unsigned short xs[3 * 128 * 192];   // 147,456 B
  int hh = blockIdx.x & 127, b = blockIdx.x >> 7;
  int tid = threadIdx.x;
  int wave = tid >> 6, lane = tid & 63;
  int lm = lane & 15, lq = lane >> 4;
  int ph = wave >> 2;                 // px half (0: 0-63, 1: 64-127)
  int oc = (wave & 3) * 16 + lm;

  // stage rows hh-1..hh+1 (3072 16B-chunks each)
#pragma unroll
  for (int r = 0; r < 3; ++r) {
    int gh = hh + r - 1;
    if ((unsigned)gh < 128u) {        // block-uniform
      const char* src = (const char*)(xn + (size_t)(b * HWPIX + gh * WWID) * CC);
#pragma unroll
      for (int j = 0; j < 6; ++j) {
        int c = j * 512 + tid;        // 0..3071
        int px = c / 24, kc = c - px * 24;
        glds16(src + (size_t)px * 384 + ((size_t)(kc ^ (px & 7)) << 4),
               (char*)xs + ((size_t)(r * 3072 + j * 512 + wave * 64)) * 16);
      }
    }
  }
  __syncthreads();

  float4v acc[4];
#pragma unroll
  for (int t = 0; t < 4; ++t) acc[t] = (float4v){0.f, 0.f, 0.f, 0.f};

  short8 w[6], wn[6];
#pragma unroll
  for (int ks = 0; ks < 6; ++ks)
    w[ks] = *(const short8*)(wT1 + ((size_t)oc) * CC + ks * 32 + lq * 8);
#pragma unroll
  for (int tap = 0; tap < 9; ++tap) {
    if (tap < 8) {
#pragma unroll
      for (int ks = 0; ks < 6; ++ks)
        wn[ks] = *(const short8*)(wT1 + ((size_t)((tap + 1) * 64) + oc) * CC + ks * 32 + lq * 8);
    }
    int kh = tap / 3, kw = tap % 3;
    int gh = hh + kh - 1;
    if ((unsigned)gh < 128u) {        // block-uniform skip of OOB rows
      const unsigned short* row = &xs[kh * 24576];
#pragma unroll
      for (int ks = 0; ks < 6; ++ks) {
#pragma unroll
        for (int t = 0; t < 4; ++t) {
          int px = ph * 64 + t * 16 + lm + kw - 1;
          int pxc = px < 0 ? 0 : (px > 127 ? 127 : px);
          short8 av = *(const short8*)&row[pxc * 192 + (((ks * 4 + lq) ^ (pxc & 7)) << 3)];
          short8 zz = {0, 0, 0, 0, 0, 0, 0, 0};
          short8 a = ((unsigned)px < 128u) ? av : zz;
          acc[t] = __builtin_amdgcn_mfma_f32_16x16x32_bf16(a, w[ks], acc[t], 0, 0, 0);
        }
      }
    }
#pragma unroll
    for (int ks = 0; ks < 6; ++ks) w[ks] = wn[ks];
  }
  float bias = c1b[oc];
#pragma unroll
  for (int t = 0; t < 4; ++t) {
    int pxb = ph * 64 + t * 16 + lq * 4;
    size_t base = ((size_t)b * HWPIX + (size_t)hh * WWID + pxb) * 64 + oc;
    cv1[base]       = f2b(gelu_exact(acc[t][0] + bias));
    cv1[base + 64]  = f2b(gelu_exact(acc[t][1] + bias));
    cv1[base + 128] = f2b(gelu_exact(acc[t][2] + bias));
    cv1[base + 192] = f2b(gelu_exact(acc[t][3] + bias));
  }
}

// ---- K7: conv3x3 64->192 + bias, LDS-staged input rows ---------------------
// grid BB*128, block 512 (8 waves = 2 px-halves x 4 oc-groups of 48).
// 3 cv1 rows staged (49,152 B, up to 3 blk/CU), same swizzle scheme
// (px stride 128B). 216 MFMA/wave; tap-ahead weight prefetch (6 frags).
__global__ __launch_bounds__(512, 2) void k_conv2l(const bf16* __restrict__ cv1,
                                                   const bf16* __restrict__ wT2,
                                                   const float* __restrict__ c2b,
                                                   bf16* __restrict__ cv2) {
  __shared__ unsigned short cs[3 * 128 * 64];    // 49,152 B
  int hh = blockIdx.x & 127, b = blockIdx.x >> 7;
  int tid = threadIdx.x;
  int wave = tid >> 6, lane = tid & 63;
  int lm = lane & 15, lq = lane >> 4;
  int ph = wave >> 2;                 // px half
  int og = wave & 3;                  // oc group (48 cols)

  // stage rows hh-1..hh+1 (1024 16B-chunks each)
#pragma unroll
  for (int r = 0; r < 3; ++r) {
    int gh = hh + r - 1;
    if ((unsigned)gh < 128u) {
      const char* src = (const char*)(cv1 + (size_t)(b * HWPIX + gh * WWID) * 64);
#pragma unroll
      for (int j = 0; j < 2; ++j) {
        int c = j * 512 + tid;        // 0..1023
        int px = c >> 3, kc = c & 7;
        glds16(src + (size_t)px * 128 + ((size_t)(kc ^ (px & 7)) << 4),
               (char*)cs + ((size_t)(r * 1024 + j * 512 + wave * 64)) * 16);
      }
    }
  }
  __syncthreads();

  float4v acc[3][4];
#pragma unroll
  for (int nt = 0; nt < 3; ++nt)
#pragma unroll
    for (int t = 0; t < 4; ++t) acc[nt][t] = (float4v){0.f, 0.f, 0.f, 0.f};

  short8 w[3][2], wn[3][2];
#pragma unroll
  for (int nt = 0; nt < 3; ++nt) {
    int oc = og * 48 + nt * 16 + lm;
#pragma unroll
    for (int ks = 0; ks < 2; ++ks)
      w[nt][ks] = *(const short8*)(wT2 + ((size_t)oc) * 64 + ks * 32 + lq * 8);
  }
#pragma unroll
  for (int tap = 0; tap < 9; ++tap) {
    if (tap < 8) {
#pragma unroll
      for (int nt = 0; nt < 3; ++nt) {
        int oc = og * 48 + nt * 16 + lm;
#pragma unroll
        for (int ks = 0; ks < 2; ++ks)
          wn[nt][ks] = *(const short8*)(wT2 + ((size_t)((tap + 1) * 192) + oc) * 64 + ks * 32 + lq * 8);
      }
    }
    int kh = tap / 3, kw = tap % 3;
    int gh = hh + kh - 1;
    if ((unsigned)gh < 128u) {
      const unsigned short* row = &cs[kh * 8192];
#pragma unroll
      for (int ks = 0; ks < 2; ++ks) {
#pragma unroll
        for (int t = 0; t < 4; ++t) {
          int px = ph * 64 + t * 16 + lm + kw - 1;
          int pxc = px < 0 ? 0 : (px > 127 ? 127 : px);
          short8 av = *(const short8*)&row[pxc * 64 + (((ks * 4 + lq) ^ (pxc & 7)) << 3)];
          short8 zz = {0, 0, 0, 0, 0, 0, 0, 0};
          short8 a = ((unsigned)px < 128u) ? av : zz;
#pragma unroll
          for (int nt = 0; nt < 3; ++nt)
            acc[nt][t] = __builtin_amdgcn_mfma_f32_16x16x32_bf16(a, w[nt][ks], acc[nt][t], 0, 0, 0);
        }
      }
    }
#pragma unroll
    for (int nt = 0; nt < 3; ++nt)
#pragma unroll
      for (int ks = 0; ks < 2; ++ks) w[nt][ks] = wn[nt][ks];
  }
#pragma unroll
  for (int nt = 0; nt < 3; ++nt) {
    int oc = og * 48 + nt * 16 + lm;
    float bias = c2b[oc];
#pragma unroll
    for (int t = 0; t < 4; ++t) {
      int pxb = ph * 64 + t * 16 + lq * 4;
      size_t base = ((size_t)b * HWPIX + (size_t)hh * WWID + pxb) * CC + oc;
      cv2[base]           = f2b(acc[nt][t][0] + bias);
      cv2[base + CC]      = f2b(acc[nt][t][1] + bias);
      cv2[base + 2 * CC]  = f2b(acc[nt][t][2] + bias);
      cv2[base + 3 * CC]  = f2b(acc[nt][t][3] + bias);
    }
  }
}

// ---------------- K8: global average pool (sum into pooled, pre-zeroed) ----
__global__ __launch_bounds__(192) void k_pool(const bf16* __restrict__ cv2,
                                              float* __restrict__ pooled) {
  int t = threadIdx.x;                        // channel
  int b = blockIdx.x >> 7;
  int pc = blockIdx.x & 127;                  // 128-pixel chunk
  const bf16* base = cv2 + ((size_t)b * HWPIX + (size_t)pc * 128) * CC + t;
  float s = 0.f;
#pragma unroll 4
  for (int p = 0; p < 128; ++p) s += b2f(base[(size_t)p * CC]);
  atomicAdd(&pooled[b * CC + t], s);
}

// ---------------- K9: channel attention weights ----------------
__global__ __launch_bounds__(192) void k_ca(const float* __restrict__ pooled,
                                            const float* __restrict__ w1,
                                            const float* __restrict__ b1,
                                            const float* __restrict__ w2,
                                            const float* __restrict__ b2,
                                            float* __restrict__ ca) {
  __shared__ float pld[CC];
  __shared__ float t1[6];
  int t = threadIdx.x, b = blockIdx.x;
  pld[t] = pooled[b * CC + t] * (1.0f / HWPIX);
  __syncthreads();
  if (t < 6) {
    float s = b1[t];
    for (int c = 0; c < CC; ++c) s += pld[c] * w1[c * 6 + t];
    t1[t] = fmaxf(s, 0.f);
  }
  __syncthreads();
  float s = b2[t];
#pragma unroll
  for (int k = 0; k < 6; ++k) s += t1[k] * w2[k * CC + t];
  ca[b * CC + t] = 1.f / (1.f + __expf(-s));
}

// --- K10: LN2 with conv-branch fold: yn = LN(y + cv2*ca*0.01) bf16 ---------
__global__ __launch_bounds__(256) void k_ln2(const float* __restrict__ y,
                                             const bf16* __restrict__ cv2,
                                             const float* __restrict__ ca,
                                             const float* __restrict__ g2,
                                             const float* __restrict__ b2,
                                             bf16* __restrict__ yn) {
  int wv = threadIdx.x >> 6, lane = threadIdx.x & 63;
  int tok = blockIdx.x * 4 + wv;
  const float* cab = ca + (tok >> 14) * CC;
  size_t row = (size_t)tok * CC;
  float v0 = y[row + lane]       + b2f(cv2[row + lane])       * cab[lane]       * CONV_SC;
  float v1 = y[row + lane + 64]  + b2f(cv2[row + lane + 64])  * cab[lane + 64]  * CONV_SC;
  float v2 = y[row + lane + 128] + b2f(cv2[row + lane + 128]) * cab[lane + 128] * CONV_SC;
  float s = v0 + v1 + v2, ss = v0 * v0 + v1 * v1 + v2 * v2;
#pragma unroll
  for (int off = 1; off < 64; off <<= 1) {
    s += __shfl_xor(s, off, 64);
    ss += __shfl_xor(ss, off, 64);
  }
  float mean = s * (1.0f / CC);
  float rstd = rsqrtf(ss * (1.0f / CC) - mean * mean + 1e-5f);
  yn[row + lane]       = f2b((v0 - mean) * rstd * g2[lane]       + b2[lane]);
  yn[row + lane + 64]  = f2b((v1 - mean) * rstd * g2[lane + 64]  + b2[lane + 64]);
  yn[row + lane + 128] = f2b((v2 - mean) * rstd * g2[lane + 128] + b2[lane + 128]);
}

// --- K11a: fc1 weight-stationary: h = GELU(yn @ fc1 + b) --------------------
// grid 512 = 4 col-panels (cg) x 128 token-blocks (tb, 512 tokens).
// Panel wF1[cg*192..+192)[192] = 73,728 B is CONTIGUOUS in wF1 -> staged once
// by a linear global_load_lds memcpy (source XOR-swizzled at 16B granularity
// with (row&7); LDS stays linear per rule #21). Wave's 18 weight frags
// hoisted to 72 VGPR, then a barrier-free loop over 32 token tiles.
__global__ __launch_bounds__(256, 2) void k_fc1ws(const bf16* __restrict__ yn,
                                                  const bf16* __restrict__ wF1,
                                                  const float* __restrict__ fb1,
                                                  bf16* __restrict__ h) {
  __shared__ unsigned short wl[192 * 192];   // 73,728 B
  int cg = blockIdx.x & 3, tb = blockIdx.x >> 2;
  int tid = threadIdx.x;
  int wave = tid >> 6, lane = tid & 63;
  int lm = lane & 15, lq = lane >> 4;

  const char* src = (const char*)wF1 + (size_t)cg * 73728;
#pragma unroll
  for (int j = 0; j < 18; ++j) {
    int ci = j * 256 + tid;                  // 16B-chunk index 0..4607
    int r = ci / 24, c = ci - r * 24;        // row 0..191, chunk 0..23
    glds16(src + (size_t)r * 384 + ((c ^ (r & 7)) << 4),
           (char*)wl + (size_t)(j * 256 + wave * 64) * 16);
  }
  __syncthreads();

  // hoist wave's B-frags (cols wave*48 + nt*16 + lm) -- one-time LDS reads
  short8 wfr[3][6];
#pragma unroll
  for (int nt = 0; nt < 3; ++nt) {
    int rl = wave * 48 + nt * 16 + lm;
#pragma unroll
    for (int ks = 0; ks < 6; ++ks)
      wfr[nt][ks] = *(const short8*)&wl[rl * 192 + (((ks * 4 + lq) ^ (rl & 7)) << 3)];
  }
  float4 b4[3];
#pragma unroll
  for (int nt = 0; nt < 3; ++nt)
    b4[nt] = *(const float4*)(fb1 + cg * 192 + wave * 48 + nt * 16 + lq * 4);

  int tok0b = tb * 512;
#pragma unroll 2
  for (int t = 0; t < 32; ++t) {
    int tok0 = tok0b + t * 16;
    const bf16* arow = yn + (size_t)(tok0 + lm) * CC + lq * 8;
    float4v acc[3];
#pragma unroll
    for (int nt = 0; nt < 3; ++nt) acc[nt] = (float4v){0.f, 0.f, 0.f, 0.f};
#pragma unroll
    for (int ks = 0; ks < 6; ++ks) {
      short8 tf = *(const short8*)(arow + ks * 32);
#pragma unroll
      for (int nt = 0; nt < 3; ++nt)
        acc[nt] = __builtin_amdgcn_mfma_f32_16x16x32_bf16(wfr[nt][ks], tf, acc[nt], 0, 0, 0);
    }
    bf16* hrow = h + (size_t)(tok0 + lm) * 768 + cg * 192 + wave * 48 + lq * 4;
#pragma unroll
    for (int nt = 0; nt < 3; ++nt) {
      unsigned short u0 = f2bu(gelu_exact(acc[nt][0] + b4[nt].x));
      unsigned short u1 = f2bu(gelu_exact(acc[nt][1] + b4[nt].y));
      unsigned short u2 = f2bu(gelu_exact(acc[nt][2] + b4[nt].z));
      unsigned short u3 = f2bu(gelu_exact(acc[nt][3] + b4[nt].w));
      uint2 pk;
      pk.x = (unsigned)u0 | ((unsigned)u1 << 16);
      pk.y = (unsigned)u2 | ((unsigned)u3 << 16);
      *(uint2*)(hrow + nt * 16) = pk;
    }
  }
}

// --- K11b: fc2 via m97-style double-buffered LDS GEMM + residual epilogue ---
// grid 512 (2 blocks/CU), block 256 (4 waves). Tile: 128 tokens x 192 cols,
// BK=32, 24 K-steps, one __syncthreads per step.
__global__ __launch_bounds__(256, 2) void k_fc2m(const bf16* __restrict__ h,
                                                 const bf16* __restrict__ wF2,
                                                 const float* __restrict__ fb2,
                                                 const float* __restrict__ y,
                                                 const bf16* __restrict__ cv2,
                                                 const float* __restrict__ ca,
                                                 float* __restrict__ out) {
  __shared__ unsigned short ha[2][4096];   // [128 tok][32 k] bf16, 8,192 B/buf
  __shared__ unsigned short wbt[2][6144];  // [192 col][32 k] bf16, 12,288 B/buf
  int r0 = blockIdx.x * 128;
  int tid = threadIdx.x;
  int wave = tid >> 6, lane = tid & 63;
  int lm = lane & 15, lq = lane >> 4;

  const char* hsrc = (const char*)(h + (size_t)r0 * 768);
  const char* wsrc = (const char*)wF2;

  float4v acc[2][12];
#pragma unroll
  for (int mt = 0; mt < 2; ++mt)
#pragma unroll
    for (int nt = 0; nt < 12; ++nt) acc[mt][nt] = (float4v){0.f, 0.f, 0.f, 0.f};

  // stage K-chunk kc into buffer b (linear LDS, per m97: no swizzle)
  auto stage = [&](int kc, int b) {
    int k0b = kc * 64;                     // byte offset of k-chunk in a row
#pragma unroll
    for (int j = 0; j < 2; ++j) {          // ha: 512 x 16B chunks
      int c = j * 256 + tid;               // row=c>>2 (x1536B), koff=c&3 (x16B)
      glds16(hsrc + (size_t)(c >> 2) * 1536 + k0b + (c & 3) * 16,
             (char*)&ha[b][0] + (j * 256 + wave * 64) * 16);
    }
#pragma unroll
    for (int j = 0; j < 3; ++j) {          // wbt: 768 x 16B chunks
      int c = j * 256 + tid;               // col=c>>2, koff=c&3
      glds16(wsrc + (size_t)(c >> 2) * 1536 + k0b + (c & 3) * 16,
             (char*)&wbt[b][0] + (j * 256 + wave * 64) * 16);
    }
  };

  stage(0, 0);
  __syncthreads();
#pragma unroll 1
  for (int kc = 0; kc < 24; ++kc) {
    int cur = kc & 1;
    if (kc < 23) stage(kc + 1, cur ^ 1);
    short8 af[2], bf[12];
#pragma unroll
    for (int mt = 0; mt < 2; ++mt)
      af[mt] = *(const short8*)&ha[cur][(wave * 32 + mt * 16 + lm) * 32 + lq * 8];
#pragma unroll
    for (int nt = 0; nt < 12; ++nt)
      bf[nt] = *(const short8*)&wbt[cur][(nt * 16 + lm) * 32 + lq * 8];
#pragma unroll
    for (int mt = 0; mt < 2; ++mt)
#pragma unroll
      for (int nt = 0; nt < 12; ++nt)
        acc[mt][nt] = __builtin_amdgcn_mfma_f32_16x16x32_bf16(af[mt], bf[nt], acc[mt][nt], 0, 0, 0);
    __syncthreads();
  }

  // epilogue: out = acc + y + cv2*ca*0.01 + bias
  const float* cab = ca + (r0 >> 14) * CC;
#pragma unroll
  for (int nt = 0; nt < 12; ++nt) {
    int col = nt * 16 + lm;
    float bias = fb2[col];
    float cas = cab[col] * CONV_SC;
#pragma unroll
    for (int mt = 0; mt < 2; ++mt) {
#pragma unroll
      for (int reg = 0; reg < 4; ++reg) {
        int tok = r0 + wave * 32 + mt * 16 + lq * 4 + reg;
        size_t idx = (size_t)tok * CC + col;
        out[idx] = y[idx] + b2f(cv2[idx]) * cas + acc[mt][nt][reg] + bias;
      }
    }
  }
}

extern "C" void kernel_launch(void* const* d_in, const int* in_sizes, int n_in,
                              void* d_out, int out_size, void* d_ws, size_t ws_size,
                              hipStream_t stream) {
  const float* x      = (const float*)d_in[0];
  const float* qkv_w  = (const float*)d_in[1];
  const float* qkv_b  = (const float*)d_in[2];
  const float* proj_w = (const float*)d_in[3];
  const float* proj_b = (const float*)d_in[4];
  const float* rpb    = (const float*)d_in[5];
  const float* n1w    = (const float*)d_in[6];
  const float* n1b    = (const float*)d_in[7];
  const float* n2w    = (const float*)d_in[8];
  const float* n2b    = (const float*)d_in[9];
  const float* c1w    = (const float*)d_in[10];
  const float* c1b    = (const float*)d_in[11];
  const float* c2w    = (const float*)d_in[12];
  const float* c2b    = (const float*)d_in[13];
  const float* ca1w   = (const float*)d_in[14];
  const float* ca1b   = (const float*)d_in[15];
  const float* ca2w   = (const float*)d_in[16];
  const float* ca2b   = (const float*)d_in[17];
  const float* fc1w   = (const float*)d_in[18];
  const float* fc1b   = (const float*)d_in[19];
  const float* fc2w   = (const float*)d_in[20];
  const float* fc2b   = (const float*)d_in[21];
  const int*   rpi    = (const int*)d_in[22];
  (void)in_sizes; (void)n_in; (void)out_size; (void)ws_size;

  // ---- workspace layout: peak ~212.6 MB (< 256 MiB) ----
  char* wsb = (char*)d_ws;
  bf16*  xn    = (bf16*)(wsb + 0);            // 25,165,824
  bf16*  yn    = (bf16*)(wsb + 0);            // alias xn (dead after conv1l)
  float* biasQ = (float*)(wsb + 25165824);    //  1,572,864
  bf16*  Qg    = (bf16*)(wsb + 26738688);     // 25,165,824
  bf16*  Kg    = (bf16*)(wsb + 51904512);     // 25,165,824
  bf16*  Vg    = (bf16*)(wsb + 77070336);     // 25,165,824
  bf16*  AO    = (bf16*)(wsb + 102236160);    // 25,165,824
  bf16*  hbuf  = (bf16*)(wsb + 26738688);     // 100,663,296 alias Qg..AO (dead after proj2)
  float* y     = (float*)(wsb + 127401984);   // 50,331,648
  bf16*  cv1   = (bf16*)(wsb + 177733632);    //  8,388,608
  bf16*  cv2   = (bf16*)(wsb + 186122240);    // 25,165,824
  float* pool  = (float*)(wsb + 211288064);   //      3,072
  float* cavec = (float*)(wsb + 211291136);   //      3,072
  bf16*  wT1   = (bf16*)(wsb + 211294208);    //    221,184  [9][64][192]
  bf16*  wT2   = (bf16*)(wsb + 211515392);    //    221,184  [9][192][64]
  bf16*  wF1   = (bf16*)(wsb + 211736576);    //    294,912  [768][192]
  bf16*  wF2   = (bf16*)(wsb + 212031488);    //    294,912  [192][768]
  bf16*  wQv   = (bf16*)(wsb + 212326400);    //    221,184  [576][192]
  bf16*  wP    = (bf16*)(wsb + 212547584);    //     73,728  [192][192]
  float* out   = (float*)d_out;               // end 212,621,312

  k_ln1<<<TTOT / 4, 256, 0, stream>>>(x, n1w, n1b, xn);
  k_biasq<<<NHEAD * NTOK, 256, 0, stream>>>(rpi, rpb, biasQ);
  k_wprep<<<432, 256, 0, stream>>>(c1w, c2w, wT1, wT2);
  k_wprep2<<<576, 256, 0, stream>>>(fc1w, fc2w, wF1, wF2);
  k_wprep3<<<576, 256, 0, stream>>>(qkv_w, proj_w, wQv, wP);
  k_qkvg2<<<TTOT / 32, 256, 0, stream>>>(xn, wQv, qkv_b, Qg, Kg, Vg);
  k_attn2<<<BB * 64 * NHEAD * 2, 256, 0, stream>>>(Qg, Kg, Vg, biasQ, AO);
  k_proj2<<<TTOT / 32, 256, 0, stream>>>(AO, wP, proj_b, x, y);
  k_conv1l<<<BB * 128, 512, 0, stream>>>(xn, wT1, c1b, cv1);
  k_conv2l<<<BB * 128, 512, 0, stream>>>(cv1, wT2, c2b, cv2);
  hipMemsetAsync(pool, 0, BB * CC * sizeof(float), stream);
  k_pool<<<512, 192, 0, stream>>>(cv2, pool);
  k_ca<<<BB, 192, 0, stream>>>(pool, ca1w, ca1b, ca2w, ca2b, cavec);
  k_ln2<<<TTOT / 4, 256, 0, stream>>>(y, cv2, cavec, n2w, n2b, yn);
  k_fc1ws<<<512, 256, 0, stream>>>(yn, wF1, fc1b, hbuf);
  k_fc2m<<<512, 256, 0, stream>>>(hbuf, wF2, fc2b, y, cv2, cavec, out);
}

// Round 10
// 561.724 us; speedup vs baseline: 1.4718x; 1.0516x over previous
//
#include <hip/hip_runtime.h>
#include <hip/hip_bf16.h>
#include <cstdint>
#include <cstddef>

#define BB 4
#define CC 192
#define NHEAD 6
#define WSZ 16
#define SSH 8
#define NTOK 256
#define HD 32
#define HWPIX 16384
#define TTOT 65536
#define WWID 128
#define SCALE_Q 0.17677669529663687f
#define CONV_SC 0.01f
#define PSTR 264   // attn LDS row stride (shorts): 16B-aligned, <=2-way banks
#define KSTR 40    // attn K LDS row stride (shorts): 80B -> 8 banks 2-way

typedef __hip_bfloat16 bf16;
typedef __attribute__((ext_vector_type(8))) short short8;
typedef __attribute__((ext_vector_type(4))) float float4v;

__device__ __forceinline__ float b2f(bf16 v) { return __bfloat162float(v); }
__device__ __forceinline__ bf16 f2b(float v) { return __float2bfloat16(v); }
__device__ __forceinline__ unsigned short f2bu(float f) {
  bf16 h = __float2bfloat16(f);
  return *reinterpret_cast<unsigned short*>(&h);
}
__device__ __forceinline__ float gelu_exact(float x) {
  return 0.5f * x * (1.0f + erff(x * 0.7071067811865475f));
}
__device__ __forceinline__ short8 ld8z(const bf16* p, bool ok) {
  if (ok) return *(const short8*)p;
  short8 z = {0, 0, 0, 0, 0, 0, 0, 0};
  return z;
}
// async global->LDS 16B per lane: LDS dest = wave-uniform base + lane*16,
// global source is per-lane. size must be literal 16.
__device__ __forceinline__ void glds16(const void* g, void* l) {
  __builtin_amdgcn_global_load_lds(
      (const __attribute__((address_space(1))) unsigned int*)g,
      (__attribute__((address_space(3))) unsigned int*)l, 16, 0, 0);
}

// ---------------- K1: LayerNorm1 (x fp32 -> xn bf16). 1 wave per token -----
__global__ __launch_bounds__(256) void k_ln1(const float* __restrict__ x,
                                             const float* __restrict__ g,
                                             const float* __restrict__ b,
                                             bf16* __restrict__ xn) {
  int wv = threadIdx.x >> 6, lane = threadIdx.x & 63;
  int tok = blockIdx.x * 4 + wv;
  size_t row = (size_t)tok * CC;
  float v0 = x[row + lane], v1 = x[row + lane + 64], v2 = x[row + lane + 128];
  float s = v0 + v1 + v2, ss = v0 * v0 + v1 * v1 + v2 * v2;
#pragma unroll
  for (int off = 1; off < 64; off <<= 1) {
    s += __shfl_xor(s, off, 64);
    ss += __shfl_xor(ss, off, 64);
  }
  float mean = s * (1.0f / CC);
  float rstd = rsqrtf(ss * (1.0f / CC) - mean * mean + 1e-5f);
  xn[row + lane]       = f2b((v0 - mean) * rstd * g[lane]       + b[lane]);
  xn[row + lane + 64]  = f2b((v1 - mean) * rstd * g[lane + 64]  + b[lane + 64]);
  xn[row + lane + 128] = f2b((v2 - mean) * rstd * g[lane + 128] + b[lane + 128]);
}

// ------------- K2: bias gather, PERMUTED: biasP[h][q][(k&15)*16 + (k>>4)] ---
// so that attn lane lm's 16 values (keys ct*16+lm, ct=0..15) are contiguous.
__global__ __launch_bounds__(256) void k_biasq(const int* __restrict__ rpi,
                                               const float* __restrict__ rpb,
                                               float* __restrict__ biasQ) {
  int k = threadIdx.x;
  int h = blockIdx.x >> 8;
  int q = blockIdx.x & 255;
  biasQ[(size_t)blockIdx.x * 256 + ((k & 15) << 4) + (k >> 4)] =
      rpb[rpi[q * 256 + k] * NHEAD + h];
}

// ------- K2b: conv weight transpose to [tap][oc][ci] bf16 -------------------
__global__ __launch_bounds__(256) void k_wprep(const float* __restrict__ c1w,
                                               const float* __restrict__ c2w,
                                               bf16* __restrict__ wT1,
                                               bf16* __restrict__ wT2) {
  int i = blockIdx.x * 256 + threadIdx.x;   // 0 .. 110591
  {
    int tap = i / (64 * 192); int r = i % (64 * 192);
    int oc = r / 192, ci = r % 192;
    wT1[i] = f2b(c1w[(size_t)(tap * 192 + ci) * 64 + oc]);
  }
  {
    int tap = i / (192 * 64); int r = i % (192 * 64);
    int oc = r / 64, ci = r % 64;
    wT2[i] = f2b(c2w[(size_t)(tap * 64 + ci) * 192 + oc]);
  }
}

// ------- K2c: MLP weight transpose to n-major bf16 --------------------------
__global__ __launch_bounds__(256) void k_wprep2(const float* __restrict__ fc1w,
                                                const float* __restrict__ fc2w,
                                                bf16* __restrict__ wF1,
                                                bf16* __restrict__ wF2) {
  int i = blockIdx.x * 256 + threadIdx.x;   // 0 .. 147455
  {
    int n = i / 192, k = i % 192;           // wF1[n][k], n<768 k<192
    wF1[i] = f2b(fc1w[(size_t)k * 768 + n]);
  }
  {
    int n = i / 768, k = i % 768;           // wF2[n][k], n<192 k<768
    wF2[i] = f2b(fc2w[(size_t)k * 192 + n]);
  }
}

// ------- K2d: qkv/proj weight transpose to n-major bf16 ---------------------
__global__ __launch_bounds__(256) void k_wprep3(const float* __restrict__ qkvw,
                                                const float* __restrict__ projw,
                                                bf16* __restrict__ wQv,
                                                bf16* __restrict__ wP) {
  int i = blockIdx.x * 256 + threadIdx.x;   // 0 .. 147455 (grid 576)
  if (i < 576 * 192) {
    int n = i / 192, k = i % 192;           // wQv[n][k], n<576
    wQv[i] = f2b(qkvw[(size_t)k * 576 + n]);
  }
  if (i < 192 * 192) {
    int n = i / 192, k = i % 192;           // wP[n][k]
    wP[i] = f2b(projw[(size_t)k * 192 + n]);
  }
}

// --- K3: QKV GEMM via MFMA (N=576, K=192), gathered scatter store -----------
// grid TTOT/32, block 256 (4 waves). Wave w: cols w*144..+143 (9 tiles).
// 2 token-tiles per block: each weight fragment feeds 2 MFMA.
__global__ __launch_bounds__(256) void k_qkvg2(const bf16* __restrict__ xn,
                                               const bf16* __restrict__ wQv,
                                               const float* __restrict__ qb,
                                               bf16* __restrict__ Qg,
                                               bf16* __restrict__ Kg,
                                               bf16* __restrict__ Vg) {
  int tok0 = blockIdx.x * 32;
  int wave = threadIdx.x >> 6, lane = threadIdx.x & 63;
  int lm = lane & 15, lq = lane >> 4;
  const bf16* arow0 = xn + (size_t)(tok0 + lm) * CC + lq * 8;
  const bf16* arow1 = xn + (size_t)(tok0 + 16 + lm) * CC + lq * 8;
  float4v acc[9][2];
#pragma unroll
  for (int nt = 0; nt < 9; ++nt)
#pragma unroll
    for (int tt = 0; tt < 2; ++tt) acc[nt][tt] = (float4v){0.f, 0.f, 0.f, 0.f};
#pragma unroll
  for (int ks = 0; ks < 6; ++ks) {
    short8 af0 = *(const short8*)(arow0 + ks * 32);
    short8 af1 = *(const short8*)(arow1 + ks * 32);
#pragma unroll
    for (int nt = 0; nt < 9; ++nt) {
      int col = wave * 144 + nt * 16 + lm;
      short8 bfrag = *(const short8*)(wQv + (size_t)col * CC + ks * 32 + lq * 8);
      acc[nt][0] = __builtin_amdgcn_mfma_f32_16x16x32_bf16(af0, bfrag, acc[nt][0], 0, 0, 0);
      acc[nt][1] = __builtin_amdgcn_mfma_f32_16x16x32_bf16(af1, bfrag, acc[nt][1], 0, 0, 0);
    }
  }
  // per-(tt,reg) token -> gathered (window,head) coords
  size_t base[2][4];
#pragma unroll
  for (int tt = 0; tt < 2; ++tt)
#pragma unroll
    for (int reg = 0; reg < 4; ++reg) {
      int tg = tok0 + tt * 16 + lq * 4 + reg;
      int b = tg >> 14;
      int pix = tg & 16383;
      int gh = pix >> 7, gw = pix & 127;
      int hs = (gh + 120) & 127, wsx = (gw + 120) & 127;
      int wdx = (b << 6) + ((hs >> 4) << 3) + (wsx >> 4);
      int ndx = ((hs & 15) << 4) + (wsx & 15);
      base[tt][reg] = ((size_t)wdx * NHEAD) * NTOK * HD + (size_t)ndx * HD;
    }
#pragma unroll
  for (int nt = 0; nt < 9; ++nt) {
    int col = wave * 144 + nt * 16 + lm;
    float bias = qb[col];
    int sect = col / 192, within = col - sect * 192;
    int head = within >> 5, d = within & 31;
    bf16* dst = (sect == 0) ? Qg : (sect == 1) ? Kg : Vg;
    float scale = (sect == 0) ? SCALE_Q : 1.f;
#pragma unroll
    for (int tt = 0; tt < 2; ++tt)
#pragma unroll
      for (int reg = 0; reg < 4; ++reg) {
        dst[base[tt][reg] + (size_t)head * NTOK * HD + d] =
            f2b((acc[nt][tt][reg] + bias) * scale);
      }
  }
}

// --- K4: windowed attention via MFMA, K in LDS, vector bias loads -----------
// grid = 1536*2 (wh, query-half). block 256 = 4 waves x 32 queries.
// K staged row-major [key][KSTR=40] (80B stride -> 8 banks 2-way, free) so
// QK^T is LDS-fed; biasP permuted layout gives 4 float4 loads per output row
// (was 16 serialized scalars); mask arithmetic skipped block-uniformly for
// the 49/64 windows with no boundary wrap (wr<7 && wc<7).
__global__ __launch_bounds__(256) void k_attn3(const bf16* __restrict__ Qg,
                                               const bf16* __restrict__ Kg,
                                               const bf16* __restrict__ Vg,
                                               const float* __restrict__ biasP,
                                               bf16* __restrict__ AO) {
  __shared__ unsigned short PTw[4][16 * PSTR];  // 33,792 B (wave-private P tiles)
  __shared__ unsigned short VT[32 * PSTR];      // 16,896 B (V transposed)
  __shared__ unsigned short KL[256 * KSTR];     // 20,480 B (K row-major padded)
  int wh = blockIdx.x >> 1, half = blockIdx.x & 1;
  int wdx = wh / NHEAD, h = wh - wdx * NHEAD;
  int wl = wdx & 63;
  int wr = wl >> 3, wc = wl & 7;
  int tid = threadIdx.x;
  int wave = tid >> 6, lane = tid & 63;
  int lm = lane & 15, lq = lane >> 4;
  int q0 = half * 128;
  bool needmask = (wr == 7) || (wc == 7);

  // stage V^T + K: thread tid handles key row tid
  {
    const uint4* vp = (const uint4*)(Vg + ((size_t)wh * NTOK + tid) * HD);
    uint4 vv[4] = {vp[0], vp[1], vp[2], vp[3]};
    const uint4* kp = (const uint4*)(Kg + ((size_t)wh * NTOK + tid) * HD);
    uint4 kv[4] = {kp[0], kp[1], kp[2], kp[3]};
#pragma unroll
    for (int i = 0; i < 4; ++i) {
      unsigned arr[4] = {vv[i].x, vv[i].y, vv[i].z, vv[i].w};
#pragma unroll
      for (int j = 0; j < 4; ++j) {
        int d = i * 8 + j * 2;
        VT[d * PSTR + tid]       = (unsigned short)(arr[j] & 0xffffu);
        VT[(d + 1) * PSTR + tid] = (unsigned short)(arr[j] >> 16);
      }
      *(uint4*)&KL[tid * KSTR + i * 8] = kv[i];
    }
  }
  __syncthreads();

  int wsk = (wc << 4) + lm;                       // lane's key col (w coord)
  int ridk_w = (wsk >= 112) + (wsk >= 120);
  unsigned short* PT = &PTw[wave][0];

  float4v oacc[2][2];
#pragma unroll
  for (int rt = 0; rt < 2; ++rt)
#pragma unroll
    for (int c2 = 0; c2 < 2; ++c2) oacc[rt][c2] = (float4v){0.f, 0.f, 0.f, 0.f};
  float linv[2][4];

#pragma unroll
  for (int rt = 0; rt < 2; ++rt) {
    int qrow = q0 + wave * 32 + rt * 16;
    short8 aq = *(const short8*)(Qg + ((size_t)wh * NTOK + qrow + lm) * HD + lq * 8);
    float4v sacc[16];
#pragma unroll
    for (int ct = 0; ct < 16; ++ct) sacc[ct] = (float4v){0.f, 0.f, 0.f, 0.f};
#pragma unroll
    for (int ct = 0; ct < 16; ++ct) {
      short8 kf = *(const short8*)&KL[(ct * 16 + lm) * KSTR + lq * 8];
      sacc[ct] = __builtin_amdgcn_mfma_f32_16x16x32_bf16(aq, kf, sacc[ct], 0, 0, 0);
    }
    // softmax over 256 keys, rows lq*4+reg of this 16-row tile
#pragma unroll
    for (int reg = 0; reg < 4; ++reg) {
      int nq = qrow + lq * 4 + reg;
      const float* bp = biasP + ((size_t)(h * 256 + nq)) * 256 + lm * 16;
      float bb[16];
      *(float4*)&bb[0]  = ((const float4*)bp)[0];
      *(float4*)&bb[4]  = ((const float4*)bp)[1];
      *(float4*)&bb[8]  = ((const float4*)bp)[2];
      *(float4*)&bb[12] = ((const float4*)bp)[3];
      float sv[16];
      float mx = -1.0e30f;
      if (needmask) {
        int hsq = (wr << 4) + (nq >> 4), wsq = (wc << 4) + (nq & 15);
        int ridq = ((hsq >= 112) + (hsq >= 120)) * 3 + ((wsq >= 112) + (wsq >= 120));
#pragma unroll
        for (int ct = 0; ct < 16; ++ct) {
          int hsk = (wr << 4) + ct;
          int ridk = ((hsk >= 112) + (hsk >= 120)) * 3 + ridk_w;
          float s = sacc[ct][reg] + bb[ct] + ((ridk != ridq) ? -100.f : 0.f);
          sv[ct] = s;
          mx = fmaxf(mx, s);
        }
      } else {
#pragma unroll
        for (int ct = 0; ct < 16; ++ct) {
          float s = sacc[ct][reg] + bb[ct];
          sv[ct] = s;
          mx = fmaxf(mx, s);
        }
      }
#pragma unroll
      for (int off = 1; off < 16; off <<= 1) mx = fmaxf(mx, __shfl_xor(mx, off, 64));
      float l = 0.f;
#pragma unroll
      for (int ct = 0; ct < 16; ++ct) {
        float p = __expf(sv[ct] - mx);
        l += p;
        PT[(lq * 4 + reg) * PSTR + ct * 16 + lm] = f2bu(p);
      }
#pragma unroll
      for (int off = 1; off < 16; off <<= 1) l += __shfl_xor(l, off, 64);
      linv[rt][reg] = 1.f / l;
    }
    // PV for this row tile: A = P rows (wave-private, in-wave LDS ordering)
#pragma unroll
    for (int kb = 0; kb < 8; ++kb) {
      short8 pf = *(const short8*)&PT[lm * PSTR + kb * 32 + lq * 8];
#pragma unroll
      for (int c2 = 0; c2 < 2; ++c2) {
        short8 vf = *(const short8*)&VT[(c2 * 16 + lm) * PSTR + kb * 32 + lq * 8];
        oacc[rt][c2] = __builtin_amdgcn_mfma_f32_16x16x32_bf16(pf, vf, oacc[rt][c2], 0, 0, 0);
      }
    }
  }
  // write AO
#pragma unroll
  for (int rt = 0; rt < 2; ++rt)
#pragma unroll
    for (int c2 = 0; c2 < 2; ++c2) {
      int d = c2 * 16 + lm;
#pragma unroll
      for (int reg = 0; reg < 4; ++reg) {
        int nq = q0 + wave * 32 + rt * 16 + lq * 4 + reg;
        AO[((size_t)wdx * NTOK + nq) * CC + h * HD + d] =
            f2b(oacc[rt][c2][reg] * linv[rt][reg]);
      }
    }
}

// --- K5: proj GEMM via MFMA (N=192, K=192) + shift-reverse + x residual -----
// grid TTOT/32 (win-order rows), block 256 (4 waves). Wave w: cols w*48..+47.
// 2 token-tiles per block: each wP fragment feeds 2 MFMA.
__global__ __launch_bounds__(256) void k_proj2(const bf16* __restrict__ AO,
                                               const bf16* __restrict__ wP,
                                               const float* __restrict__ pb,
                                               const float* __restrict__ x,
                                               float* __restrict__ y) {
  int r0 = blockIdx.x * 32;
  int wave = threadIdx.x >> 6, lane = threadIdx.x & 63;
  int lm = lane & 15, lq = lane >> 4;
  const bf16* arow0 = AO + (size_t)(r0 + lm) * CC + lq * 8;
  const bf16* arow1 = AO + (size_t)(r0 + 16 + lm) * CC + lq * 8;
  float4v acc[3][2];
#pragma unroll
  for (int nt = 0; nt < 3; ++nt)
#pragma unroll
    for (int tt = 0; tt < 2; ++tt) acc[nt][tt] = (float4v){0.f, 0.f, 0.f, 0.f};
#pragma unroll
  for (int ks = 0; ks < 6; ++ks) {
    short8 af0 = *(const short8*)(arow0 + ks * 32);
    short8 af1 = *(const short8*)(arow1 + ks * 32);
#pragma unroll
    for (int nt = 0; nt < 3; ++nt) {
      int col = wave * 48 + nt * 16 + lm;
      short8 bfrag = *(const short8*)(wP + (size_t)col * CC + ks * 32 + lq * 8);
      acc[nt][0] = __builtin_amdgcn_mfma_f32_16x16x32_bf16(af0, bfrag, acc[nt][0], 0, 0, 0);
      acc[nt][1] = __builtin_amdgcn_mfma_f32_16x16x32_bf16(af1, bfrag, acc[nt][1], 0, 0, 0);
    }
  }
  size_t drow[2][4];
#pragma unroll
  for (int tt = 0; tt < 2; ++tt)
#pragma unroll
    for (int reg = 0; reg < 4; ++reg) {
      int r = r0 + tt * 16 + lq * 4 + reg;
      int wdx = r >> 8, n = r & 255;
      int wb = wdx >> 6, wl = wdx & 63;
      int hs = ((wl >> 3) << 4) + (n >> 4);
      int wsx = ((wl & 7) << 4) + (n & 15);
      int gh = (hs + SSH) & 127, gw = (wsx + SSH) & 127;
      drow[tt][reg] = ((size_t)wb * HWPIX + (size_t)gh * WWID + gw) * CC;
    }
#pragma unroll
  for (int nt = 0; nt < 3; ++nt) {
    int col = wave * 48 + nt * 16 + lm;
    float bias = pb[col];
#pragma unroll
    for (int tt = 0; tt < 2; ++tt)
#pragma unroll
      for (int reg = 0; reg < 4; ++reg) {
        y[drow[tt][reg] + col] = x[drow[tt][reg] + col] + acc[nt][tt][reg] + bias;
      }
  }
}

// ---- K6: conv3x3 192->64 + GELU, LDS-staged input rows ---------------------
// grid BB*128 (b x row), block 512 (8 waves = 2 px-halves x 4 oc-tiles).
// 3 full xn rows staged to LDS via global_load_lds (147,456 B, 1 blk/CU);
// source XOR-swizzled (kc ^= px&7). One barrier, then barrier-free main loop:
// 216 MFMA/wave fed from LDS; per-tap weight frags prefetched one tap ahead.
__global__ __launch_bounds__(512, 1) void k_conv1l(const bf16* __restrict__ xn,
                                                   const bf16* __restrict__ wT1,
                                                   const float* __restrict__ c1b,
                                                   bf16* __restrict__ cv1) {
  __shared__ unsigned short xs[3 * 128 * 192];   // 147,456 B
  int hh = blockIdx.x & 127, b = blockIdx.x >> 7;
  int tid = threadIdx.x;
  int wave = tid >> 6, lane = tid & 63;
  int lm = lane & 15, lq = lane >> 4;
  int ph = wave >> 2;                 // px half (0: 0-63, 1: 64-127)
  int oc = (wave & 3) * 16 + lm;

  // stage rows hh-1..hh+1 (3072 16B-chunks each)
#pragma unroll
  for (int r = 0; r < 3; ++r) {
    int gh = hh + r - 1;
    if ((unsigned)gh < 128u) {        // block-uniform
      const char* src = (const char*)(xn + (size_t)(b * HWPIX + gh * WWID) * CC);
#pragma unroll
      for (int j = 0; j < 6; ++j) {
        int c = j * 512 + tid;        // 0..3071
        int px = c / 24, kc = c - px * 24;
        glds16(src + (size_t)px * 384 + ((size_t)(kc ^ (px & 7)) << 4),
               (char*)xs + ((size_t)(r * 3072 + j * 512 + wave * 64)) * 16);
      }
    }
  }
  __syncthreads();

  float4v acc[4];
#pragma unroll
  for (int t = 0; t < 4; ++t) acc[t] = (float4v){0.f, 0.f, 0.f, 0.f};

  short8 w[6], wn[6];
#pragma unroll
  for (int ks = 0; ks < 6; ++ks)
    w[ks] = *(const short8*)(wT1 + ((size_t)oc) * CC + ks * 32 + lq * 8);
#pragma unroll
  for (int tap = 0; tap < 9; ++tap) {
    if (tap < 8) {
#pragma unroll
      for (int ks = 0; ks < 6; ++ks)
        wn[ks] = *(const short8*)(wT1 + ((size_t)((tap + 1) * 64) + oc) * CC + ks * 32 + lq * 8);
    }
    int kh = tap / 3, kw = tap % 3;
    int gh = hh + kh - 1;
    if ((unsigned)gh < 128u) {        // block-uniform skip of OOB rows
      const unsigned short* row = &xs[kh * 24576];
#pragma unroll
      for (int ks = 0; ks < 6; ++ks) {
#pragma unroll
        for (int t = 0; t < 4; ++t) {
          int px = ph * 64 + t * 16 + lm + kw - 1;
          int pxc = px < 0 ? 0 : (px > 127 ? 127 : px);
          short8 av = *(const short8*)&row[pxc * 192 + (((ks * 4 + lq) ^ (pxc & 7)) << 3)];
          short8 zz = {0, 0, 0, 0, 0, 0, 0, 0};
          short8 a = ((unsigned)px < 128u) ? av : zz;
          acc[t] = __builtin_amdgcn_mfma_f32_16x16x32_bf16(a, w[ks], acc[t], 0, 0, 0);
        }
      }
    }
#pragma unroll
    for (int ks = 0; ks < 6; ++ks) w[ks] = wn[ks];
  }
  float bias = c1b[oc];
#pragma unroll
  for (int t = 0; t < 4; ++t) {
    int pxb = ph * 64 + t * 16 + lq * 4;
    size_t base = ((size_t)b * HWPIX + (size_t)hh * WWID + pxb) * 64 + oc;
    cv1[base]       = f2b(gelu_exact(acc[t][0] + bias));
    cv1[base + 64]  = f2b(gelu_exact(acc[t][1] + bias));
    cv1[base + 128] = f2b(gelu_exact(acc[t][2] + bias));
    cv1[base + 192] = f2b(gelu_exact(acc[t][3] + bias));
  }
}

// ---- K7: conv3x3 64->192 + bias, LDS-staged input rows ---------------------
// grid BB*128, block 512 (8 waves = 2 px-halves x 4 oc-groups of 48).
// 3 cv1 rows staged (49,152 B), same swizzle scheme. Tap-ahead weight prefetch.
__global__ __launch_bounds__(512, 2) void k_conv2l(const bf16* __restrict__ cv1,
                                                   const bf16* __restrict__ wT2,
                                                   const float* __restrict__ c2b,
                                                   bf16* __restrict__ cv2) {
  __shared__ unsigned short cs[3 * 128 * 64];    // 49,152 B
  int hh = blockIdx.x & 127, b = blockIdx.x >> 7;
  int tid = threadIdx.x;
  int wave = tid >> 6, lane = tid & 63;
  int lm = lane & 15, lq = lane >> 4;
  int ph = wave >> 2;                 // px half
  int og = wave & 3;                  // oc group (48 cols)

  // stage rows hh-1..hh+1 (1024 16B-chunks each)
#pragma unroll
  for (int r = 0; r < 3; ++r) {
    int gh = hh + r - 1;
    if ((unsigned)gh < 128u) {
      const char* src = (const char*)(cv1 + (size_t)(b * HWPIX + gh * WWID) * 64);
#pragma unroll
      for (int j = 0; j < 2; ++j) {
        int c = j * 512 + tid;        // 0..1023
        int px = c >> 3, kc = c & 7;
        glds16(src + (size_t)px * 128 + ((size_t)(kc ^ (px & 7)) << 4),
               (char*)cs + ((size_t)(r * 1024 + j * 512 + wave * 64)) * 16);
      }
    }
  }
  __syncthreads();

  float4v acc[3][4];
#pragma unroll
  for (int nt = 0; nt < 3; ++nt)
#pragma unroll
    for (int t = 0; t < 4; ++t) acc[nt][t] = (float4v){0.f, 0.f, 0.f, 0.f};

  short8 w[3][2], wn[3][2];
#pragma unroll
  for (int nt = 0; nt < 3; ++nt) {
    int oc = og * 48 + nt * 16 + lm;
#pragma unroll
    for (int ks = 0; ks < 2; ++ks)
      w[nt][ks] = *(const short8*)(wT2 + ((size_t)oc) * 64 + ks * 32 + lq * 8);
  }
#pragma unroll
  for (int tap = 0; tap < 9; ++tap) {
    if (tap < 8) {
#pragma unroll
      for (int nt = 0; nt < 3; ++nt) {
        int oc = og * 48 + nt * 16 + lm;
#pragma unroll
        for (int ks = 0; ks < 2; ++ks)
          wn[nt][ks] = *(const short8*)(wT2 + ((size_t)((tap + 1) * 192) + oc) * 64 + ks * 32 + lq * 8);
      }
    }
    int kh = tap / 3, kw = tap % 3;
    int gh = hh + kh - 1;
    if ((unsigned)gh < 128u) {
      const unsigned short* row = &cs[kh * 8192];
#pragma unroll
      for (int ks = 0; ks < 2; ++ks) {
#pragma unroll
        for (int t = 0; t < 4; ++t) {
          int px = ph * 64 + t * 16 + lm + kw - 1;
          int pxc = px < 0 ? 0 : (px > 127 ? 127 : px);
          short8 av = *(const short8*)&row[pxc * 64 + (((ks * 4 + lq) ^ (pxc & 7)) << 3)];
          short8 zz = {0, 0, 0, 0, 0, 0, 0, 0};
          short8 a = ((unsigned)px < 128u) ? av : zz;
#pragma unroll
          for (int nt = 0; nt < 3; ++nt)
            acc[nt][t] = __builtin_amdgcn_mfma_f32_16x16x32_bf16(a, w[nt][ks], acc[nt][t], 0, 0, 0);
        }
      }
    }
#pragma unroll
    for (int nt = 0; nt < 3; ++nt)
#pragma unroll
      for (int ks = 0; ks < 2; ++ks) w[nt][ks] = wn[nt][ks];
  }
#pragma unroll
  for (int nt = 0; nt < 3; ++nt) {
    int oc = og * 48 + nt * 16 + lm;
    float bias = c2b[oc];
#pragma unroll
    for (int t = 0; t < 4; ++t) {
      int pxb = ph * 64 + t * 16 + lq * 4;
      size_t base = ((size_t)b * HWPIX + (size_t)hh * WWID + pxb) * CC + oc;
      cv2[base]           = f2b(acc[nt][t][0] + bias);
      cv2[base + CC]      = f2b(acc[nt][t][1] + bias);
      cv2[base + 2 * CC]  = f2b(acc[nt][t][2] + bias);
      cv2[base + 3 * CC]  = f2b(acc[nt][t][3] + bias);
    }
  }
}

// ---------------- K8: global average pool (sum into pooled, pre-zeroed) ----
__global__ __launch_bounds__(192) void k_pool(const bf16* __restrict__ cv2,
                                              float* __restrict__ pooled) {
  int t = threadIdx.x;                        // channel
  int b = blockIdx.x >> 7;
  int pc = blockIdx.x & 127;                  // 128-pixel chunk
  const bf16* base = cv2 + ((size_t)b * HWPIX + (size_t)pc * 128) * CC + t;
  float s = 0.f;
#pragma unroll 4
  for (int p = 0; p < 128; ++p) s += b2f(base[(size_t)p * CC]);
  atomicAdd(&pooled[b * CC + t], s);
}

// ---------------- K9: channel attention weights ----------------
__global__ __launch_bounds__(192) void k_ca(const float* __restrict__ pooled,
                                            const float* __restrict__ w1,
                                            const float* __restrict__ b1,
                                            const float* __restrict__ w2,
                                            const float* __restrict__ b2,
                                            float* __restrict__ ca) {
  __shared__ float pld[CC];
  __shared__ float t1[6];
  int t = threadIdx.x, b = blockIdx.x;
  pld[t] = pooled[b * CC + t] * (1.0f / HWPIX);
  __syncthreads();
  if (t < 6) {
    float s = b1[t];
    for (int c = 0; c < CC; ++c) s += pld[c] * w1[c * 6 + t];
    t1[t] = fmaxf(s, 0.f);
  }
  __syncthreads();
  float s = b2[t];
#pragma unroll
  for (int k = 0; k < 6; ++k) s += t1[k] * w2[k * CC + t];
  ca[b * CC + t] = 1.f / (1.f + __expf(-s));
}

// --- K10: LN2 with conv-branch fold: yn = LN(y + cv2*ca*0.01) bf16 ---------
__global__ __launch_bounds__(256) void k_ln2(const float* __restrict__ y,
                                             const bf16* __restrict__ cv2,
                                             const float* __restrict__ ca,
                                             const float* __restrict__ g2,
                                             const float* __restrict__ b2,
                                             bf16* __restrict__ yn) {
  int wv = threadIdx.x >> 6, lane = threadIdx.x & 63;
  int tok = blockIdx.x * 4 + wv;
  const float* cab = ca + (tok >> 14) * CC;
  size_t row = (size_t)tok * CC;
  float v0 = y[row + lane]       + b2f(cv2[row + lane])       * cab[lane]       * CONV_SC;
  float v1 = y[row + lane + 64]  + b2f(cv2[row + lane + 64])  * cab[lane + 64]  * CONV_SC;
  float v2 = y[row + lane + 128] + b2f(cv2[row + lane + 128]) * cab[lane + 128] * CONV_SC;
  float s = v0 + v1 + v2, ss = v0 * v0 + v1 * v1 + v2 * v2;
#pragma unroll
  for (int off = 1; off < 64; off <<= 1) {
    s += __shfl_xor(s, off, 64);
    ss += __shfl_xor(ss, off, 64);
  }
  float mean = s * (1.0f / CC);
  float rstd = rsqrtf(ss * (1.0f / CC) - mean * mean + 1e-5f);
  yn[row + lane]       = f2b((v0 - mean) * rstd * g2[lane]       + b2[lane]);
  yn[row + lane + 64]  = f2b((v1 - mean) * rstd * g2[lane + 64]  + b2[lane + 64]);
  yn[row + lane + 128] = f2b((v2 - mean) * rstd * g2[lane + 128] + b2[lane + 128]);
}

// --- K11a: fc1 weight-stationary: h = GELU(yn @ fc1 + b) --------------------
// grid 512 = 4 col-panels (cg) x 128 token-blocks (tb, 512 tokens).
__global__ __launch_bounds__(256, 2) void k_fc1ws(const bf16* __restrict__ yn,
                                                  const bf16* __restrict__ wF1,
                                                  const float* __restrict__ fb1,
                                                  bf16* __restrict__ h) {
  __shared__ unsigned short wl[192 * 192];   // 73,728 B
  int cg = blockIdx.x & 3, tb = blockIdx.x >> 2;
  int tid = threadIdx.x;
  int wave = tid >> 6, lane = tid & 63;
  int lm = lane & 15, lq = lane >> 4;

  const char* src = (const char*)wF1 + (size_t)cg * 73728;
#pragma unroll
  for (int j = 0; j < 18; ++j) {
    int ci = j * 256 + tid;                  // 16B-chunk index 0..4607
    int r = ci / 24, c = ci - r * 24;        // row 0..191, chunk 0..23
    glds16(src + (size_t)r * 384 + ((c ^ (r & 7)) << 4),
           (char*)wl + (size_t)(j * 256 + wave * 64) * 16);
  }
  __syncthreads();

  // hoist wave's B-frags (cols wave*48 + nt*16 + lm) -- one-time LDS reads
  short8 wfr[3][6];
#pragma unroll
  for (int nt = 0; nt < 3; ++nt) {
    int rl = wave * 48 + nt * 16 + lm;
#pragma unroll
    for (int ks = 0; ks < 6; ++ks)
      wfr[nt][ks] = *(const short8*)&wl[rl * 192 + (((ks * 4 + lq) ^ (rl & 7)) << 3)];
  }
  float4 b4[3];
#pragma unroll
  for (int nt = 0; nt < 3; ++nt)
    b4[nt] = *(const float4*)(fb1 + cg * 192 + wave * 48 + nt * 16 + lq * 4);

  int tok0b = tb * 512;
#pragma unroll 2
  for (int t = 0; t < 32; ++t) {
    int tok0 = tok0b + t * 16;
    const bf16* arow = yn + (size_t)(tok0 + lm) * CC + lq * 8;
    float4v acc[3];
#pragma unroll
    for (int nt = 0; nt < 3; ++nt) acc[nt] = (float4v){0.f, 0.f, 0.f, 0.f};
#pragma unroll
    for (int ks = 0; ks < 6; ++ks) {
      short8 tf = *(const short8*)(arow + ks * 32);
#pragma unroll
      for (int nt = 0; nt < 3; ++nt)
        acc[nt] = __builtin_amdgcn_mfma_f32_16x16x32_bf16(wfr[nt][ks], tf, acc[nt], 0, 0, 0);
    }
    bf16* hrow = h + (size_t)(tok0 + lm) * 768 + cg * 192 + wave * 48 + lq * 4;
#pragma unroll
    for (int nt = 0; nt < 3; ++nt) {
      unsigned short u0 = f2bu(gelu_exact(acc[nt][0] + b4[nt].x));
      unsigned short u1 = f2bu(gelu_exact(acc[nt][1] + b4[nt].y));
      unsigned short u2 = f2bu(gelu_exact(acc[nt][2] + b4[nt].z));
      unsigned short u3 = f2bu(gelu_exact(acc[nt][3] + b4[nt].w));
      uint2 pk;
      pk.x = (unsigned)u0 | ((unsigned)u1 << 16);
      pk.y = (unsigned)u2 | ((unsigned)u3 << 16);
      *(uint2*)(hrow + nt * 16) = pk;
    }
  }
}

// --- K11b: fc2 via m97-style double-buffered LDS GEMM + residual epilogue ---
// grid 512 (2 blocks/CU), block 256 (4 waves). Tile: 128 tokens x 192 cols,
// BK=32, 24 K-steps, one __syncthreads per step.
__global__ __launch_bounds__(256, 2) void k_fc2m(const bf16* __restrict__ h,
                                                 const bf16* __restrict__ wF2,
                                                 const float* __restrict__ fb2,
                                                 const float* __restrict__ y,
                                                 const bf16* __restrict__ cv2,
                                                 const float* __restrict__ ca,
                                                 float* __restrict__ out) {
  __shared__ unsigned short ha[2][4096];   // [128 tok][32 k] bf16, 8,192 B/buf
  __shared__ unsigned short wbt[2][6144];  // [192 col][32 k] bf16, 12,288 B/buf
  int r0 = blockIdx.x * 128;
  int tid = threadIdx.x;
  int wave = tid >> 6, lane = tid & 63;
  int lm = lane & 15, lq = lane >> 4;

  const char* hsrc = (const char*)(h + (size_t)r0 * 768);
  const char* wsrc = (const char*)wF2;

  float4v acc[2][12];
#pragma unroll
  for (int mt = 0; mt < 2; ++mt)
#pragma unroll
    for (int nt = 0; nt < 12; ++nt) acc[mt][nt] = (float4v){0.f, 0.f, 0.f, 0.f};

  // stage K-chunk kc into buffer b (linear LDS, per m97: no swizzle)
  auto stage = [&](int kc, int b) {
    int k0b = kc * 64;                     // byte offset of k-chunk in a row
#pragma unroll
    for (int j = 0; j < 2; ++j) {          // ha: 512 x 16B chunks
      int c = j * 256 + tid;               // row=c>>2 (x1536B), koff=c&3 (x16B)
      glds16(hsrc + (size_t)(c >> 2) * 1536 + k0b + (c & 3) * 16,
             (char*)&ha[b][0] + (j * 256 + wave * 64) * 16);
    }
#pragma unroll
    for (int j = 0; j < 3; ++j) {          // wbt: 768 x 16B chunks
      int c = j * 256 + tid;               // col=c>>2, koff=c&3
      glds16(wsrc + (size_t)(c >> 2) * 1536 + k0b + (c & 3) * 16,
             (char*)&wbt[b][0] + (j * 256 + wave * 64) * 16);
    }
  };

  stage(0, 0);
  __syncthreads();
#pragma unroll 1
  for (int kc = 0; kc < 24; ++kc) {
    int cur = kc & 1;
    if (kc < 23) stage(kc + 1, cur ^ 1);
    short8 af[2], bf[12];
#pragma unroll
    for (int mt = 0; mt < 2; ++mt)
      af[mt] = *(const short8*)&ha[cur][(wave * 32 + mt * 16 + lm) * 32 + lq * 8];
#pragma unroll
    for (int nt = 0; nt < 12; ++nt)
      bf[nt] = *(const short8*)&wbt[cur][(nt * 16 + lm) * 32 + lq * 8];
#pragma unroll
    for (int mt = 0; mt < 2; ++mt)
#pragma unroll
      for (int nt = 0; nt < 12; ++nt)
        acc[mt][nt] = __builtin_amdgcn_mfma_f32_16x16x32_bf16(af[mt], bf[nt], acc[mt][nt], 0, 0, 0);
    __syncthreads();
  }

  // epilogue: out = acc + y + cv2*ca*0.01 + bias
  const float* cab = ca + (r0 >> 14) * CC;
#pragma unroll
  for (int nt = 0; nt < 12; ++nt) {
    int col = nt * 16 + lm;
    float bias = fb2[col];
    float cas = cab[col] * CONV_SC;
#pragma unroll
    for (int mt = 0; mt < 2; ++mt) {
#pragma unroll
      for (int reg = 0; reg < 4; ++reg) {
        int tok = r0 + wave * 32 + mt * 16 + lq * 4 + reg;
        size_t idx = (size_t)tok * CC + col;
        out[idx] = y[idx] + b2f(cv2[idx]) * cas + acc[mt][nt][reg] + bias;
      }
    }
  }
}

extern "C" void kernel_launch(void* const* d_in, const int* in_sizes, int n_in,
                              void* d_out, int out_size, void* d_ws, size_t ws_size,
                              hipStream_t stream) {
  const float* x      = (const float*)d_in[0];
  const float* qkv_w  = (const float*)d_in[1];
  const float* qkv_b  = (const float*)d_in[2];
  const float* proj_w = (const float*)d_in[3];
  const float* proj_b = (const float*)d_in[4];
  const float* rpb    = (const float*)d_in[5];
  const float* n1w    = (const float*)d_in[6];
  const float* n1b    = (const float*)d_in[7];
  const float* n2w    = (const float*)d_in[8];
  const float* n2b    = (const float*)d_in[9];
  const float* c1w    = (const float*)d_in[10];
  const float* c1b    = (const float*)d_in[11];
  const float* c2w    = (const float*)d_in[12];
  const float* c2b    = (const float*)d_in[13];
  const float* ca1w   = (const float*)d_in[14];
  const float* ca1b   = (const float*)d_in[15];
  const float* ca2w   = (const float*)d_in[16];
  const float* ca2b   = (const float*)d_in[17];
  const float* fc1w   = (const float*)d_in[18];
  const float* fc1b   = (const float*)d_in[19];
  const float* fc2w   = (const float*)d_in[20];
  const float* fc2b   = (const float*)d_in[21];
  const int*   rpi    = (const int*)d_in[22];
  (void)in_sizes; (void)n_in; (void)out_size; (void)ws_size;

  // ---- workspace layout: peak ~212.6 MB (< 256 MiB) ----
  char* wsb = (char*)d_ws;
  bf16*  xn    = (bf16*)(wsb + 0);            // 25,165,824
  bf16*  yn    = (bf16*)(wsb + 0);            // alias xn (dead after conv1l)
  float* biasQ = (float*)(wsb + 25165824);    //  1,572,864
  bf16*  Qg    = (bf16*)(wsb + 26738688);     // 25,165,824
  bf16*  Kg    = (bf16*)(wsb + 51904512);     // 25,165,824
  bf16*  Vg    = (bf16*)(wsb + 77070336);     // 25,165,824
  bf16*  AO    = (bf16*)(wsb + 102236160);    // 25,165,824
  bf16*  hbuf  = (bf16*)(wsb + 26738688);     // 100,663,296 alias Qg..AO (dead after proj2)
  float* y     = (float*)(wsb + 127401984);   // 50,331,648
  bf16*  cv1   = (bf16*)(wsb + 177733632);    //  8,388,608
  bf16*  cv2   = (bf16*)(wsb + 186122240);    // 25,165,824
  float* pool  = (float*)(wsb + 211288064);   //      3,072
  float* cavec = (float*)(wsb + 211291136);   //      3,072
  bf16*  wT1   = (bf16*)(wsb + 211294208);    //    221,184  [9][64][192]
  bf16*  wT2   = (bf16*)(wsb + 211515392);    //    221,184  [9][192][64]
  bf16*  wF1   = (bf16*)(wsb + 211736576);    //    294,912  [768][192]
  bf16*  wF2   = (bf16*)(wsb + 212031488);    //    294,912  [192][768]
  bf16*  wQv   = (bf16*)(wsb + 212326400);    //    221,184  [576][192]
  bf16*  wP    = (bf16*)(wsb + 212547584);    //     73,728  [192][192]
  float* out   = (float*)d_out;               // end 212,621,312

  k_ln1<<<TTOT / 4, 256, 0, stream>>>(x, n1w, n1b, xn);
  k_biasq<<<NHEAD * NTOK, 256, 0, stream>>>(rpi, rpb, biasQ);
  k_wprep<<<432, 256, 0, stream>>>(c1w, c2w, wT1, wT2);
  k_wprep2<<<576, 256, 0, stream>>>(fc1w, fc2w, wF1, wF2);
  k_wprep3<<<576, 256, 0, stream>>>(qkv_w, proj_w, wQv, wP);
  k_qkvg2<<<TTOT / 32, 256, 0, stream>>>(xn, wQv, qkv_b, Qg, Kg, Vg);
  k_attn3<<<BB * 64 * NHEAD * 2, 256, 0, stream>>>(Qg, Kg, Vg, biasQ, AO);
  k_proj2<<<TTOT / 32, 256, 0, stream>>>(AO, wP, proj_b, x, y);
  k_conv1l<<<BB * 128, 512, 0, stream>>>(xn, wT1, c1b, cv1);
  k_conv2l<<<BB * 128, 512, 0, stream>>>(cv1, wT2, c2b, cv2);
  hipMemsetAsync(pool, 0, BB * CC * sizeof(float), stream);
  k_pool<<<512, 192, 0, stream>>>(cv2, pool);
  k_ca<<<BB, 192, 0, stream>>>(pool, ca1w, ca1b, ca2w, ca2b, cavec);
  k_ln2<<<TTOT / 4, 256, 0, stream>>>(y, cv2, cavec, n2w, n2b, yn);
  k_fc1ws<<<512, 256, 0, stream>>>(yn, wF1, fc1b, hbuf);
  k_fc2m<<<512, 256, 0, stream>>>(hbuf, wF2, fc2b, y, cv2, cavec, out);
}

// Round 11
// 544.078 us; speedup vs baseline: 1.5195x; 1.0324x over previous
//
#include <hip/hip_runtime.h>
#include <hip/hip_bf16.h>
#include <cstdint>
#include <cstddef>

#define BB 4
#define CC 192
#define NHEAD 6
#define WSZ 16
#define SSH 8
#define NTOK 256
#define HD 32
#define HWPIX 16384
#define TTOT 65536
#define WWID 128
#define SCALE_Q 0.17677669529663687f
#define CONV_SC 0.01f
#define PSTR 264   // attn LDS row stride (shorts): 16B-aligned, <=2-way banks
#define KSTR 40    // attn K LDS row stride (shorts): 80B -> 8 banks 2-way

typedef __hip_bfloat16 bf16;
typedef __attribute__((ext_vector_type(8))) short short8;
typedef __attribute__((ext_vector_type(4))) float float4v;

__device__ __forceinline__ float b2f(bf16 v) { return __bfloat162float(v); }
__device__ __forceinline__ bf16 f2b(float v) { return __float2bfloat16(v); }
__device__ __forceinline__ unsigned short f2bu(float f) {
  bf16 h = __float2bfloat16(f);
  return *reinterpret_cast<unsigned short*>(&h);
}
__device__ __forceinline__ float gelu_exact(float x) {
  return 0.5f * x * (1.0f + erff(x * 0.7071067811865475f));
}
__device__ __forceinline__ short8 ld8z(const bf16* p, bool ok) {
  if (ok) return *(const short8*)p;
  short8 z = {0, 0, 0, 0, 0, 0, 0, 0};
  return z;
}
// async global->LDS 16B per lane: LDS dest = wave-uniform base + lane*16,
// global source is per-lane. size must be literal 16.
__device__ __forceinline__ void glds16(const void* g, void* l) {
  __builtin_amdgcn_global_load_lds(
      (const __attribute__((address_space(1))) unsigned int*)g,
      (__attribute__((address_space(3))) unsigned int*)l, 16, 0, 0);
}

// ---------------- K1: LayerNorm1 (x fp32 -> xn bf16). 1 wave per token -----
__global__ __launch_bounds__(256) void k_ln1(const float* __restrict__ x,
                                             const float* __restrict__ g,
                                             const float* __restrict__ b,
                                             bf16* __restrict__ xn) {
  int wv = threadIdx.x >> 6, lane = threadIdx.x & 63;
  int tok = blockIdx.x * 4 + wv;
  size_t row = (size_t)tok * CC;
  float v0 = x[row + lane], v1 = x[row + lane + 64], v2 = x[row + lane + 128];
  float s = v0 + v1 + v2, ss = v0 * v0 + v1 * v1 + v2 * v2;
#pragma unroll
  for (int off = 1; off < 64; off <<= 1) {
    s += __shfl_xor(s, off, 64);
    ss += __shfl_xor(ss, off, 64);
  }
  float mean = s * (1.0f / CC);
  float rstd = rsqrtf(ss * (1.0f / CC) - mean * mean + 1e-5f);
  xn[row + lane]       = f2b((v0 - mean) * rstd * g[lane]       + b[lane]);
  xn[row + lane + 64]  = f2b((v1 - mean) * rstd * g[lane + 64]  + b[lane + 64]);
  xn[row + lane + 128] = f2b((v2 - mean) * rstd * g[lane + 128] + b[lane + 128]);
}

// ------------- K2: bias gather, PERMUTED: biasP[h][q][(k&15)*16 + (k>>4)] ---
__global__ __launch_bounds__(256) void k_biasq(const int* __restrict__ rpi,
                                               const float* __restrict__ rpb,
                                               float* __restrict__ biasQ) {
  int k = threadIdx.x;
  int h = blockIdx.x >> 8;
  int q = blockIdx.x & 255;
  biasQ[(size_t)blockIdx.x * 256 + ((k & 15) << 4) + (k >> 4)] =
      rpb[rpi[q * 256 + k] * NHEAD + h];
}

// ------- K2b: conv weight transpose to [tap][oc][ci] bf16 -------------------
__global__ __launch_bounds__(256) void k_wprep(const float* __restrict__ c1w,
                                               const float* __restrict__ c2w,
                                               bf16* __restrict__ wT1,
                                               bf16* __restrict__ wT2) {
  int i = blockIdx.x * 256 + threadIdx.x;   // 0 .. 110591
  {
    int tap = i / (64 * 192); int r = i % (64 * 192);
    int oc = r / 192, ci = r % 192;
    wT1[i] = f2b(c1w[(size_t)(tap * 192 + ci) * 64 + oc]);
  }
  {
    int tap = i / (192 * 64); int r = i % (192 * 64);
    int oc = r / 64, ci = r % 64;
    wT2[i] = f2b(c2w[(size_t)(tap * 64 + ci) * 192 + oc]);
  }
}

// ------- K2c: MLP weight transpose to n-major bf16 --------------------------
__global__ __launch_bounds__(256) void k_wprep2(const float* __restrict__ fc1w,
                                                const float* __restrict__ fc2w,
                                                bf16* __restrict__ wF1,
                                                bf16* __restrict__ wF2) {
  int i = blockIdx.x * 256 + threadIdx.x;   // 0 .. 147455
  {
    int n = i / 192, k = i % 192;           // wF1[n][k], n<768 k<192
    wF1[i] = f2b(fc1w[(size_t)k * 768 + n]);
  }
  {
    int n = i / 768, k = i % 768;           // wF2[n][k], n<192 k<768
    wF2[i] = f2b(fc2w[(size_t)k * 192 + n]);
  }
}

// ------- K2d: qkv/proj weight transpose to n-major bf16 ---------------------
__global__ __launch_bounds__(256) void k_wprep3(const float* __restrict__ qkvw,
                                                const float* __restrict__ projw,
                                                bf16* __restrict__ wQv,
                                                bf16* __restrict__ wP) {
  int i = blockIdx.x * 256 + threadIdx.x;   // 0 .. 147455 (grid 576)
  if (i < 576 * 192) {
    int n = i / 192, k = i % 192;           // wQv[n][k], n<576
    wQv[i] = f2b(qkvw[(size_t)k * 576 + n]);
  }
  if (i < 192 * 192) {
    int n = i / 192, k = i % 192;           // wP[n][k]
    wP[i] = f2b(projw[(size_t)k * 192 + n]);
  }
}

// --- K3: QKV GEMM, weight-stationary (fc1ws template) + gathered store ------
// grid 384 = 3 col-panels (cg: 0=Q,1=K,2=V) x 128 token-blocks (512 tokens).
// Panel wQv[cg*192..+192)[192] = 73,728 B contiguous -> staged once (swizzled
// glds16 memcpy). Wave hoists 18 weight frags (72 VGPR); barrier-free loop
// over 32 token tiles: 6 xn frags + 18 swapped-operand MFMA. Swapped-C layout
// puts 4 consecutive d per lane for ONE token -> gathered store is a single
// packed uint2 (8B) per nt; window-gather base computed once per tile.
__global__ __launch_bounds__(256, 2) void k_qkvws(const bf16* __restrict__ xn,
                                                  const bf16* __restrict__ wQv,
                                                  const float* __restrict__ qb,
                                                  bf16* __restrict__ Qg,
                                                  bf16* __restrict__ Kg,
                                                  bf16* __restrict__ Vg) {
  __shared__ unsigned short wl[192 * 192];   // 73,728 B
  int cg = blockIdx.x / 128, tb = blockIdx.x - cg * 128;
  int tid = threadIdx.x;
  int wave = tid >> 6, lane = tid & 63;
  int lm = lane & 15, lq = lane >> 4;

  const char* src = (const char*)wQv + (size_t)cg * 73728;
#pragma unroll
  for (int j = 0; j < 18; ++j) {
    int ci = j * 256 + tid;                  // 16B-chunk index 0..4607
    int r = ci / 24, c = ci - r * 24;        // row 0..191, chunk 0..23
    glds16(src + (size_t)r * 384 + ((c ^ (r & 7)) << 4),
           (char*)wl + (size_t)(j * 256 + wave * 64) * 16);
  }
  __syncthreads();

  short8 wfr[3][6];
#pragma unroll
  for (int nt = 0; nt < 3; ++nt) {
    int rl = wave * 48 + nt * 16 + lm;
#pragma unroll
    for (int ks = 0; ks < 6; ++ks)
      wfr[nt][ks] = *(const short8*)&wl[rl * 192 + (((ks * 4 + lq) ^ (rl & 7)) << 3)];
  }
  float4 b4[3];
  int head[3], d0[3];
#pragma unroll
  for (int nt = 0; nt < 3; ++nt) {
    int n0p = wave * 48 + nt * 16 + lq * 4;  // within-panel col (4 consecutive)
    b4[nt] = *(const float4*)(qb + cg * 192 + n0p);
    head[nt] = n0p >> 5;
    d0[nt] = n0p & 31;
  }
  bf16* dst = (cg == 0) ? Qg : (cg == 1) ? Kg : Vg;
  float scale = (cg == 0) ? SCALE_Q : 1.f;

  int tok0b = tb * 512;
#pragma unroll 2
  for (int t = 0; t < 32; ++t) {
    int tok0 = tok0b + t * 16;
    const bf16* arow = xn + (size_t)(tok0 + lm) * CC + lq * 8;
    // per-lane token -> gathered (window) base
    int tg = tok0 + lm;
    int b = tg >> 14;
    int pix = tg & 16383;
    int gh = pix >> 7, gw = pix & 127;
    int hs = (gh + 120) & 127, wsx = (gw + 120) & 127;
    int wdx = (b << 6) + ((hs >> 4) << 3) + (wsx >> 4);
    int ndx = ((hs & 15) << 4) + (wsx & 15);
    size_t base = ((size_t)wdx * NHEAD) * NTOK * HD + (size_t)ndx * HD;

    float4v acc[3];
#pragma unroll
    for (int nt = 0; nt < 3; ++nt) acc[nt] = (float4v){0.f, 0.f, 0.f, 0.f};
#pragma unroll
    for (int ks = 0; ks < 6; ++ks) {
      short8 tf = *(const short8*)(arow + ks * 32);
#pragma unroll
      for (int nt = 0; nt < 3; ++nt)
        acc[nt] = __builtin_amdgcn_mfma_f32_16x16x32_bf16(wfr[nt][ks], tf, acc[nt], 0, 0, 0);
    }
#pragma unroll
    for (int nt = 0; nt < 3; ++nt) {
      unsigned short u0 = f2bu((acc[nt][0] + b4[nt].x) * scale);
      unsigned short u1 = f2bu((acc[nt][1] + b4[nt].y) * scale);
      unsigned short u2 = f2bu((acc[nt][2] + b4[nt].z) * scale);
      unsigned short u3 = f2bu((acc[nt][3] + b4[nt].w) * scale);
      uint2 pk;
      pk.x = (unsigned)u0 | ((unsigned)u1 << 16);
      pk.y = (unsigned)u2 | ((unsigned)u3 << 16);
      *(uint2*)(dst + base + (size_t)head[nt] * NTOK * HD + d0[nt]) = pk;
    }
  }
}

// --- K4: windowed attention via MFMA, K in LDS, vector bias loads -----------
__global__ __launch_bounds__(256) void k_attn3(const bf16* __restrict__ Qg,
                                               const bf16* __restrict__ Kg,
                                               const bf16* __restrict__ Vg,
                                               const float* __restrict__ biasP,
                                               bf16* __restrict__ AO) {
  __shared__ unsigned short PTw[4][16 * PSTR];  // 33,792 B (wave-private P tiles)
  __shared__ unsigned short VT[32 * PSTR];      // 16,896 B (V transposed)
  __shared__ unsigned short KL[256 * KSTR];     // 20,480 B (K row-major padded)
  int wh = blockIdx.x >> 1, half = blockIdx.x & 1;
  int wdx = wh / NHEAD, h = wh - wdx * NHEAD;
  int wl = wdx & 63;
  int wr = wl >> 3, wc = wl & 7;
  int tid = threadIdx.x;
  int wave = tid >> 6, lane = tid & 63;
  int lm = lane & 15, lq = lane >> 4;
  int q0 = half * 128;
  bool needmask = (wr == 7) || (wc == 7);

  // stage V^T + K: thread tid handles key row tid
  {
    const uint4* vp = (const uint4*)(Vg + ((size_t)wh * NTOK + tid) * HD);
    uint4 vv[4] = {vp[0], vp[1], vp[2], vp[3]};
    const uint4* kp = (const uint4*)(Kg + ((size_t)wh * NTOK + tid) * HD);
    uint4 kv[4] = {kp[0], kp[1], kp[2], kp[3]};
#pragma unroll
    for (int i = 0; i < 4; ++i) {
      unsigned arr[4] = {vv[i].x, vv[i].y, vv[i].z, vv[i].w};
#pragma unroll
      for (int j = 0; j < 4; ++j) {
        int d = i * 8 + j * 2;
        VT[d * PSTR + tid]       = (unsigned short)(arr[j] & 0xffffu);
        VT[(d + 1) * PSTR + tid] = (unsigned short)(arr[j] >> 16);
      }
      *(uint4*)&KL[tid * KSTR + i * 8] = kv[i];
    }
  }
  __syncthreads();

  int wsk = (wc << 4) + lm;                       // lane's key col (w coord)
  int ridk_w = (wsk >= 112) + (wsk >= 120);
  unsigned short* PT = &PTw[wave][0];

  float4v oacc[2][2];
#pragma unroll
  for (int rt = 0; rt < 2; ++rt)
#pragma unroll
    for (int c2 = 0; c2 < 2; ++c2) oacc[rt][c2] = (float4v){0.f, 0.f, 0.f, 0.f};
  float linv[2][4];

#pragma unroll
  for (int rt = 0; rt < 2; ++rt) {
    int qrow = q0 + wave * 32 + rt * 16;
    short8 aq = *(const short8*)(Qg + ((size_t)wh * NTOK + qrow + lm) * HD + lq * 8);
    float4v sacc[16];
#pragma unroll
    for (int ct = 0; ct < 16; ++ct) sacc[ct] = (float4v){0.f, 0.f, 0.f, 0.f};
#pragma unroll
    for (int ct = 0; ct < 16; ++ct) {
      short8 kf = *(const short8*)&KL[(ct * 16 + lm) * KSTR + lq * 8];
      sacc[ct] = __builtin_amdgcn_mfma_f32_16x16x32_bf16(aq, kf, sacc[ct], 0, 0, 0);
    }
    // softmax over 256 keys, rows lq*4+reg of this 16-row tile
#pragma unroll
    for (int reg = 0; reg < 4; ++reg) {
      int nq = qrow + lq * 4 + reg;
      const float* bp = biasP + ((size_t)(h * 256 + nq)) * 256 + lm * 16;
      float bb[16];
      *(float4*)&bb[0]  = ((const float4*)bp)[0];
      *(float4*)&bb[4]  = ((const float4*)bp)[1];
      *(float4*)&bb[8]  = ((const float4*)bp)[2];
      *(float4*)&bb[12] = ((const float4*)bp)[3];
      float sv[16];
      float mx = -1.0e30f;
      if (needmask) {
        int hsq = (wr << 4) + (nq >> 4), wsq = (wc << 4) + (nq & 15);
        int ridq = ((hsq >= 112) + (hsq >= 120)) * 3 + ((wsq >= 112) + (wsq >= 120));
#pragma unroll
        for (int ct = 0; ct < 16; ++ct) {
          int hsk = (wr << 4) + ct;
          int ridk = ((hsk >= 112) + (hsk >= 120)) * 3 + ridk_w;
          float s = sacc[ct][reg] + bb[ct] + ((ridk != ridq) ? -100.f : 0.f);
          sv[ct] = s;
          mx = fmaxf(mx, s);
        }
      } else {
#pragma unroll
        for (int ct = 0; ct < 16; ++ct) {
          float s = sacc[ct][reg] + bb[ct];
          sv[ct] = s;
          mx = fmaxf(mx, s);
        }
      }
#pragma unroll
      for (int off = 1; off < 16; off <<= 1) mx = fmaxf(mx, __shfl_xor(mx, off, 64));
      float l = 0.f;
#pragma unroll
      for (int ct = 0; ct < 16; ++ct) {
        float p = __expf(sv[ct] - mx);
        l += p;
        PT[(lq * 4 + reg) * PSTR + ct * 16 + lm] = f2bu(p);
      }
#pragma unroll
      for (int off = 1; off < 16; off <<= 1) l += __shfl_xor(l, off, 64);
      linv[rt][reg] = 1.f / l;
    }
    // PV for this row tile: A = P rows (wave-private, in-wave LDS ordering)
#pragma unroll
    for (int kb = 0; kb < 8; ++kb) {
      short8 pf = *(const short8*)&PT[lm * PSTR + kb * 32 + lq * 8];
#pragma unroll
      for (int c2 = 0; c2 < 2; ++c2) {
        short8 vf = *(const short8*)&VT[(c2 * 16 + lm) * PSTR + kb * 32 + lq * 8];
        oacc[rt][c2] = __builtin_amdgcn_mfma_f32_16x16x32_bf16(pf, vf, oacc[rt][c2], 0, 0, 0);
      }
    }
  }
  // write AO
#pragma unroll
  for (int rt = 0; rt < 2; ++rt)
#pragma unroll
    for (int c2 = 0; c2 < 2; ++c2) {
      int d = c2 * 16 + lm;
#pragma unroll
      for (int reg = 0; reg < 4; ++reg) {
        int nq = q0 + wave * 32 + rt * 16 + lq * 4 + reg;
        AO[((size_t)wdx * NTOK + nq) * CC + h * HD + d] =
            f2b(oacc[rt][c2][reg] * linv[rt][reg]);
      }
    }
}

// --- K5: proj GEMM, weight-stationary (fc1ws template) + shift-rev residual -
// grid 128 token-blocks (512 tokens), block 256 (4 waves x 48 cols).
// wP (73,728 B) staged once; 32 token tiles x {6 AO frags, 18 MFMA}.
// Swapped-C: lane holds 4 consecutive cols for ONE token -> epilogue is
// float4 x-load + float4 y-store at the shift-reversed row (was 8 scalar f32).
__global__ __launch_bounds__(256, 2) void k_projws(const bf16* __restrict__ AO,
                                                   const bf16* __restrict__ wP,
                                                   const float* __restrict__ pb,
                                                   const float* __restrict__ x,
                                                   float* __restrict__ y) {
  __shared__ unsigned short wl[192 * 192];   // 73,728 B
  int tb = blockIdx.x;
  int tid = threadIdx.x;
  int wave = tid >> 6, lane = tid & 63;
  int lm = lane & 15, lq = lane >> 4;

  const char* src = (const char*)wP;
#pragma unroll
  for (int j = 0; j < 18; ++j) {
    int ci = j * 256 + tid;
    int r = ci / 24, c = ci - r * 24;
    glds16(src + (size_t)r * 384 + ((c ^ (r & 7)) << 4),
           (char*)wl + (size_t)(j * 256 + wave * 64) * 16);
  }
  __syncthreads();

  short8 wfr[3][6];
#pragma unroll
  for (int nt = 0; nt < 3; ++nt) {
    int rl = wave * 48 + nt * 16 + lm;
#pragma unroll
    for (int ks = 0; ks < 6; ++ks)
      wfr[nt][ks] = *(const short8*)&wl[rl * 192 + (((ks * 4 + lq) ^ (rl & 7)) << 3)];
  }
  float4 b4[3];
#pragma unroll
  for (int nt = 0; nt < 3; ++nt)
    b4[nt] = *(const float4*)(pb + wave * 48 + nt * 16 + lq * 4);

  int r0b = tb * 512;
#pragma unroll 2
  for (int t = 0; t < 32; ++t) {
    int r0 = r0b + t * 16;
    const bf16* arow = AO + (size_t)(r0 + lm) * CC + lq * 8;
    // per-lane win-order row -> shift-reversed pixel row
    int r = r0 + lm;
    int wdx = r >> 8, n = r & 255;
    int wb = wdx >> 6, wlx = wdx & 63;
    int hs = ((wlx >> 3) << 4) + (n >> 4);
    int wsx = ((wlx & 7) << 4) + (n & 15);
    int gh = (hs + SSH) & 127, gw = (wsx + SSH) & 127;
    size_t drow = ((size_t)wb * HWPIX + (size_t)gh * WWID + gw) * CC;

    float4v acc[3];
#pragma unroll
    for (int nt = 0; nt < 3; ++nt) acc[nt] = (float4v){0.f, 0.f, 0.f, 0.f};
#pragma unroll
    for (int ks = 0; ks < 6; ++ks) {
      short8 tf = *(const short8*)(arow + ks * 32);
#pragma unroll
      for (int nt = 0; nt < 3; ++nt)
        acc[nt] = __builtin_amdgcn_mfma_f32_16x16x32_bf16(wfr[nt][ks], tf, acc[nt], 0, 0, 0);
    }
#pragma unroll
    for (int nt = 0; nt < 3; ++nt) {
      int col0 = wave * 48 + nt * 16 + lq * 4;
      float4 xv = *(const float4*)(x + drow + col0);
      float4 ov;
      ov.x = xv.x + acc[nt][0] + b4[nt].x;
      ov.y = xv.y + acc[nt][1] + b4[nt].y;
      ov.z = xv.z + acc[nt][2] + b4[nt].z;
      ov.w = xv.w + acc[nt][3] + b4[nt].w;
      *(float4*)(y + drow + col0) = ov;
    }
  }
}

// ---- K6: conv3x3 192->64 + GELU, LDS-staged input rows ---------------------
__global__ __launch_bounds__(512, 1) void k_conv1l(const bf16* __restrict__ xn,
                                                   const bf16* __restrict__ wT1,
                                                   const float* __restrict__ c1b,
                                                   bf16* __restrict__ cv1) {
  __shared__ unsigned short xs[3 * 128 * 192];   // 147,456 B
  int hh = blockIdx.x & 127, b = blockIdx.x >> 7;
  int tid = threadIdx.x;
  int wave = tid >> 6, lane = tid & 63;
  int lm = lane & 15, lq = lane >> 4;
  int ph = wave >> 2;                 // px half (0: 0-63, 1: 64-127)
  int oc = (wave & 3) * 16 + lm;

  // stage rows hh-1..hh+1 (3072 16B-chunks each)
#pragma unroll
  for (int r = 0; r < 3; ++r) {
    int gh = hh + r - 1;
    if ((unsigned)gh < 128u) {        // block-uniform
      const char* src = (const char*)(xn + (size_t)(b * HWPIX + gh * WWID) * CC);
#pragma unroll
      for (int j = 0; j < 6; ++j) {
        int c = j * 512 + tid;        // 0..3071
        int px = c / 24, kc = c - px * 24;
        glds16(src + (size_t)px * 384 + ((size_t)(kc ^ (px & 7)) << 4),
               (char*)xs + ((size_t)(r * 3072 + j * 512 + wave * 64)) * 16);
      }
    }
  }
  __syncthreads();

  float4v acc[4];
#pragma unroll
  for (int t = 0; t < 4; ++t) acc[t] = (float4v){0.f, 0.f, 0.f, 0.f};

  short8 w[6], wn[6];
#pragma unroll
  for (int ks = 0; ks < 6; ++ks)
    w[ks] = *(const short8*)(wT1 + ((size_t)oc) * CC + ks * 32 + lq * 8);
#pragma unroll
  for (int tap = 0; tap < 9; ++tap) {
    if (tap < 8) {
#pragma unroll
      for (int ks = 0; ks < 6; ++ks)
        wn[ks] = *(const short8*)(wT1 + ((size_t)((tap + 1) * 64) + oc) * CC + ks * 32 + lq * 8);
    }
    int kh = tap / 3, kw = tap % 3;
    int gh = hh + kh - 1;
    if ((unsigned)gh < 128u) {        // block-uniform skip of OOB rows
      const unsigned short* row = &xs[kh * 24576];
#pragma unroll
      for (int ks = 0; ks < 6; ++ks) {
#pragma unroll
        for (int t = 0; t < 4; ++t) {
          int px = ph * 64 + t * 16 + lm + kw - 1;
          int pxc = px < 0 ? 0 : (px > 127 ? 127 : px);
          short8 av = *(const short8*)&row[pxc * 192 + (((ks * 4 + lq) ^ (pxc & 7)) << 3)];
          short8 zz = {0, 0, 0, 0, 0, 0, 0, 0};
          short8 a = ((unsigned)px < 128u) ? av : zz;
          acc[t] = __builtin_amdgcn_mfma_f32_16x16x32_bf16(a, w[ks], acc[t], 0, 0, 0);
        }
      }
    }
#pragma unroll
    for (int ks = 0; ks < 6; ++ks) w[ks] = wn[ks];
  }
  float bias = c1b[oc];
#pragma unroll
  for (int t = 0; t < 4; ++t) {
    int pxb = ph * 64 + t * 16 + lq * 4;
    size_t base = ((size_t)b * HWPIX + (size_t)hh * WWID + pxb) * 64 + oc;
    cv1[base]       = f2b(gelu_exact(acc[t][0] + bias));
    cv1[base + 64]  = f2b(gelu_exact(acc[t][1] + bias));
    cv1[base + 128] = f2b(gelu_exact(acc[t][2] + bias));
    cv1[base + 192] = f2b(gelu_exact(acc[t][3] + bias));
  }
}

// ---- K7: conv3x3 64->192 + bias, LDS-staged input rows ---------------------
__global__ __launch_bounds__(512, 2) void k_conv2l(const bf16* __restrict__ cv1,
                                                   const bf16* __restrict__ wT2,
                                                   const float* __restrict__ c2b,
                                                   bf16* __restrict__ cv2) {
  __shared__ unsigned short cs[3 * 128 * 64];    // 49,152 B
  int hh = blockIdx.x & 127, b = blockIdx.x >> 7;
  int tid = threadIdx.x;
  int wave = tid >> 6, lane = tid & 63;
  int lm = lane & 15, lq = lane >> 4;
  int ph = wave >> 2;                 // px half
  int og = wave & 3;                  // oc group (48 cols)

  // stage rows hh-1..hh+1 (1024 16B-chunks each)
#pragma unroll
  for (int r = 0; r < 3; ++r) {
    int gh = hh + r - 1;
    if ((unsigned)gh < 128u) {
      const char* src = (const char*)(cv1 + (size_t)(b * HWPIX + gh * WWID) * 64);
#pragma unroll
      for (int j = 0; j < 2; ++j) {
        int c = j * 512 + tid;        // 0..1023
        int px = c >> 3, kc = c & 7;
        glds16(src + (size_t)px * 128 + ((size_t)(kc ^ (px & 7)) << 4),
               (char*)cs + ((size_t)(r * 1024 + j * 512 + wave * 64)) * 16);
      }
    }
  }
  __syncthreads();

  float4v acc[3][4];
#pragma unroll
  for (int nt = 0; nt < 3; ++nt)
#pragma unroll
    for (int t = 0; t < 4; ++t) acc[nt][t] = (float4v){0.f, 0.f, 0.f, 0.f};

  short8 w[3][2], wn[3][2];
#pragma unroll
  for (int nt = 0; nt < 3; ++nt) {
    int oc = og * 48 + nt * 16 + lm;
#pragma unroll
    for (int ks = 0; ks < 2; ++ks)
      w[nt][ks] = *(const short8*)(wT2 + ((size_t)oc) * 64 + ks * 32 + lq * 8);
  }
#pragma unroll
  for (int tap = 0; tap < 9; ++tap) {
    if (tap < 8) {
#pragma unroll
      for (int nt = 0; nt < 3; ++nt) {
        int oc = og * 48 + nt * 16 + lm;
#pragma unroll
        for (int ks = 0; ks < 2; ++ks)
          wn[nt][ks] = *(const short8*)(wT2 + ((size_t)((tap + 1) * 192) + oc) * 64 + ks * 32 + lq * 8);
      }
    }
    int kh = tap / 3, kw = tap % 3;
    int gh = hh + kh - 1;
    if ((unsigned)gh < 128u) {
      const unsigned short* row = &cs[kh * 8192];
#pragma unroll
      for (int ks = 0; ks < 2; ++ks) {
#pragma unroll
        for (int t = 0; t < 4; ++t) {
          int px = ph * 64 + t * 16 + lm + kw - 1;
          int pxc = px < 0 ? 0 : (px > 127 ? 127 : px);
          short8 av = *(const short8*)&row[pxc * 64 + (((ks * 4 + lq) ^ (pxc & 7)) << 3)];
          short8 zz = {0, 0, 0, 0, 0, 0, 0, 0};
          short8 a = ((unsigned)px < 128u) ? av : zz;
#pragma unroll
          for (int nt = 0; nt < 3; ++nt)
            acc[nt][t] = __builtin_amdgcn_mfma_f32_16x16x32_bf16(a, w[nt][ks], acc[nt][t], 0, 0, 0);
        }
      }
    }
#pragma unroll
    for (int nt = 0; nt < 3; ++nt)
#pragma unroll
      for (int ks = 0; ks < 2; ++ks) w[nt][ks] = wn[nt][ks];
  }
#pragma unroll
  for (int nt = 0; nt < 3; ++nt) {
    int oc = og * 48 + nt * 16 + lm;
    float bias = c2b[oc];
#pragma unroll
    for (int t = 0; t < 4; ++t) {
      int pxb = ph * 64 + t * 16 + lq * 4;
      size_t base = ((size_t)b * HWPIX + (size_t)hh * WWID + pxb) * CC + oc;
      cv2[base]           = f2b(acc[nt][t][0] + bias);
      cv2[base + CC]      = f2b(acc[nt][t][1] + bias);
      cv2[base + 2 * CC]  = f2b(acc[nt][t][2] + bias);
      cv2[base + 3 * CC]  = f2b(acc[nt][t][3] + bias);
    }
  }
}

// ---------------- K8: global average pool (sum into pooled, pre-zeroed) ----
__global__ __launch_bounds__(192) void k_pool(const bf16* __restrict__ cv2,
                                              float* __restrict__ pooled) {
  int t = threadIdx.x;                        // channel
  int b = blockIdx.x >> 7;
  int pc = blockIdx.x & 127;                  // 128-pixel chunk
  const bf16* base = cv2 + ((size_t)b * HWPIX + (size_t)pc * 128) * CC + t;
  float s = 0.f;
#pragma unroll 4
  for (int p = 0; p < 128; ++p) s += b2f(base[(size_t)p * CC]);
  atomicAdd(&pooled[b * CC + t], s);
}

// ---------------- K9: channel attention weights ----------------
__global__ __launch_bounds__(192) void k_ca(const float* __restrict__ pooled,
                                            const float* __restrict__ w1,
                                            const float* __restrict__ b1,
                                            const float* __restrict__ w2,
                                            const float* __restrict__ b2,
                                            float* __restrict__ ca) {
  __shared__ float pld[CC];
  __shared__ float t1[6];
  int t = threadIdx.x, b = blockIdx.x;
  pld[t] = pooled[b * CC + t] * (1.0f / HWPIX);
  __syncthreads();
  if (t < 6) {
    float s = b1[t];
    for (int c = 0; c < CC; ++c) s += pld[c] * w1[c * 6 + t];
    t1[t] = fmaxf(s, 0.f);
  }
  __syncthreads();
  float s = b2[t];
#pragma unroll
  for (int k = 0; k < 6; ++k) s += t1[k] * w2[k * CC + t];
  ca[b * CC + t] = 1.f / (1.f + __expf(-s));
}

// --- K10: LN2 with conv-branch fold: yn = LN(y + cv2*ca*0.01) bf16 ---------
__global__ __launch_bounds__(256) void k_ln2(const float* __restrict__ y,
                                             const bf16* __restrict__ cv2,
                                             const float* __restrict__ ca,
                                             const float* __restrict__ g2,
                                             const float* __restrict__ b2,
                                             bf16* __restrict__ yn) {
  int wv = threadIdx.x >> 6, lane = threadIdx.x & 63;
  int tok = blockIdx.x * 4 + wv;
  const float* cab = ca + (tok >> 14) * CC;
  size_t row = (size_t)tok * CC;
  float v0 = y[row + lane]       + b2f(cv2[row + lane])       * cab[lane]       * CONV_SC;
  float v1 = y[row + lane + 64]  + b2f(cv2[row + lane + 64])  * cab[lane + 64]  * CONV_SC;
  float v2 = y[row + lane + 128] + b2f(cv2[row + lane + 128]) * cab[lane + 128] * CONV_SC;
  float s = v0 + v1 + v2, ss = v0 * v0 + v1 * v1 + v2 * v2;
#pragma unroll
  for (int off = 1; off < 64; off <<= 1) {
    s += __shfl_xor(s, off, 64);
    ss += __shfl_xor(ss, off, 64);
  }
  float mean = s * (1.0f / CC);
  float rstd = rsqrtf(ss * (1.0f / CC) - mean * mean + 1e-5f);
  yn[row + lane]       = f2b((v0 - mean) * rstd * g2[lane]       + b2[lane]);
  yn[row + lane + 64]  = f2b((v1 - mean) * rstd * g2[lane + 64]  + b2[lane + 64]);
  yn[row + lane + 128] = f2b((v2 - mean) * rstd * g2[lane + 128] + b2[lane + 128]);
}

// --- K11a: fc1 weight-stationary: h = GELU(yn @ fc1 + b) --------------------
__global__ __launch_bounds__(256, 2) void k_fc1ws(const bf16* __restrict__ yn,
                                                  const bf16* __restrict__ wF1,
                                                  const float* __restrict__ fb1,
                                                  bf16* __restrict__ h) {
  __shared__ unsigned short wl[192 * 192];   // 73,728 B
  int cg = blockIdx.x & 3, tb = blockIdx.x >> 2;
  int tid = threadIdx.x;
  int wave = tid >> 6, lane = tid & 63;
  int lm = lane & 15, lq = lane >> 4;

  const char* src = (const char*)wF1 + (size_t)cg * 73728;
#pragma unroll
  for (int j = 0; j < 18; ++j) {
    int ci = j * 256 + tid;                  // 16B-chunk index 0..4607
    int r = ci / 24, c = ci - r * 24;        // row 0..191, chunk 0..23
    glds16(src + (size_t)r * 384 + ((c ^ (r & 7)) << 4),
           (char*)wl + (size_t)(j * 256 + wave * 64) * 16);
  }
  __syncthreads();

  // hoist wave's B-frags (cols wave*48 + nt*16 + lm) -- one-time LDS reads
  short8 wfr[3][6];
#pragma unroll
  for (int nt = 0; nt < 3; ++nt) {
    int rl = wave * 48 + nt * 16 + lm;
#pragma unroll
    for (int ks = 0; ks < 6; ++ks)
      wfr[nt][ks] = *(const short8*)&wl[rl * 192 + (((ks * 4 + lq) ^ (rl & 7)) << 3)];
  }
  float4 b4[3];
#pragma unroll
  for (int nt = 0; nt < 3; ++nt)
    b4[nt] = *(const float4*)(fb1 + cg * 192 + wave * 48 + nt * 16 + lq * 4);

  int tok0b = tb * 512;
#pragma unroll 2
  for (int t = 0; t < 32; ++t) {
    int tok0 = tok0b + t * 16;
    const bf16* arow = yn + (size_t)(tok0 + lm) * CC + lq * 8;
    float4v acc[3];
#pragma unroll
    for (int nt = 0; nt < 3; ++nt) acc[nt] = (float4v){0.f, 0.f, 0.f, 0.f};
#pragma unroll
    for (int ks = 0; ks < 6; ++ks) {
      short8 tf = *(const short8*)(arow + ks * 32);
#pragma unroll
      for (int nt = 0; nt < 3; ++nt)
        acc[nt] = __builtin_amdgcn_mfma_f32_16x16x32_bf16(wfr[nt][ks], tf, acc[nt], 0, 0, 0);
    }
    bf16* hrow = h + (size_t)(tok0 + lm) * 768 + cg * 192 + wave * 48 + lq * 4;
#pragma unroll
    for (int nt = 0; nt < 3; ++nt) {
      unsigned short u0 = f2bu(gelu_exact(acc[nt][0] + b4[nt].x));
      unsigned short u1 = f2bu(gelu_exact(acc[nt][1] + b4[nt].y));
      unsigned short u2 = f2bu(gelu_exact(acc[nt][2] + b4[nt].z));
      unsigned short u3 = f2bu(gelu_exact(acc[nt][3] + b4[nt].w));
      uint2 pk;
      pk.x = (unsigned)u0 | ((unsigned)u1 << 16);
      pk.y = (unsigned)u2 | ((unsigned)u3 << 16);
      *(uint2*)(hrow + nt * 16) = pk;
    }
  }
}

// --- K11b: fc2 via m97-style double-buffered LDS GEMM + residual epilogue ---
__global__ __launch_bounds__(256, 2) void k_fc2m(const bf16* __restrict__ h,
                                                 const bf16* __restrict__ wF2,
                                                 const float* __restrict__ fb2,
                                                 const float* __restrict__ y,
                                                 const bf16* __restrict__ cv2,
                                                 const float* __restrict__ ca,
                                                 float* __restrict__ out) {
  __shared__ unsigned short ha[2][4096];   // [128 tok][32 k] bf16, 8,192 B/buf
  __shared__ unsigned short wbt[2][6144];  // [192 col][32 k] bf16, 12,288 B/buf
  int r0 = blockIdx.x * 128;
  int tid = threadIdx.x;
  int wave = tid >> 6, lane = tid & 63;
  int lm = lane & 15, lq = lane >> 4;

  const char* hsrc = (const char*)(h + (size_t)r0 * 768);
  const char* wsrc = (const char*)wF2;

  float4v acc[2][12];
#pragma unroll
  for (int mt = 0; mt < 2; ++mt)
#pragma unroll
    for (int nt = 0; nt < 12; ++nt) acc[mt][nt] = (float4v){0.f, 0.f, 0.f, 0.f};

  // stage K-chunk kc into buffer b (linear LDS, per m97: no swizzle)
  auto stage = [&](int kc, int b) {
    int k0b = kc * 64;                     // byte offset of k-chunk in a row
#pragma unroll
    for (int j = 0; j < 2; ++j) {          // ha: 512 x 16B chunks
      int c = j * 256 + tid;               // row=c>>2 (x1536B), koff=c&3 (x16B)
      glds16(hsrc + (size_t)(c >> 2) * 1536 + k0b + (c & 3) * 16,
             (char*)&ha[b][0] + (j * 256 + wave * 64) * 16);
    }
#pragma unroll
    for (int j = 0; j < 3; ++j) {          // wbt: 768 x 16B chunks
      int c = j * 256 + tid;               // col=c>>2, koff=c&3
      glds16(wsrc + (size_t)(c >> 2) * 1536 + k0b + (c & 3) * 16,
             (char*)&wbt[b][0] + (j * 256 + wave * 64) * 16);
    }
  };

  stage(0, 0);
  __syncthreads();
#pragma unroll 1
  for (int kc = 0; kc < 24; ++kc) {
    int cur = kc & 1;
    if (kc < 23) stage(kc + 1, cur ^ 1);
    short8 af[2], bf[12];
#pragma unroll
    for (int mt = 0; mt < 2; ++mt)
      af[mt] = *(const short8*)&ha[cur][(wave * 32 + mt * 16 + lm) * 32 + lq * 8];
#pragma unroll
    for (int nt = 0; nt < 12; ++nt)
      bf[nt] = *(const short8*)&wbt[cur][(nt * 16 + lm) * 32 + lq * 8];
#pragma unroll
    for (int mt = 0; mt < 2; ++mt)
#pragma unroll
      for (int nt = 0; nt < 12; ++nt)
        acc[mt][nt] = __builtin_amdgcn_mfma_f32_16x16x32_bf16(af[mt], bf[nt], acc[mt][nt], 0, 0, 0);
    __syncthreads();
  }

  // epilogue: out = acc + y + cv2*ca*0.01 + bias
  const float* cab = ca + (r0 >> 14) * CC;
#pragma unroll
  for (int nt = 0; nt < 12; ++nt) {
    int col = nt * 16 + lm;
    float bias = fb2[col];
    float cas = cab[col] * CONV_SC;
#pragma unroll
    for (int mt = 0; mt < 2; ++mt) {
#pragma unroll
      for (int reg = 0; reg < 4; ++reg) {
        int tok = r0 + wave * 32 + mt * 16 + lq * 4 + reg;
        size_t idx = (size_t)tok * CC + col;
        out[idx] = y[idx] + b2f(cv2[idx]) * cas + acc[mt][nt][reg] + bias;
      }
    }
  }
}

extern "C" void kernel_launch(void* const* d_in, const int* in_sizes, int n_in,
                              void* d_out, int out_size, void* d_ws, size_t ws_size,
                              hipStream_t stream) {
  const float* x      = (const float*)d_in[0];
  const float* qkv_w  = (const float*)d_in[1];
  const float* qkv_b  = (const float*)d_in[2];
  const float* proj_w = (const float*)d_in[3];
  const float* proj_b = (const float*)d_in[4];
  const float* rpb    = (const float*)d_in[5];
  const float* n1w    = (const float*)d_in[6];
  const float* n1b    = (const float*)d_in[7];
  const float* n2w    = (const float*)d_in[8];
  const float* n2b    = (const float*)d_in[9];
  const float* c1w    = (const float*)d_in[10];
  const float* c1b    = (const float*)d_in[11];
  const float* c2w    = (const float*)d_in[12];
  const float* c2b    = (const float*)d_in[13];
  const float* ca1w   = (const float*)d_in[14];
  const float* ca1b   = (const float*)d_in[15];
  const float* ca2w   = (const float*)d_in[16];
  const float* ca2b   = (const float*)d_in[17];
  const float* fc1w   = (const float*)d_in[18];
  const float* fc1b   = (const float*)d_in[19];
  const float* fc2w   = (const float*)d_in[20];
  const float* fc2b   = (const float*)d_in[21];
  const int*   rpi    = (const int*)d_in[22];
  (void)in_sizes; (void)n_in; (void)out_size; (void)ws_size;

  // ---- workspace layout: peak ~212.6 MB (< 256 MiB) ----
  char* wsb = (char*)d_ws;
  bf16*  xn    = (bf16*)(wsb + 0);            // 25,165,824
  bf16*  yn    = (bf16*)(wsb + 0);            // alias xn (dead after conv1l)
  float* biasQ = (float*)(wsb + 25165824);    //  1,572,864
  bf16*  Qg    = (bf16*)(wsb + 26738688);     // 25,165,824
  bf16*  Kg    = (bf16*)(wsb + 51904512);     // 25,165,824
  bf16*  Vg    = (bf16*)(wsb + 77070336);     // 25,165,824
  bf16*  AO    = (bf16*)(wsb + 102236160);    // 25,165,824
  bf16*  hbuf  = (bf16*)(wsb + 26738688);     // 100,663,296 alias Qg..AO (dead after projws)
  float* y     = (float*)(wsb + 127401984);   // 50,331,648
  bf16*  cv1   = (bf16*)(wsb + 177733632);    //  8,388,608
  bf16*  cv2   = (bf16*)(wsb + 186122240);    // 25,165,824
  float* pool  = (float*)(wsb + 211288064);   //      3,072
  float* cavec = (float*)(wsb + 211291136);   //      3,072
  bf16*  wT1   = (bf16*)(wsb + 211294208);    //    221,184  [9][64][192]
  bf16*  wT2   = (bf16*)(wsb + 211515392);    //    221,184  [9][192][64]
  bf16*  wF1   = (bf16*)(wsb + 211736576);    //    294,912  [768][192]
  bf16*  wF2   = (bf16*)(wsb + 212031488);    //    294,912  [192][768]
  bf16*  wQv   = (bf16*)(wsb + 212326400);    //    221,184  [576][192]
  bf16*  wP    = (bf16*)(wsb + 212547584);    //     73,728  [192][192]
  float* out   = (float*)d_out;               // end 212,621,312

  k_ln1<<<TTOT / 4, 256, 0, stream>>>(x, n1w, n1b, xn);
  k_biasq<<<NHEAD * NTOK, 256, 0, stream>>>(rpi, rpb, biasQ);
  k_wprep<<<432, 256, 0, stream>>>(c1w, c2w, wT1, wT2);
  k_wprep2<<<576, 256, 0, stream>>>(fc1w, fc2w, wF1, wF2);
  k_wprep3<<<576, 256, 0, stream>>>(qkv_w, proj_w, wQv, wP);
  k_qkvws<<<384, 256, 0, stream>>>(xn, wQv, qkv_b, Qg, Kg, Vg);
  k_attn3<<<BB * 64 * NHEAD * 2, 256, 0, stream>>>(Qg, Kg, Vg, biasQ, AO);
  k_projws<<<128, 256, 0, stream>>>(AO, wP, proj_b, x, y);
  k_conv1l<<<BB * 128, 512, 0, stream>>>(xn, wT1, c1b, cv1);
  k_conv2l<<<BB * 128, 512, 0, stream>>>(cv1, wT2, c2b, cv2);
  hipMemsetAsync(pool, 0, BB * CC * sizeof(float), stream);
  k_pool<<<512, 192, 0, stream>>>(cv2, pool);
  k_ca<<<BB, 192, 0, stream>>>(pool, ca1w, ca1b, ca2w, ca2b, cavec);
  k_ln2<<<TTOT / 4, 256, 0, stream>>>(y, cv2, cavec, n2w, n2b, yn);
  k_fc1ws<<<512, 256, 0, stream>>>(yn, wF1, fc1b, hbuf);
  k_fc2m<<<512, 256, 0, stream>>>(hbuf, wF2, fc2b, y, cv2, cavec, out);
}